// Round 1
// baseline (4814.281 us; speedup 1.0000x reference)
//
#include <hip/hip_runtime.h>
#include <math.h>

#define NN 50000
#define MM 4
#define EE 400000
#define BB 64
#define NROWS (NN*MM)   // 200000

// ---------- helpers ----------

__device__ __forceinline__ unsigned enc_f(float f) {
  unsigned u = __float_as_uint(f);
  return (u & 0x80000000u) ? ~u : (u | 0x80000000u);
}
__device__ __forceinline__ float dec_f(unsigned u) {
  return (u & 0x80000000u) ? __uint_as_float(u ^ 0x80000000u) : __uint_as_float(~u);
}

__device__ __forceinline__ void fma16(float* acc, float s, const float* w) {
  float4 w0 = *(const float4*)(w + 0);
  float4 w1 = *(const float4*)(w + 4);
  float4 w2 = *(const float4*)(w + 8);
  float4 w3 = *(const float4*)(w + 12);
  acc[0]  += s * w0.x;  acc[1]  += s * w0.y;  acc[2]  += s * w0.z;  acc[3]  += s * w0.w;
  acc[4]  += s * w1.x;  acc[5]  += s * w1.y;  acc[6]  += s * w1.z;  acc[7]  += s * w1.w;
  acc[8]  += s * w2.x;  acc[9]  += s * w2.y;  acc[10] += s * w2.z;  acc[11] += s * w2.w;
  acc[12] += s * w3.x;  acc[13] += s * w3.y;  acc[14] += s * w3.z;  acc[15] += s * w3.w;
}

// ---------- layer 0 (Din = 1) ----------

// agg0[dst, m] += x0[src, m]   (E*M threads)
__global__ void scatter0_k(const float* __restrict__ x0, const int* __restrict__ ei,
                           float* __restrict__ agg0) {
  int idx = blockIdx.x * blockDim.x + threadIdx.x;
  if (idx >= EE * MM) return;
  int e = idx >> 2, m = idx & 3;
  int src = ei[e], dst = ei[EE + e];
  unsafeAtomicAdd(&agg0[dst * MM + m], x0[src * MM + m]);
}

// x1[row, h] = relu(x0[row]*Ws0[h] + agg0[row]*Wn0[h]) -> xcat col 0..64
__global__ void conv0_k(const float* __restrict__ x0, const float* __restrict__ agg0,
                        const float* __restrict__ Ws0, const float* __restrict__ Wn0,
                        float* __restrict__ xcat) {
  int idx = blockIdx.x * blockDim.x + threadIdx.x;   // NROWS*64
  int row = idx >> 6, h = idx & 63;
  float v = x0[row] * Ws0[h] + agg0[row] * Wn0[h];
  xcat[(size_t)row * 192 + h] = fmaxf(v, 0.0f);
}

// ---------- 64-channel scatter-add (layers 1,2) ----------
// xin: base pointer at proper column offset, row stride 192
__global__ void scatter64_k(const float* __restrict__ xin, const int* __restrict__ ei,
                            float* __restrict__ agg) {
  int idx = blockIdx.x * blockDim.x + threadIdx.x;   // E*M*16
  if (idx >= EE * MM * 16) return;
  int c4 = idx & 15;
  int m  = (idx >> 4) & 3;
  int e  = idx >> 6;
  int src = ei[e], dst = ei[EE + e];
  float4 v = *(const float4*)(xin + (size_t)(src * MM + m) * 192 + (c4 << 2));
  float* d = agg + (size_t)(dst * MM + m) * 64 + (c4 << 2);
  unsafeAtomicAdd(d + 0, v.x);
  unsafeAtomicAdd(d + 1, v.y);
  unsafeAtomicAdd(d + 2, v.z);
  unsafeAtomicAdd(d + 3, v.w);
}

// ---------- conv layers 1,2: y = relu(x@Ws + agg@Wn), 64 rows/block ----------
__global__ __launch_bounds__(256) void conv_k(const float* __restrict__ xin,
                                              const float* __restrict__ agg,
                                              const float* __restrict__ Ws,
                                              const float* __restrict__ Wn,
                                              float* __restrict__ xout) {
  __shared__ float Xl[64][68];
  __shared__ float Al[64][68];
  const int row0 = blockIdx.x << 6;
  const int tid = threadIdx.x;

  for (int k = tid; k < 1024; k += 256) {            // 64 rows x 16 float4
    int r = k >> 4, c = (k & 15) << 2;
    *(float4*)&Xl[r][c] = *(const float4*)(xin + (size_t)(row0 + r) * 192 + c);
    *(float4*)&Al[r][c] = *(const float4*)(agg + (size_t)(row0 + r) * 64 + c);
  }
  __syncthreads();

  const int r = tid >> 2, c0 = (tid & 3) << 4;
  float acc[16];
#pragma unroll
  for (int j = 0; j < 16; ++j) acc[j] = 0.0f;

#pragma unroll 2
  for (int i = 0; i < 64; ++i) {
    float xv = Xl[r][i], av = Al[r][i];
    fma16(acc, xv, Ws + i * 64 + c0);
    fma16(acc, av, Wn + i * 64 + c0);
  }

  float* op = xout + (size_t)(row0 + r) * 192 + c0;
#pragma unroll
  for (int q = 0; q < 4; ++q) {
    float4 o;
    o.x = fmaxf(acc[q*4+0], 0.0f);
    o.y = fmaxf(acc[q*4+1], 0.0f);
    o.z = fmaxf(acc[q*4+2], 0.0f);
    o.w = fmaxf(acc[q*4+3], 0.0f);
    *(float4*)(op + (q << 2)) = o;
  }
}

// ---------- fused 3-layer MLP + mean over M -> g[N,64] ----------
__global__ __launch_bounds__(256) void mlp_k(const float* __restrict__ xcat,
    const float* __restrict__ W1, const float* __restrict__ b1,
    const float* __restrict__ W2, const float* __restrict__ b2,
    const float* __restrict__ W3, const float* __restrict__ b3,
    float* __restrict__ g) {
  __shared__ float smem[64 * 196];                   // Xl [64][196]; Hl aliases as [64][68]
#define XL(r, i) smem[(r) * 196 + (i)]
#define HL(r, c) smem[(r) * 68 + (c)]
  const int row0 = blockIdx.x << 6;
  const int tid = threadIdx.x;

  const float4* src = (const float4*)(xcat + (size_t)row0 * 192);
  for (int k = tid; k < 3072; k += 256) {            // 64 rows x 48 float4
    float4 v = src[k];
    int r = k / 48, c = (k % 48) << 2;
    *(float4*)&XL(r, c) = v;
  }
  __syncthreads();

  const int r = tid >> 2, c0 = (tid & 3) << 4;
  float acc[16];

  // layer 1: 192 -> 64, relu
#pragma unroll
  for (int j = 0; j < 16; ++j) acc[j] = b1[c0 + j];
#pragma unroll 2
  for (int i = 0; i < 192; ++i)
    fma16(acc, XL(r, i), W1 + i * 64 + c0);
  __syncthreads();                                   // Xl reads done before Hl (alias) writes
#pragma unroll
  for (int j = 0; j < 16; ++j) HL(r, c0 + j) = fmaxf(acc[j], 0.0f);
  __syncthreads();

  // layer 2: 64 -> 64, relu
#pragma unroll
  for (int j = 0; j < 16; ++j) acc[j] = b2[c0 + j];
#pragma unroll 2
  for (int i = 0; i < 64; ++i)
    fma16(acc, HL(r, i), W2 + i * 64 + c0);
  __syncthreads();
#pragma unroll
  for (int j = 0; j < 16; ++j) HL(r, c0 + j) = fmaxf(acc[j], 0.0f);
  __syncthreads();

  // layer 3: 64 -> 64, no relu
#pragma unroll
  for (int j = 0; j < 16; ++j) acc[j] = b3[c0 + j];
#pragma unroll 2
  for (int i = 0; i < 64; ++i)
    fma16(acc, HL(r, i), W3 + i * 64 + c0);
  __syncthreads();
#pragma unroll
  for (int j = 0; j < 16; ++j) HL(r, c0 + j) = acc[j];
  __syncthreads();

  // mean over M=4 rows per node -> g[node, 64]
  for (int k = tid; k < 16 * 64; k += 256) {
    int nl = k >> 6, c = k & 63;
    float s = HL(nl * 4 + 0, c) + HL(nl * 4 + 1, c) + HL(nl * 4 + 2, c) + HL(nl * 4 + 3, c);
    g[(size_t)((row0 >> 2) + nl) * 64 + c] = 0.25f * s;
  }
#undef XL
#undef HL
}

// ---------- global min/max over g ----------
__global__ void minmax_k(const float4* __restrict__ g4, unsigned* __restrict__ mm) {
  const int n4 = NN * 64 / 4;
  float lmin = 3.4e38f, lmax = -3.4e38f;
  for (int idx = blockIdx.x * blockDim.x + threadIdx.x; idx < n4;
       idx += gridDim.x * blockDim.x) {
    float4 v = g4[idx];
    lmin = fminf(lmin, fminf(fminf(v.x, v.y), fminf(v.z, v.w)));
    lmax = fmaxf(lmax, fmaxf(fmaxf(v.x, v.y), fmaxf(v.z, v.w)));
  }
#pragma unroll
  for (int off = 32; off; off >>= 1) {
    lmin = fminf(lmin, __shfl_xor(lmin, off));
    lmax = fmaxf(lmax, __shfl_xor(lmax, off));
  }
  if ((threadIdx.x & 63) == 0) {
    atomicMin(&mm[0], enc_f(lmin));
    atomicMax(&mm[1], enc_f(lmax));
  }
}

// ---------- rescale + pooled[batch[n]] += ----------
__global__ void pool_k(const float* __restrict__ g, const int* __restrict__ batch,
                       const unsigned* __restrict__ mm, float* __restrict__ pooled) {
  int idx = blockIdx.x * blockDim.x + threadIdx.x;   // NN*64
  float gmin = dec_f(mm[0]), gmax = dec_f(mm[1]);
  float sc = 2.0f / (gmax - gmin);
  int n = idx >> 6, c = idx & 63;
  float v = (g[idx] - gmin) * sc;
  unsafeAtomicAdd(&pooled[(batch[n] << 6) + c], v);
}

// ---------- out[b] = pooled[b,:] . Wo + bo ----------
__global__ void out_k(const float* __restrict__ pooled, const float* __restrict__ Wo,
                      const float* __restrict__ bo, float* __restrict__ out) {
  int b = blockIdx.x, l = threadIdx.x;
  float v = pooled[(b << 6) + l] * Wo[l];
#pragma unroll
  for (int off = 32; off; off >>= 1) v += __shfl_xor(v, off);
  if (l == 0) out[b] = v + bo[0];
}

// ---------- launch ----------

extern "C" void kernel_launch(void* const* d_in, const int* in_sizes, int n_in,
                              void* d_out, int out_size, void* d_ws, size_t ws_size,
                              hipStream_t stream) {
  const float* x0   = (const float*)d_in[0];
  const int*   ei   = (const int*)d_in[1];
  const int*   batch= (const int*)d_in[2];
  const float* Ws0  = (const float*)d_in[3];
  const float* Wn0  = (const float*)d_in[4];
  const float* Ws1  = (const float*)d_in[5];
  const float* Wn1  = (const float*)d_in[6];
  const float* Ws2  = (const float*)d_in[7];
  const float* Wn2  = (const float*)d_in[8];
  const float* W1   = (const float*)d_in[9];
  const float* b1   = (const float*)d_in[10];
  const float* W2   = (const float*)d_in[11];
  const float* b2   = (const float*)d_in[12];
  const float* W3   = (const float*)d_in[13];
  const float* b3   = (const float*)d_in[14];
  const float* Wo   = (const float*)d_in[15];
  const float* bo   = (const float*)d_in[16];
  float* out = (float*)d_out;

  float* xcat   = (float*)d_ws;                       // [NROWS,192]
  float* agg    = xcat + (size_t)NROWS * 192;         // [NROWS,64]
  float* agg0   = agg  + (size_t)NROWS * 64;          // [NROWS]
  float* g      = agg0 + NROWS;                       // [NN,64]
  float* pooled = g    + (size_t)NN * 64;             // [BB,64]
  unsigned* mm  = (unsigned*)(pooled + BB * 64);      // [2]

  // layer 0
  hipMemsetAsync(agg0, 0, NROWS * sizeof(float), stream);
  scatter0_k<<<(EE * MM) / 256, 256, 0, stream>>>(x0, ei, agg0);
  conv0_k<<<(NROWS * 64) / 256, 256, 0, stream>>>(x0, agg0, Ws0, Wn0, xcat);

  // layer 1
  hipMemsetAsync(agg, 0, (size_t)NROWS * 64 * sizeof(float), stream);
  scatter64_k<<<(EE * MM * 16) / 256, 256, 0, stream>>>(xcat, ei, agg);
  conv_k<<<NROWS / 64, 256, 0, stream>>>(xcat, agg, Ws1, Wn1, xcat + 64);

  // layer 2
  hipMemsetAsync(agg, 0, (size_t)NROWS * 64 * sizeof(float), stream);
  scatter64_k<<<(EE * MM * 16) / 256, 256, 0, stream>>>(xcat + 64, ei, agg);
  conv_k<<<NROWS / 64, 256, 0, stream>>>(xcat + 64, agg, Ws2, Wn2, xcat + 128);

  // MLP + mean over M
  mlp_k<<<NROWS / 64, 256, 0, stream>>>(xcat, W1, b1, W2, b2, W3, b3, g);

  // global min/max
  hipMemsetAsync(mm, 0xFF, 4, stream);
  hipMemsetAsync(mm + 1, 0x00, 4, stream);
  minmax_k<<<3125, 256, 0, stream>>>((const float4*)g, mm);

  // rescale + pooling
  hipMemsetAsync(pooled, 0, BB * 64 * sizeof(float), stream);
  pool_k<<<(NN * 64) / 256, 256, 0, stream>>>(g, batch, mm, pooled);

  // output linear
  out_k<<<BB, 64, 0, stream>>>(pooled, Wo, bo, out);
}

// Round 2
// 2239.892 us; speedup vs baseline: 2.1493x; 2.1493x over previous
//
#include <hip/hip_runtime.h>
#include <math.h>

#define NN 50000
#define MM 4
#define EE 400000
#define BB 64
#define NROWS (NN*MM)           // 200000
#define NBLK_SCAN 98            // ceil(50000/512)

// ---------- helpers ----------

__device__ __forceinline__ unsigned enc_f(float f) {
  unsigned u = __float_as_uint(f);
  return (u & 0x80000000u) ? ~u : (u | 0x80000000u);
}
__device__ __forceinline__ float dec_f(unsigned u) {
  return (u & 0x80000000u) ? __uint_as_float(u ^ 0x80000000u) : __uint_as_float(~u);
}

__device__ __forceinline__ void fma16(float* acc, float s, const float* w) {
  float4 w0 = *(const float4*)(w + 0);
  float4 w1 = *(const float4*)(w + 4);
  float4 w2 = *(const float4*)(w + 8);
  float4 w3 = *(const float4*)(w + 12);
  acc[0]  += s * w0.x;  acc[1]  += s * w0.y;  acc[2]  += s * w0.z;  acc[3]  += s * w0.w;
  acc[4]  += s * w1.x;  acc[5]  += s * w1.y;  acc[6]  += s * w1.z;  acc[7]  += s * w1.w;
  acc[8]  += s * w2.x;  acc[9]  += s * w2.y;  acc[10] += s * w2.z;  acc[11] += s * w2.w;
  acc[12] += s * w3.x;  acc[13] += s * w3.y;  acc[14] += s * w3.z;  acc[15] += s * w3.w;
}

// ---------- CSR build (dst-major neighbor lists) ----------

__global__ void hist_k(const int* __restrict__ ei, int* __restrict__ deg) {
  int e = blockIdx.x * blockDim.x + threadIdx.x;
  if (e < EE) atomicAdd(&deg[ei[EE + e]], 1);
}

__global__ __launch_bounds__(512) void scan1_k(const int* __restrict__ deg,
                                               int* __restrict__ rowstart,
                                               int* __restrict__ bsum) {
  __shared__ int s[512];
  int i = blockIdx.x * 512 + threadIdx.x;
  int v = (i < NN) ? deg[i] : 0;
  s[threadIdx.x] = v;
  __syncthreads();
  for (int off = 1; off < 512; off <<= 1) {
    int t = (threadIdx.x >= (unsigned)off) ? s[threadIdx.x - off] : 0;
    __syncthreads();
    s[threadIdx.x] += t;
    __syncthreads();
  }
  if (i < NN) rowstart[i] = s[threadIdx.x] - v;      // exclusive partial
  if (threadIdx.x == 511) bsum[blockIdx.x] = s[511];
}

__global__ void scan2_k(int* __restrict__ bsum) {
  if (threadIdx.x == 0) {
    int acc = 0;
    for (int k = 0; k < NBLK_SCAN; ++k) { int t = bsum[k]; bsum[k] = acc; acc += t; }
  }
}

__global__ __launch_bounds__(512) void scan3_k(int* __restrict__ rowstart,
                                               int* __restrict__ cursor,
                                               const int* __restrict__ bsum) {
  int i = blockIdx.x * 512 + threadIdx.x;
  if (i < NN) {
    int v = rowstart[i] + bsum[blockIdx.x];
    rowstart[i] = v;
    cursor[i] = v;
  }
  if (i == 0) rowstart[NN] = EE;
}

__global__ void fill_k(const int* __restrict__ ei, int* __restrict__ cursor,
                       int* __restrict__ nbr) {
  int e = blockIdx.x * blockDim.x + threadIdx.x;
  if (e >= EE) return;
  int d = ei[EE + e];
  int p = atomicAdd(&cursor[d], 1);
  nbr[p] = ei[e];
}

// ---------- gather-based aggregations ----------

// agg0[n*4+m] = sum_{s in N(n)} x0[s*4+m]
__global__ void agg0_gather_k(const float* __restrict__ x0,
                              const int* __restrict__ rowstart,
                              const int* __restrict__ nbr,
                              float* __restrict__ agg0) {
  int idx = blockIdx.x * blockDim.x + threadIdx.x;   // NROWS
  if (idx >= NROWS) return;
  int n = idx >> 2, m = idx & 3;
  int beg = rowstart[n], end = rowstart[n + 1];
  float acc = 0.0f;
  for (int i = beg; i < end; ++i) acc += x0[nbr[i] * 4 + m];
  agg0[idx] = acc;
}

// agg[(n*4+m)*64 + c] = sum_{s in N(n)} xin[(s*4+m)*192 + c]
// one wave per node: lanes = (m 0..3) x (c4 0..15)
__global__ void agg_gather_k(const float* __restrict__ xin,
                             const int* __restrict__ rowstart,
                             const int* __restrict__ nbr,
                             float* __restrict__ agg) {
  int idx = blockIdx.x * blockDim.x + threadIdx.x;   // NN*64
  int c  = (idx & 15) << 2;
  int m  = (idx >> 4) & 3;
  int n  = idx >> 6;
  if (n >= NN) return;
  int beg = rowstart[n], end = rowstart[n + 1];
  float4 acc = {0.0f, 0.0f, 0.0f, 0.0f};
  for (int i = beg; i < end; ++i) {
    int s = nbr[i];
    float4 v = *(const float4*)(xin + (size_t)(s * 4 + m) * 192 + c);
    acc.x += v.x; acc.y += v.y; acc.z += v.z; acc.w += v.w;
  }
  *(float4*)(agg + (size_t)(n * 4 + m) * 64 + c) = acc;
}

// ---------- layer 0 (Din = 1) ----------

__global__ void conv0_k(const float* __restrict__ x0, const float* __restrict__ agg0,
                        const float* __restrict__ Ws0, const float* __restrict__ Wn0,
                        float* __restrict__ xcat) {
  int idx = blockIdx.x * blockDim.x + threadIdx.x;   // NROWS*64
  int row = idx >> 6, h = idx & 63;
  float v = x0[row] * Ws0[h] + agg0[row] * Wn0[h];
  xcat[(size_t)row * 192 + h] = fmaxf(v, 0.0f);
}

// ---------- conv layers 1,2: y = relu(x@Ws + agg@Wn), 64 rows/block ----------

__global__ __launch_bounds__(256) void conv_k(const float* __restrict__ xin,
                                              const float* __restrict__ agg,
                                              const float* __restrict__ Ws,
                                              const float* __restrict__ Wn,
                                              float* __restrict__ xout) {
  __shared__ float Xl[64][68];
  __shared__ float Al[64][68];
  const int row0 = blockIdx.x << 6;
  const int tid = threadIdx.x;

  for (int k = tid; k < 1024; k += 256) {            // 64 rows x 16 float4
    int r = k >> 4, c = (k & 15) << 2;
    *(float4*)&Xl[r][c] = *(const float4*)(xin + (size_t)(row0 + r) * 192 + c);
    *(float4*)&Al[r][c] = *(const float4*)(agg + (size_t)(row0 + r) * 64 + c);
  }
  __syncthreads();

  const int r = tid >> 2, c0 = (tid & 3) << 4;
  float acc[16];
#pragma unroll
  for (int j = 0; j < 16; ++j) acc[j] = 0.0f;

#pragma unroll 2
  for (int i = 0; i < 64; ++i) {
    float xv = Xl[r][i], av = Al[r][i];
    fma16(acc, xv, Ws + i * 64 + c0);
    fma16(acc, av, Wn + i * 64 + c0);
  }

  float* op = xout + (size_t)(row0 + r) * 192 + c0;
#pragma unroll
  for (int q = 0; q < 4; ++q) {
    float4 o;
    o.x = fmaxf(acc[q*4+0], 0.0f);
    o.y = fmaxf(acc[q*4+1], 0.0f);
    o.z = fmaxf(acc[q*4+2], 0.0f);
    o.w = fmaxf(acc[q*4+3], 0.0f);
    *(float4*)(op + (q << 2)) = o;
  }
}

// ---------- fused 3-layer MLP + mean over M -> g[N,64] ----------

__global__ __launch_bounds__(256) void mlp_k(const float* __restrict__ xcat,
    const float* __restrict__ W1, const float* __restrict__ b1,
    const float* __restrict__ W2, const float* __restrict__ b2,
    const float* __restrict__ W3, const float* __restrict__ b3,
    float* __restrict__ g) {
  __shared__ float smem[64 * 196];                   // Xl [64][196]; Hl aliases as [64][68]
#define XL(r, i) smem[(r) * 196 + (i)]
#define HL(r, c) smem[(r) * 68 + (c)]
  const int row0 = blockIdx.x << 6;
  const int tid = threadIdx.x;

  const float4* src = (const float4*)(xcat + (size_t)row0 * 192);
  for (int k = tid; k < 3072; k += 256) {            // 64 rows x 48 float4
    float4 v = src[k];
    int r = k / 48, c = (k % 48) << 2;
    *(float4*)&XL(r, c) = v;
  }
  __syncthreads();

  const int r = tid >> 2, c0 = (tid & 3) << 4;
  float acc[16];

  // layer 1: 192 -> 64, relu
#pragma unroll
  for (int j = 0; j < 16; ++j) acc[j] = b1[c0 + j];
#pragma unroll 2
  for (int i = 0; i < 192; ++i)
    fma16(acc, XL(r, i), W1 + i * 64 + c0);
  __syncthreads();                                   // Xl reads done before Hl (alias) writes
#pragma unroll
  for (int j = 0; j < 16; ++j) HL(r, c0 + j) = fmaxf(acc[j], 0.0f);
  __syncthreads();

  // layer 2: 64 -> 64, relu
#pragma unroll
  for (int j = 0; j < 16; ++j) acc[j] = b2[c0 + j];
#pragma unroll 2
  for (int i = 0; i < 64; ++i)
    fma16(acc, HL(r, i), W2 + i * 64 + c0);
  __syncthreads();
#pragma unroll
  for (int j = 0; j < 16; ++j) HL(r, c0 + j) = fmaxf(acc[j], 0.0f);
  __syncthreads();

  // layer 3: 64 -> 64, no relu
#pragma unroll
  for (int j = 0; j < 16; ++j) acc[j] = b3[c0 + j];
#pragma unroll 2
  for (int i = 0; i < 64; ++i)
    fma16(acc, HL(r, i), W3 + i * 64 + c0);
  __syncthreads();
#pragma unroll
  for (int j = 0; j < 16; ++j) HL(r, c0 + j) = acc[j];
  __syncthreads();

  // mean over M=4 rows per node -> g[node, 64]
  for (int k = tid; k < 16 * 64; k += 256) {
    int nl = k >> 6, c = k & 63;
    float s = HL(nl * 4 + 0, c) + HL(nl * 4 + 1, c) + HL(nl * 4 + 2, c) + HL(nl * 4 + 3, c);
    g[(size_t)((row0 >> 2) + nl) * 64 + c] = 0.25f * s;
  }
#undef XL
#undef HL
}

// ---------- global min/max over g ----------

__global__ void minmax_k(const float4* __restrict__ g4, unsigned* __restrict__ mm) {
  const int n4 = NN * 64 / 4;
  float lmin = 3.4e38f, lmax = -3.4e38f;
  for (int idx = blockIdx.x * blockDim.x + threadIdx.x; idx < n4;
       idx += gridDim.x * blockDim.x) {
    float4 v = g4[idx];
    lmin = fminf(lmin, fminf(fminf(v.x, v.y), fminf(v.z, v.w)));
    lmax = fmaxf(lmax, fmaxf(fmaxf(v.x, v.y), fmaxf(v.z, v.w)));
  }
#pragma unroll
  for (int off = 32; off; off >>= 1) {
    lmin = fminf(lmin, __shfl_xor(lmin, off));
    lmax = fmaxf(lmax, __shfl_xor(lmax, off));
  }
  if ((threadIdx.x & 63) == 0) {
    atomicMin(&mm[0], enc_f(lmin));
    atomicMax(&mm[1], enc_f(lmax));
  }
}

// ---------- rescale + pool (sorted batch -> run-length accumulate) ----------

__global__ __launch_bounds__(256) void pool2_k(const float* __restrict__ g,
                                               const int* __restrict__ batch,
                                               const unsigned* __restrict__ mm,
                                               float* __restrict__ pooled) {
  int c = threadIdx.x & 63;
  int grp = threadIdx.x >> 6;                        // 0..3
  int base = blockIdx.x * 64 + grp * 16;             // 16 consecutive nodes per group
  float gmin = dec_f(mm[0]);
  float sc = 2.0f / (dec_f(mm[1]) - gmin);
  float acc = 0.0f; int cur = -1;
  for (int i = 0; i < 16; ++i) {
    int n = base + i;
    if (n >= NN) break;
    int b = batch[n];
    if (b != cur) {
      if (cur >= 0) unsafeAtomicAdd(&pooled[(cur << 6) + c], acc);
      cur = b; acc = 0.0f;
    }
    acc += (g[(size_t)n * 64 + c] - gmin) * sc;
  }
  if (cur >= 0) unsafeAtomicAdd(&pooled[(cur << 6) + c], acc);
}

// ---------- out[b] = pooled[b,:] . Wo + bo ----------

__global__ void out_k(const float* __restrict__ pooled, const float* __restrict__ Wo,
                      const float* __restrict__ bo, float* __restrict__ out) {
  int b = blockIdx.x, l = threadIdx.x;
  float v = pooled[(b << 6) + l] * Wo[l];
#pragma unroll
  for (int off = 32; off; off >>= 1) v += __shfl_xor(v, off);
  if (l == 0) out[b] = v + bo[0];
}

// ---------- launch ----------

extern "C" void kernel_launch(void* const* d_in, const int* in_sizes, int n_in,
                              void* d_out, int out_size, void* d_ws, size_t ws_size,
                              hipStream_t stream) {
  const float* x0   = (const float*)d_in[0];
  const int*   ei   = (const int*)d_in[1];
  const int*   batch= (const int*)d_in[2];
  const float* Ws0  = (const float*)d_in[3];
  const float* Wn0  = (const float*)d_in[4];
  const float* Ws1  = (const float*)d_in[5];
  const float* Wn1  = (const float*)d_in[6];
  const float* Ws2  = (const float*)d_in[7];
  const float* Wn2  = (const float*)d_in[8];
  const float* W1   = (const float*)d_in[9];
  const float* b1   = (const float*)d_in[10];
  const float* W2   = (const float*)d_in[11];
  const float* b2   = (const float*)d_in[12];
  const float* W3   = (const float*)d_in[13];
  const float* b3   = (const float*)d_in[14];
  const float* Wo   = (const float*)d_in[15];
  const float* bo   = (const float*)d_in[16];
  float* out = (float*)d_out;

  float* xcat   = (float*)d_ws;                       // [NROWS,192]
  float* agg    = xcat + (size_t)NROWS * 192;         // [NROWS,64]
  float* agg0   = agg  + (size_t)NROWS * 64;          // [NROWS]
  float* g      = agg0 + NROWS;                       // [NN,64]
  float* pooled = g    + (size_t)NN * 64;             // [BB,64]
  unsigned* mm  = (unsigned*)(pooled + BB * 64);      // [2]
  int* deg      = (int*)(mm + 2);                     // [NN]
  int* rowstart = deg + NN;                           // [NN+1]
  int* cursor   = rowstart + NN + 1;                  // [NN]
  int* nbr      = cursor + NN;                        // [EE]
  int* bsum     = nbr + EE;                           // [NBLK_SCAN]

  // ---- CSR build ----
  hipMemsetAsync(deg, 0, NN * sizeof(int), stream);
  hist_k<<<(EE + 255) / 256, 256, 0, stream>>>(ei, deg);
  scan1_k<<<NBLK_SCAN, 512, 0, stream>>>(deg, rowstart, bsum);
  scan2_k<<<1, 64, 0, stream>>>(bsum);
  scan3_k<<<NBLK_SCAN, 512, 0, stream>>>(rowstart, cursor, bsum);
  fill_k<<<(EE + 255) / 256, 256, 0, stream>>>(ei, cursor, nbr);

  // ---- layer 0 ----
  agg0_gather_k<<<(NROWS + 255) / 256, 256, 0, stream>>>(x0, rowstart, nbr, agg0);
  conv0_k<<<(NROWS * 64) / 256, 256, 0, stream>>>(x0, agg0, Ws0, Wn0, xcat);

  // ---- layer 1 ----
  agg_gather_k<<<(NN * 64) / 256, 256, 0, stream>>>(xcat, rowstart, nbr, agg);
  conv_k<<<NROWS / 64, 256, 0, stream>>>(xcat, agg, Ws1, Wn1, xcat + 64);

  // ---- layer 2 ----
  agg_gather_k<<<(NN * 64) / 256, 256, 0, stream>>>(xcat + 64, rowstart, nbr, agg);
  conv_k<<<NROWS / 64, 256, 0, stream>>>(xcat + 64, agg, Ws2, Wn2, xcat + 128);

  // ---- MLP + mean over M ----
  mlp_k<<<NROWS / 64, 256, 0, stream>>>(xcat, W1, b1, W2, b2, W3, b3, g);

  // ---- global min/max ----
  hipMemsetAsync(mm, 0xFF, 4, stream);
  hipMemsetAsync(mm + 1, 0x00, 4, stream);
  minmax_k<<<3125, 256, 0, stream>>>((const float4*)g, mm);

  // ---- rescale + pooling ----
  hipMemsetAsync(pooled, 0, BB * 64 * sizeof(float), stream);
  pool2_k<<<(NN + 63) / 64, 256, 0, stream>>>(g, batch, mm, pooled);

  // ---- output linear ----
  out_k<<<BB, 64, 0, stream>>>(pooled, Wo, bo, out);
}

// Round 3
// 516.625 us; speedup vs baseline: 9.3187x; 4.3356x over previous
//
#include <hip/hip_runtime.h>
#include <math.h>

#define NN 50000
#define MM 4
#define EE 400000
#define BB 64
#define NROWS (NN*MM)           // 200000
#define NBLK_SCAN 98            // ceil(50000/512)

// ---------- helpers ----------

__device__ __forceinline__ unsigned enc_f(float f) {
  unsigned u = __float_as_uint(f);
  return (u & 0x80000000u) ? ~u : (u | 0x80000000u);
}
__device__ __forceinline__ float dec_f(unsigned u) {
  return (u & 0x80000000u) ? __uint_as_float(u ^ 0x80000000u) : __uint_as_float(~u);
}

__device__ __forceinline__ void fma16(float* acc, float s, const float* w) {
  float4 w0 = *(const float4*)(w + 0);
  float4 w1 = *(const float4*)(w + 4);
  float4 w2 = *(const float4*)(w + 8);
  float4 w3 = *(const float4*)(w + 12);
  acc[0]  += s * w0.x;  acc[1]  += s * w0.y;  acc[2]  += s * w0.z;  acc[3]  += s * w0.w;
  acc[4]  += s * w1.x;  acc[5]  += s * w1.y;  acc[6]  += s * w1.z;  acc[7]  += s * w1.w;
  acc[8]  += s * w2.x;  acc[9]  += s * w2.y;  acc[10] += s * w2.z;  acc[11] += s * w2.w;
  acc[12] += s * w3.x;  acc[13] += s * w3.y;  acc[14] += s * w3.z;  acc[15] += s * w3.w;
}

// ---------- CSR build (dst-major neighbor lists) ----------

__global__ void hist_k(const int* __restrict__ ei, int* __restrict__ deg) {
  int e = blockIdx.x * blockDim.x + threadIdx.x;
  if (e < EE) atomicAdd(&deg[ei[EE + e]], 1);
}

__global__ __launch_bounds__(512) void scan1_k(const int* __restrict__ deg,
                                               int* __restrict__ rowstart,
                                               int* __restrict__ bsum) {
  __shared__ int s[512];
  int i = blockIdx.x * 512 + threadIdx.x;
  int v = (i < NN) ? deg[i] : 0;
  s[threadIdx.x] = v;
  __syncthreads();
  for (int off = 1; off < 512; off <<= 1) {
    int t = (threadIdx.x >= (unsigned)off) ? s[threadIdx.x - off] : 0;
    __syncthreads();
    s[threadIdx.x] += t;
    __syncthreads();
  }
  if (i < NN) rowstart[i] = s[threadIdx.x] - v;      // exclusive partial
  if (threadIdx.x == 511) bsum[blockIdx.x] = s[511];
}

__global__ void scan2_k(int* __restrict__ bsum) {
  if (threadIdx.x == 0) {
    int acc = 0;
    for (int k = 0; k < NBLK_SCAN; ++k) { int t = bsum[k]; bsum[k] = acc; acc += t; }
  }
}

__global__ __launch_bounds__(512) void scan3_k(int* __restrict__ rowstart,
                                               int* __restrict__ cursor,
                                               const int* __restrict__ bsum) {
  int i = blockIdx.x * 512 + threadIdx.x;
  if (i < NN) {
    int v = rowstart[i] + bsum[blockIdx.x];
    rowstart[i] = v;
    cursor[i] = v;
  }
  if (i == 0) rowstart[NN] = EE;
}

__global__ void fill_k(const int* __restrict__ ei, int* __restrict__ cursor,
                       int* __restrict__ nbr) {
  int e = blockIdx.x * blockDim.x + threadIdx.x;
  if (e >= EE) return;
  int d = ei[EE + e];
  int p = atomicAdd(&cursor[d], 1);
  nbr[p] = ei[e];
}

// ---------- gather-based aggregations ----------

__global__ void agg0_gather_k(const float* __restrict__ x0,
                              const int* __restrict__ rowstart,
                              const int* __restrict__ nbr,
                              float* __restrict__ agg0) {
  int idx = blockIdx.x * blockDim.x + threadIdx.x;   // NROWS
  if (idx >= NROWS) return;
  int n = idx >> 2, m = idx & 3;
  int beg = rowstart[n], end = rowstart[n + 1];
  float acc = 0.0f;
  for (int i = beg; i < end; ++i) acc += x0[nbr[i] * 4 + m];
  agg0[idx] = acc;
}

// agg[(n*4+m)*64 + c] = sum_{s in N(n)} xin[(s*4+m)*192 + c]
__global__ void agg_gather_k(const float* __restrict__ xin,
                             const int* __restrict__ rowstart,
                             const int* __restrict__ nbr,
                             float* __restrict__ agg) {
  int idx = blockIdx.x * blockDim.x + threadIdx.x;   // NN*64
  int c  = (idx & 15) << 2;
  int m  = (idx >> 4) & 3;
  int n  = idx >> 6;
  if (n >= NN) return;
  int beg = rowstart[n], end = rowstart[n + 1];
  float4 acc = {0.0f, 0.0f, 0.0f, 0.0f};
  for (int i = beg; i < end; ++i) {
    int s = nbr[i];
    float4 v = *(const float4*)(xin + (size_t)(s * 4 + m) * 192 + c);
    acc.x += v.x; acc.y += v.y; acc.z += v.z; acc.w += v.w;
  }
  *(float4*)(agg + (size_t)(n * 4 + m) * 64 + c) = acc;
}

// ---------- layer 0 (Din = 1) ----------

__global__ void conv0_k(const float* __restrict__ x0, const float* __restrict__ agg0,
                        const float* __restrict__ Ws0, const float* __restrict__ Wn0,
                        float* __restrict__ xcat) {
  int idx = blockIdx.x * blockDim.x + threadIdx.x;   // NROWS*64
  int row = idx >> 6, h = idx & 63;
  float v = x0[row] * Ws0[h] + agg0[row] * Wn0[h];
  xcat[(size_t)row * 192 + h] = fmaxf(v, 0.0f);
}

// ---------- conv layers 1,2: y = relu(x@Ws + agg@Wn), 64 rows/block ----------
// Weights staged in LDS; inner loop is LDS-only (no global loads -> no vmcnt stall)

__global__ __launch_bounds__(256, 4) void conv_k(const float* __restrict__ xin,
                                                 const float* __restrict__ agg,
                                                 const float* __restrict__ Ws,
                                                 const float* __restrict__ Wn,
                                                 float* __restrict__ xout) {
  __shared__ float Xl[64][68];   // +4 pad: row reads spread banks
  __shared__ float Wl[64][64];   // broadcast reads, no pad needed
  const int row0 = blockIdx.x << 6;
  const int tid = threadIdx.x;
  const int r = tid >> 2, c0 = (tid & 3) << 4;
  float acc[16];
#pragma unroll
  for (int j = 0; j < 16; ++j) acc[j] = 0.0f;

  // phase A: self term (X @ Ws)
  for (int k = tid; k < 1024; k += 256) {
    int rr = k >> 4, cc = (k & 15) << 2;
    *(float4*)&Xl[rr][cc] = *(const float4*)(xin + (size_t)(row0 + rr) * 192 + cc);
    *(float4*)&Wl[rr][cc] = *(const float4*)(Ws + rr * 64 + cc);
  }
  __syncthreads();
#pragma unroll 2
  for (int i = 0; i < 64; i += 4) {
    float4 xv = *(const float4*)&Xl[r][i];
    fma16(acc, xv.x, &Wl[i + 0][c0]);
    fma16(acc, xv.y, &Wl[i + 1][c0]);
    fma16(acc, xv.z, &Wl[i + 2][c0]);
    fma16(acc, xv.w, &Wl[i + 3][c0]);
  }
  __syncthreads();

  // phase B: neighbor term (A @ Wn)
  for (int k = tid; k < 1024; k += 256) {
    int rr = k >> 4, cc = (k & 15) << 2;
    *(float4*)&Xl[rr][cc] = *(const float4*)(agg + (size_t)(row0 + rr) * 64 + cc);
    *(float4*)&Wl[rr][cc] = *(const float4*)(Wn + rr * 64 + cc);
  }
  __syncthreads();
#pragma unroll 2
  for (int i = 0; i < 64; i += 4) {
    float4 xv = *(const float4*)&Xl[r][i];
    fma16(acc, xv.x, &Wl[i + 0][c0]);
    fma16(acc, xv.y, &Wl[i + 1][c0]);
    fma16(acc, xv.z, &Wl[i + 2][c0]);
    fma16(acc, xv.w, &Wl[i + 3][c0]);
  }

  float* op = xout + (size_t)(row0 + r) * 192 + c0;
#pragma unroll
  for (int q = 0; q < 4; ++q) {
    float4 o;
    o.x = fmaxf(acc[q*4+0], 0.0f);
    o.y = fmaxf(acc[q*4+1], 0.0f);
    o.z = fmaxf(acc[q*4+2], 0.0f);
    o.w = fmaxf(acc[q*4+3], 0.0f);
    *(float4*)(op + (q << 2)) = o;
  }
}

// ---------- fused 3-layer MLP + mean over M + global min/max -> g[N,64], mm ----------

__global__ __launch_bounds__(256, 4) void mlp_k(const float* __restrict__ xcat,
    const float* __restrict__ W1, const float* __restrict__ b1,
    const float* __restrict__ W2, const float* __restrict__ b2,
    const float* __restrict__ W3, const float* __restrict__ b3,
    float* __restrict__ g, unsigned* __restrict__ mm) {
  __shared__ float Xl[64][68];
  __shared__ float Wl[64][64];
  __shared__ float red[8];
  const int row0 = blockIdx.x << 6;
  const int tid = threadIdx.x;
  const int r = tid >> 2, c0 = (tid & 3) << 4;
  float acc[16];

  // ---- layer 1: 192 -> 64, K-chunked weight+X staging ----
#pragma unroll
  for (int j = 0; j < 16; ++j) acc[j] = b1[c0 + j];
  for (int kc = 0; kc < 3; ++kc) {
    if (kc) __syncthreads();
    for (int k = tid; k < 1024; k += 256) {
      int rr = k >> 4, cc = (k & 15) << 2;
      *(float4*)&Xl[rr][cc] = *(const float4*)(xcat + (size_t)(row0 + rr) * 192 + kc * 64 + cc);
      *(float4*)&Wl[rr][cc] = *(const float4*)(W1 + (kc * 64 + rr) * 64 + cc);
    }
    __syncthreads();
#pragma unroll 2
    for (int i = 0; i < 64; i += 4) {
      float4 xv = *(const float4*)&Xl[r][i];
      fma16(acc, xv.x, &Wl[i + 0][c0]);
      fma16(acc, xv.y, &Wl[i + 1][c0]);
      fma16(acc, xv.z, &Wl[i + 2][c0]);
      fma16(acc, xv.w, &Wl[i + 3][c0]);
    }
  }

  // ---- layer 2: 64 -> 64 (H lives in Xl) ----
  __syncthreads();
#pragma unroll
  for (int q = 0; q < 4; ++q) {
    float4 h;
    h.x = fmaxf(acc[q*4+0], 0.0f);
    h.y = fmaxf(acc[q*4+1], 0.0f);
    h.z = fmaxf(acc[q*4+2], 0.0f);
    h.w = fmaxf(acc[q*4+3], 0.0f);
    *(float4*)&Xl[r][c0 + (q << 2)] = h;
  }
  for (int k = tid; k < 1024; k += 256) {
    int rr = k >> 4, cc = (k & 15) << 2;
    *(float4*)&Wl[rr][cc] = *(const float4*)(W2 + rr * 64 + cc);
  }
  __syncthreads();
#pragma unroll
  for (int j = 0; j < 16; ++j) acc[j] = b2[c0 + j];
#pragma unroll 2
  for (int i = 0; i < 64; i += 4) {
    float4 xv = *(const float4*)&Xl[r][i];
    fma16(acc, xv.x, &Wl[i + 0][c0]);
    fma16(acc, xv.y, &Wl[i + 1][c0]);
    fma16(acc, xv.z, &Wl[i + 2][c0]);
    fma16(acc, xv.w, &Wl[i + 3][c0]);
  }

  // ---- layer 3: 64 -> 64, no relu ----
  __syncthreads();
#pragma unroll
  for (int q = 0; q < 4; ++q) {
    float4 h;
    h.x = fmaxf(acc[q*4+0], 0.0f);
    h.y = fmaxf(acc[q*4+1], 0.0f);
    h.z = fmaxf(acc[q*4+2], 0.0f);
    h.w = fmaxf(acc[q*4+3], 0.0f);
    *(float4*)&Xl[r][c0 + (q << 2)] = h;
  }
  for (int k = tid; k < 1024; k += 256) {
    int rr = k >> 4, cc = (k & 15) << 2;
    *(float4*)&Wl[rr][cc] = *(const float4*)(W3 + rr * 64 + cc);
  }
  __syncthreads();
#pragma unroll
  for (int j = 0; j < 16; ++j) acc[j] = b3[c0 + j];
#pragma unroll 2
  for (int i = 0; i < 64; i += 4) {
    float4 xv = *(const float4*)&Xl[r][i];
    fma16(acc, xv.x, &Wl[i + 0][c0]);
    fma16(acc, xv.y, &Wl[i + 1][c0]);
    fma16(acc, xv.z, &Wl[i + 2][c0]);
    fma16(acc, xv.w, &Wl[i + 3][c0]);
  }

  // ---- mean over M + per-block min/max ----
  __syncthreads();
#pragma unroll
  for (int q = 0; q < 4; ++q)
    *(float4*)&Xl[r][c0 + (q << 2)] = *(float4*)&acc[q << 2];
  __syncthreads();

  float lmin = 3.4e38f, lmax = -3.4e38f;
  for (int k = tid; k < 1024; k += 256) {
    int nl = k >> 6, c = k & 63;
    float s = 0.25f * (Xl[4*nl][c] + Xl[4*nl+1][c] + Xl[4*nl+2][c] + Xl[4*nl+3][c]);
    g[(size_t)((row0 >> 2) + nl) * 64 + c] = s;
    lmin = fminf(lmin, s);
    lmax = fmaxf(lmax, s);
  }
#pragma unroll
  for (int off = 32; off; off >>= 1) {
    lmin = fminf(lmin, __shfl_xor(lmin, off));
    lmax = fmaxf(lmax, __shfl_xor(lmax, off));
  }
  if ((tid & 63) == 0) { red[tid >> 6] = lmin; red[4 + (tid >> 6)] = lmax; }
  __syncthreads();
  if (tid == 0) {
    float m0 = fminf(fminf(red[0], red[1]), fminf(red[2], red[3]));
    float m1 = fmaxf(fmaxf(red[4], red[5]), fmaxf(red[6], red[7]));
    atomicMin(&mm[0], enc_f(m0));
    atomicMax(&mm[1], enc_f(m1));
  }
}

// ---------- rescale + pool (sorted batch -> run-length accumulate) ----------

__global__ __launch_bounds__(256) void pool2_k(const float* __restrict__ g,
                                               const int* __restrict__ batch,
                                               const unsigned* __restrict__ mm,
                                               float* __restrict__ pooled) {
  int c = threadIdx.x & 63;
  int grp = threadIdx.x >> 6;                        // 0..3
  int base = blockIdx.x * 64 + grp * 16;             // 16 consecutive nodes per group
  float gmin = dec_f(mm[0]);
  float sc = 2.0f / (dec_f(mm[1]) - gmin);
  float acc = 0.0f; int cur = -1;
  for (int i = 0; i < 16; ++i) {
    int n = base + i;
    if (n >= NN) break;
    int b = batch[n];
    if (b != cur) {
      if (cur >= 0) unsafeAtomicAdd(&pooled[(cur << 6) + c], acc);
      cur = b; acc = 0.0f;
    }
    acc += (g[(size_t)n * 64 + c] - gmin) * sc;
  }
  if (cur >= 0) unsafeAtomicAdd(&pooled[(cur << 6) + c], acc);
}

// ---------- out[b] = pooled[b,:] . Wo + bo ----------

__global__ void out_k(const float* __restrict__ pooled, const float* __restrict__ Wo,
                      const float* __restrict__ bo, float* __restrict__ out) {
  int b = blockIdx.x, l = threadIdx.x;
  float v = pooled[(b << 6) + l] * Wo[l];
#pragma unroll
  for (int off = 32; off; off >>= 1) v += __shfl_xor(v, off);
  if (l == 0) out[b] = v + bo[0];
}

// ---------- launch ----------

extern "C" void kernel_launch(void* const* d_in, const int* in_sizes, int n_in,
                              void* d_out, int out_size, void* d_ws, size_t ws_size,
                              hipStream_t stream) {
  const float* x0   = (const float*)d_in[0];
  const int*   ei   = (const int*)d_in[1];
  const int*   batch= (const int*)d_in[2];
  const float* Ws0  = (const float*)d_in[3];
  const float* Wn0  = (const float*)d_in[4];
  const float* Ws1  = (const float*)d_in[5];
  const float* Wn1  = (const float*)d_in[6];
  const float* Ws2  = (const float*)d_in[7];
  const float* Wn2  = (const float*)d_in[8];
  const float* W1   = (const float*)d_in[9];
  const float* b1   = (const float*)d_in[10];
  const float* W2   = (const float*)d_in[11];
  const float* b2   = (const float*)d_in[12];
  const float* W3   = (const float*)d_in[13];
  const float* b3   = (const float*)d_in[14];
  const float* Wo   = (const float*)d_in[15];
  const float* bo   = (const float*)d_in[16];
  float* out = (float*)d_out;

  float* xcat   = (float*)d_ws;                       // [NROWS,192]
  float* agg    = xcat + (size_t)NROWS * 192;         // [NROWS,64]
  float* agg0   = agg  + (size_t)NROWS * 64;          // [NROWS]
  float* g      = agg0 + NROWS;                       // [NN,64]
  float* pooled = g    + (size_t)NN * 64;             // [BB,64]
  unsigned* mm  = (unsigned*)(pooled + BB * 64);      // [2]
  int* deg      = (int*)(mm + 2);                     // [NN]
  int* rowstart = deg + NN;                           // [NN+1]
  int* cursor   = rowstart + NN + 1;                  // [NN]
  int* nbr      = cursor + NN;                        // [EE]
  int* bsum     = nbr + EE;                           // [NBLK_SCAN]

  // ---- CSR build ----
  hipMemsetAsync(deg, 0, NN * sizeof(int), stream);
  hist_k<<<(EE + 255) / 256, 256, 0, stream>>>(ei, deg);
  scan1_k<<<NBLK_SCAN, 512, 0, stream>>>(deg, rowstart, bsum);
  scan2_k<<<1, 64, 0, stream>>>(bsum);
  scan3_k<<<NBLK_SCAN, 512, 0, stream>>>(rowstart, cursor, bsum);
  fill_k<<<(EE + 255) / 256, 256, 0, stream>>>(ei, cursor, nbr);

  // ---- layer 0 ----
  agg0_gather_k<<<(NROWS + 255) / 256, 256, 0, stream>>>(x0, rowstart, nbr, agg0);
  conv0_k<<<(NROWS * 64) / 256, 256, 0, stream>>>(x0, agg0, Ws0, Wn0, xcat);

  // ---- layer 1 ----
  agg_gather_k<<<(NN * 64) / 256, 256, 0, stream>>>(xcat, rowstart, nbr, agg);
  conv_k<<<NROWS / 64, 256, 0, stream>>>(xcat, agg, Ws1, Wn1, xcat + 64);

  // ---- layer 2 ----
  agg_gather_k<<<(NN * 64) / 256, 256, 0, stream>>>(xcat + 64, rowstart, nbr, agg);
  conv_k<<<NROWS / 64, 256, 0, stream>>>(xcat + 64, agg, Ws2, Wn2, xcat + 128);

  // ---- MLP + mean + min/max (fused) ----
  hipMemsetAsync(mm, 0xFF, 4, stream);
  hipMemsetAsync(mm + 1, 0x00, 4, stream);
  mlp_k<<<NROWS / 64, 256, 0, stream>>>(xcat, W1, b1, W2, b2, W3, b3, g, mm);

  // ---- rescale + pooling ----
  hipMemsetAsync(pooled, 0, BB * 64 * sizeof(float), stream);
  pool2_k<<<(NN + 63) / 64, 256, 0, stream>>>(g, batch, mm, pooled);

  // ---- output linear ----
  out_k<<<BB, 64, 0, stream>>>(pooled, Wo, bo, out);
}

// Round 4
// 474.351 us; speedup vs baseline: 10.1492x; 1.0891x over previous
//
#include <hip/hip_runtime.h>
#include <math.h>

#define NN 50000
#define MM 4
#define EE 400000
#define BB 64
#define NROWS (NN*MM)           // 200000
#define NBLK_SCAN 98            // ceil(50000/512)

// ---------- helpers ----------

__device__ __forceinline__ unsigned enc_f(float f) {
  unsigned u = __float_as_uint(f);
  return (u & 0x80000000u) ? ~u : (u | 0x80000000u);
}
__device__ __forceinline__ float dec_f(unsigned u) {
  return (u & 0x80000000u) ? __uint_as_float(u ^ 0x80000000u) : __uint_as_float(~u);
}

__device__ __forceinline__ void fma16(float* acc, float s, const float* w) {
  float4 w0 = *(const float4*)(w + 0);
  float4 w1 = *(const float4*)(w + 4);
  float4 w2 = *(const float4*)(w + 8);
  float4 w3 = *(const float4*)(w + 12);
  acc[0]  += s * w0.x;  acc[1]  += s * w0.y;  acc[2]  += s * w0.z;  acc[3]  += s * w0.w;
  acc[4]  += s * w1.x;  acc[5]  += s * w1.y;  acc[6]  += s * w1.z;  acc[7]  += s * w1.w;
  acc[8]  += s * w2.x;  acc[9]  += s * w2.y;  acc[10] += s * w2.z;  acc[11] += s * w2.w;
  acc[12] += s * w3.x;  acc[13] += s * w3.y;  acc[14] += s * w3.z;  acc[15] += s * w3.w;
}

// ---------- CSR build (dst-major neighbor lists) ----------

__global__ void hist_k(const int* __restrict__ ei, int* __restrict__ deg) {
  int e = blockIdx.x * blockDim.x + threadIdx.x;
  if (e < EE) atomicAdd(&deg[ei[EE + e]], 1);
}

__global__ __launch_bounds__(512) void scan1_k(const int* __restrict__ deg,
                                               int* __restrict__ rowstart,
                                               int* __restrict__ bsum) {
  __shared__ int s[512];
  int i = blockIdx.x * 512 + threadIdx.x;
  int v = (i < NN) ? deg[i] : 0;
  s[threadIdx.x] = v;
  __syncthreads();
  for (int off = 1; off < 512; off <<= 1) {
    int t = (threadIdx.x >= (unsigned)off) ? s[threadIdx.x - off] : 0;
    __syncthreads();
    s[threadIdx.x] += t;
    __syncthreads();
  }
  if (i < NN) rowstart[i] = s[threadIdx.x] - v;      // exclusive partial
  if (threadIdx.x == 511) bsum[blockIdx.x] = s[511];
}

__global__ void scan2_k(int* __restrict__ bsum) {
  if (threadIdx.x == 0) {
    int acc = 0;
    for (int k = 0; k < NBLK_SCAN; ++k) { int t = bsum[k]; bsum[k] = acc; acc += t; }
  }
}

__global__ __launch_bounds__(512) void scan3_k(int* __restrict__ rowstart,
                                               int* __restrict__ cursor,
                                               const int* __restrict__ bsum) {
  int i = blockIdx.x * 512 + threadIdx.x;
  if (i < NN) {
    int v = rowstart[i] + bsum[blockIdx.x];
    rowstart[i] = v;
    cursor[i] = v;
  }
  if (i == 0) rowstart[NN] = EE;
}

__global__ void fill_k(const int* __restrict__ ei, int* __restrict__ cursor,
                       int* __restrict__ nbr) {
  int e = blockIdx.x * blockDim.x + threadIdx.x;
  if (e >= EE) return;
  int d = ei[EE + e];
  int p = atomicAdd(&cursor[d], 1);
  nbr[p] = ei[e];
}

// ---------- aggregation 0: agg0[n*4+m] = sum_{s in N(n)} x0[s*4+m] ----------

__global__ void agg0_gather_k(const float* __restrict__ x0,
                              const int* __restrict__ rowstart,
                              const int* __restrict__ nbr,
                              float* __restrict__ agg0) {
  int idx = blockIdx.x * blockDim.x + threadIdx.x;   // NROWS
  if (idx >= NROWS) return;
  int n = idx >> 2, m = idx & 3;
  int beg = rowstart[n], end = rowstart[n + 1];
  float acc = 0.0f;
  for (int i = beg; i < end; ++i) acc += x0[nbr[i] * 4 + m];
  agg0[idx] = acc;
}

// ---------- aggregation 1 with conv0 recompute (rank-1, never materialized) ----------
// agg[(n*4+m)*64+c] = sum_{s in N(n)} relu(x0[s*4+m]*Ws0[c] + agg0[s*4+m]*Wn0[c])

__global__ void agg1_gather_k(const float* __restrict__ x0,
                              const float* __restrict__ agg0,
                              const int* __restrict__ rowstart,
                              const int* __restrict__ nbr,
                              const float* __restrict__ Ws0,
                              const float* __restrict__ Wn0,
                              float* __restrict__ agg) {
  int idx = blockIdx.x * blockDim.x + threadIdx.x;   // NN*64
  int c  = (idx & 15) << 2;
  int m  = (idx >> 4) & 3;
  int n  = idx >> 6;
  if (n >= NN) return;
  float4 ws = *(const float4*)(Ws0 + c);
  float4 wn = *(const float4*)(Wn0 + c);
  int beg = rowstart[n], end = rowstart[n + 1];
  float4 acc = {0.0f, 0.0f, 0.0f, 0.0f};
  for (int i = beg; i < end; ++i) {
    int s = nbr[i];
    float xv = x0[s * 4 + m];
    float av = agg0[s * 4 + m];
    acc.x += fmaxf(xv * ws.x + av * wn.x, 0.0f);
    acc.y += fmaxf(xv * ws.y + av * wn.y, 0.0f);
    acc.z += fmaxf(xv * ws.z + av * wn.z, 0.0f);
    acc.w += fmaxf(xv * ws.w + av * wn.w, 0.0f);
  }
  *(float4*)(agg + (size_t)(n * 4 + m) * 64 + c) = acc;
}

// ---------- conv1: x1 = relu(x0feat@Ws1 + agg1@Wn1), x0feat recomputed ----------

__global__ __launch_bounds__(256, 4) void conv1_k(const float* __restrict__ x0,
                                                  const float* __restrict__ agg0,
                                                  const float* __restrict__ Ws0,
                                                  const float* __restrict__ Wn0,
                                                  const float* __restrict__ Ws1,
                                                  const float* __restrict__ Wn1,
                                                  const float* __restrict__ aggin,
                                                  float* __restrict__ x1) {
  __shared__ float Xl[64][68];
  __shared__ float Wl[64][64];
  const int row0 = blockIdx.x << 6;
  const int tid = threadIdx.x;
  const int r = tid >> 2, c0 = (tid & 3) << 4;
  float acc[16];
#pragma unroll
  for (int j = 0; j < 16; ++j) acc[j] = 0.0f;

  // phase A: Xl = recomputed x0feat, Wl = Ws1
  for (int k = tid; k < 1024; k += 256) {
    int rr = k >> 4, cc = (k & 15) << 2;
    float xv = x0[row0 + rr], av = agg0[row0 + rr];
    float4 ws = *(const float4*)(Ws0 + cc);
    float4 wn = *(const float4*)(Wn0 + cc);
    float4 t;
    t.x = fmaxf(xv * ws.x + av * wn.x, 0.0f);
    t.y = fmaxf(xv * ws.y + av * wn.y, 0.0f);
    t.z = fmaxf(xv * ws.z + av * wn.z, 0.0f);
    t.w = fmaxf(xv * ws.w + av * wn.w, 0.0f);
    *(float4*)&Xl[rr][cc] = t;
    *(float4*)&Wl[rr][cc] = *(const float4*)(Ws1 + rr * 64 + cc);
  }
  __syncthreads();
#pragma unroll 2
  for (int i = 0; i < 64; i += 4) {
    float4 xv = *(const float4*)&Xl[r][i];
    fma16(acc, xv.x, &Wl[i + 0][c0]);
    fma16(acc, xv.y, &Wl[i + 1][c0]);
    fma16(acc, xv.z, &Wl[i + 2][c0]);
    fma16(acc, xv.w, &Wl[i + 3][c0]);
  }
  __syncthreads();

  // phase B: Xl = agg1 rows, Wl = Wn1
  for (int k = tid; k < 1024; k += 256) {
    int rr = k >> 4, cc = (k & 15) << 2;
    *(float4*)&Xl[rr][cc] = *(const float4*)(aggin + (size_t)(row0 + rr) * 64 + cc);
    *(float4*)&Wl[rr][cc] = *(const float4*)(Wn1 + rr * 64 + cc);
  }
  __syncthreads();
#pragma unroll 2
  for (int i = 0; i < 64; i += 4) {
    float4 xv = *(const float4*)&Xl[r][i];
    fma16(acc, xv.x, &Wl[i + 0][c0]);
    fma16(acc, xv.y, &Wl[i + 1][c0]);
    fma16(acc, xv.z, &Wl[i + 2][c0]);
    fma16(acc, xv.w, &Wl[i + 3][c0]);
  }

  float* op = x1 + (size_t)(row0 + r) * 64 + c0;
#pragma unroll
  for (int q = 0; q < 4; ++q) {
    float4 o;
    o.x = fmaxf(acc[q*4+0], 0.0f);
    o.y = fmaxf(acc[q*4+1], 0.0f);
    o.z = fmaxf(acc[q*4+2], 0.0f);
    o.w = fmaxf(acc[q*4+3], 0.0f);
    *(float4*)(op + (q << 2)) = o;
  }
}

// ---------- aggregation 2: gather x1 (stride 64) ----------

__global__ void agg_gather_k(const float* __restrict__ xin,
                             const int* __restrict__ rowstart,
                             const int* __restrict__ nbr,
                             float* __restrict__ agg) {
  int idx = blockIdx.x * blockDim.x + threadIdx.x;   // NN*64
  int c  = (idx & 15) << 2;
  int m  = (idx >> 4) & 3;
  int n  = idx >> 6;
  if (n >= NN) return;
  int beg = rowstart[n], end = rowstart[n + 1];
  float4 acc = {0.0f, 0.0f, 0.0f, 0.0f};
  for (int i = beg; i < end; ++i) {
    int s = nbr[i];
    float4 v = *(const float4*)(xin + (size_t)(s * 4 + m) * 64 + c);
    acc.x += v.x; acc.y += v.y; acc.z += v.z; acc.w += v.w;
  }
  *(float4*)(agg + (size_t)(n * 4 + m) * 64 + c) = acc;
}

// ---------- fused conv2 + 3-layer MLP + mean over M + min/max ----------

__global__ __launch_bounds__(256, 3) void fused2_k(const float* __restrict__ x1,
    const float* __restrict__ aggin,
    const float* __restrict__ x0, const float* __restrict__ agg0,
    const float* __restrict__ Ws0, const float* __restrict__ Wn0,
    const float* __restrict__ Ws2, const float* __restrict__ Wn2,
    const float* __restrict__ W1, const float* __restrict__ b1,
    const float* __restrict__ W2, const float* __restrict__ b2,
    const float* __restrict__ W3, const float* __restrict__ b3,
    float* __restrict__ g, unsigned* __restrict__ mm) {
  __shared__ float XA[64][68];   // x1 rows, later hidden
  __shared__ float XB[64][68];   // agg2, then x2
  __shared__ float Wl[64][64];
  __shared__ float red[8];
  const int row0 = blockIdx.x << 6;
  const int tid = threadIdx.x;
  const int r = tid >> 2, c0 = (tid & 3) << 4;
  float acc[16];

#define MACC(XS)                                        \
  _Pragma("unroll 2")                                   \
  for (int i = 0; i < 64; i += 4) {                     \
    float4 xv = *(const float4*)&XS[r][i];              \
    fma16(acc, xv.x, &Wl[i + 0][c0]);                   \
    fma16(acc, xv.y, &Wl[i + 1][c0]);                   \
    fma16(acc, xv.z, &Wl[i + 2][c0]);                   \
    fma16(acc, xv.w, &Wl[i + 3][c0]);                   \
  }

  // ---- conv2 phase A: self term (x1 @ Ws2) ----
  for (int k = tid; k < 1024; k += 256) {
    int rr = k >> 4, cc = (k & 15) << 2;
    *(float4*)&XA[rr][cc] = *(const float4*)(x1 + (size_t)(row0 + rr) * 64 + cc);
    *(float4*)&Wl[rr][cc] = *(const float4*)(Ws2 + rr * 64 + cc);
  }
  __syncthreads();
#pragma unroll
  for (int j = 0; j < 16; ++j) acc[j] = 0.0f;
  MACC(XA);
  __syncthreads();

  // ---- conv2 phase B: neighbor term (agg2 @ Wn2) ----
  for (int k = tid; k < 1024; k += 256) {
    int rr = k >> 4, cc = (k & 15) << 2;
    *(float4*)&XB[rr][cc] = *(const float4*)(aggin + (size_t)(row0 + rr) * 64 + cc);
    *(float4*)&Wl[rr][cc] = *(const float4*)(Wn2 + rr * 64 + cc);
  }
  __syncthreads();
  MACC(XB);
  __syncthreads();

  // ---- x2 = relu(acc) -> XB; stage W1 chunk c (x2 part) ----
#pragma unroll
  for (int q = 0; q < 4; ++q) {
    float4 h;
    h.x = fmaxf(acc[q*4+0], 0.0f);
    h.y = fmaxf(acc[q*4+1], 0.0f);
    h.z = fmaxf(acc[q*4+2], 0.0f);
    h.w = fmaxf(acc[q*4+3], 0.0f);
    *(float4*)&XB[r][c0 + (q << 2)] = h;
  }
  for (int k = tid; k < 1024; k += 256) {
    int rr = k >> 4, cc = (k & 15) << 2;
    *(float4*)&Wl[rr][cc] = *(const float4*)(W1 + (128 + rr) * 64 + cc);
  }
  __syncthreads();
#pragma unroll
  for (int j = 0; j < 16; ++j) acc[j] = b1[c0 + j];
  MACC(XB);
  __syncthreads();

  // ---- MLP l1 chunk b: x1 @ W1[64:128] ----
  for (int k = tid; k < 1024; k += 256) {
    int rr = k >> 4, cc = (k & 15) << 2;
    *(float4*)&Wl[rr][cc] = *(const float4*)(W1 + (64 + rr) * 64 + cc);
  }
  __syncthreads();
  MACC(XA);
  __syncthreads();

  // ---- MLP l1 chunk a: x0feat recomputed into XA, W1[0:64] ----
  for (int k = tid; k < 1024; k += 256) {
    int rr = k >> 4, cc = (k & 15) << 2;
    float xv = x0[row0 + rr], av = agg0[row0 + rr];
    float4 ws = *(const float4*)(Ws0 + cc);
    float4 wn = *(const float4*)(Wn0 + cc);
    float4 t;
    t.x = fmaxf(xv * ws.x + av * wn.x, 0.0f);
    t.y = fmaxf(xv * ws.y + av * wn.y, 0.0f);
    t.z = fmaxf(xv * ws.z + av * wn.z, 0.0f);
    t.w = fmaxf(xv * ws.w + av * wn.w, 0.0f);
    *(float4*)&XA[rr][cc] = t;
    *(float4*)&Wl[rr][cc] = *(const float4*)(W1 + rr * 64 + cc);
  }
  __syncthreads();
  MACC(XA);
  __syncthreads();

  // ---- MLP l2 ----
#pragma unroll
  for (int q = 0; q < 4; ++q) {
    float4 h;
    h.x = fmaxf(acc[q*4+0], 0.0f);
    h.y = fmaxf(acc[q*4+1], 0.0f);
    h.z = fmaxf(acc[q*4+2], 0.0f);
    h.w = fmaxf(acc[q*4+3], 0.0f);
    *(float4*)&XA[r][c0 + (q << 2)] = h;
  }
  for (int k = tid; k < 1024; k += 256) {
    int rr = k >> 4, cc = (k & 15) << 2;
    *(float4*)&Wl[rr][cc] = *(const float4*)(W2 + rr * 64 + cc);
  }
  __syncthreads();
#pragma unroll
  for (int j = 0; j < 16; ++j) acc[j] = b2[c0 + j];
  MACC(XA);
  __syncthreads();

  // ---- MLP l3 (no relu) ----
#pragma unroll
  for (int q = 0; q < 4; ++q) {
    float4 h;
    h.x = fmaxf(acc[q*4+0], 0.0f);
    h.y = fmaxf(acc[q*4+1], 0.0f);
    h.z = fmaxf(acc[q*4+2], 0.0f);
    h.w = fmaxf(acc[q*4+3], 0.0f);
    *(float4*)&XA[r][c0 + (q << 2)] = h;
  }
  for (int k = tid; k < 1024; k += 256) {
    int rr = k >> 4, cc = (k & 15) << 2;
    *(float4*)&Wl[rr][cc] = *(const float4*)(W3 + rr * 64 + cc);
  }
  __syncthreads();
#pragma unroll
  for (int j = 0; j < 16; ++j) acc[j] = b3[c0 + j];
  MACC(XA);
  __syncthreads();

  // ---- mean over M + per-block min/max ----
#pragma unroll
  for (int q = 0; q < 4; ++q)
    *(float4*)&XA[r][c0 + (q << 2)] = *(float4*)&acc[q << 2];
  __syncthreads();

  float lmin = 3.4e38f, lmax = -3.4e38f;
  for (int k = tid; k < 1024; k += 256) {
    int nl = k >> 6, c = k & 63;
    float s = 0.25f * (XA[4*nl][c] + XA[4*nl+1][c] + XA[4*nl+2][c] + XA[4*nl+3][c]);
    g[(size_t)((row0 >> 2) + nl) * 64 + c] = s;
    lmin = fminf(lmin, s);
    lmax = fmaxf(lmax, s);
  }
#pragma unroll
  for (int off = 32; off; off >>= 1) {
    lmin = fminf(lmin, __shfl_xor(lmin, off));
    lmax = fmaxf(lmax, __shfl_xor(lmax, off));
  }
  if ((tid & 63) == 0) { red[tid >> 6] = lmin; red[4 + (tid >> 6)] = lmax; }
  __syncthreads();
  if (tid == 0) {
    float m0 = fminf(fminf(red[0], red[1]), fminf(red[2], red[3]));
    float m1 = fmaxf(fmaxf(red[4], red[5]), fmaxf(red[6], red[7]));
    atomicMin(&mm[0], enc_f(m0));
    atomicMax(&mm[1], enc_f(m1));
  }
#undef MACC
}

// ---------- rescale + pool (sorted batch -> run-length accumulate) ----------

__global__ __launch_bounds__(256) void pool2_k(const float* __restrict__ g,
                                               const int* __restrict__ batch,
                                               const unsigned* __restrict__ mm,
                                               float* __restrict__ pooled) {
  int c = threadIdx.x & 63;
  int grp = threadIdx.x >> 6;                        // 0..3
  int base = blockIdx.x * 64 + grp * 16;             // 16 consecutive nodes per group
  float gmin = dec_f(mm[0]);
  float sc = 2.0f / (dec_f(mm[1]) - gmin);
  float acc = 0.0f; int cur = -1;
  for (int i = 0; i < 16; ++i) {
    int n = base + i;
    if (n >= NN) break;
    int b = batch[n];
    if (b != cur) {
      if (cur >= 0) unsafeAtomicAdd(&pooled[(cur << 6) + c], acc);
      cur = b; acc = 0.0f;
    }
    acc += (g[(size_t)n * 64 + c] - gmin) * sc;
  }
  if (cur >= 0) unsafeAtomicAdd(&pooled[(cur << 6) + c], acc);
}

// ---------- out[b] = pooled[b,:] . Wo + bo ----------

__global__ void out_k(const float* __restrict__ pooled, const float* __restrict__ Wo,
                      const float* __restrict__ bo, float* __restrict__ out) {
  int b = blockIdx.x, l = threadIdx.x;
  float v = pooled[(b << 6) + l] * Wo[l];
#pragma unroll
  for (int off = 32; off; off >>= 1) v += __shfl_xor(v, off);
  if (l == 0) out[b] = v + bo[0];
}

// ---------- launch ----------

extern "C" void kernel_launch(void* const* d_in, const int* in_sizes, int n_in,
                              void* d_out, int out_size, void* d_ws, size_t ws_size,
                              hipStream_t stream) {
  const float* x0   = (const float*)d_in[0];
  const int*   ei   = (const int*)d_in[1];
  const int*   batch= (const int*)d_in[2];
  const float* Ws0  = (const float*)d_in[3];
  const float* Wn0  = (const float*)d_in[4];
  const float* Ws1  = (const float*)d_in[5];
  const float* Wn1  = (const float*)d_in[6];
  const float* Ws2  = (const float*)d_in[7];
  const float* Wn2  = (const float*)d_in[8];
  const float* W1   = (const float*)d_in[9];
  const float* b1   = (const float*)d_in[10];
  const float* W2   = (const float*)d_in[11];
  const float* b2   = (const float*)d_in[12];
  const float* W3   = (const float*)d_in[13];
  const float* b3   = (const float*)d_in[14];
  const float* Wo   = (const float*)d_in[15];
  const float* bo   = (const float*)d_in[16];
  float* out = (float*)d_out;

  float* x1     = (float*)d_ws;                       // [NROWS,64]
  float* agg    = x1   + (size_t)NROWS * 64;          // [NROWS,64]
  float* agg0   = agg  + (size_t)NROWS * 64;          // [NROWS]
  float* g      = agg0 + NROWS;                       // [NN,64]
  float* pooled = g    + (size_t)NN * 64;             // [BB,64]
  unsigned* mm  = (unsigned*)(pooled + BB * 64);      // [2]
  int* deg      = (int*)(mm + 2);                     // [NN]
  int* rowstart = deg + NN;                           // [NN+1]
  int* cursor   = rowstart + NN + 1;                  // [NN]
  int* nbr      = cursor + NN;                        // [EE]
  int* bsum     = nbr + EE;                           // [NBLK_SCAN]

  // ---- CSR build ----
  hipMemsetAsync(deg, 0, NN * sizeof(int), stream);
  hist_k<<<(EE + 255) / 256, 256, 0, stream>>>(ei, deg);
  scan1_k<<<NBLK_SCAN, 512, 0, stream>>>(deg, rowstart, bsum);
  scan2_k<<<1, 64, 0, stream>>>(bsum);
  scan3_k<<<NBLK_SCAN, 512, 0, stream>>>(rowstart, cursor, bsum);
  fill_k<<<(EE + 255) / 256, 256, 0, stream>>>(ei, cursor, nbr);

  // ---- layer 0 aggregate (scalar) ----
  agg0_gather_k<<<(NROWS + 255) / 256, 256, 0, stream>>>(x0, rowstart, nbr, agg0);

  // ---- layer 1: gather with conv0 recompute, then conv1 -> x1 ----
  agg1_gather_k<<<(NN * 64) / 256, 256, 0, stream>>>(x0, agg0, rowstart, nbr, Ws0, Wn0, agg);
  conv1_k<<<NROWS / 64, 256, 0, stream>>>(x0, agg0, Ws0, Wn0, Ws1, Wn1, agg, x1);

  // ---- layer 2 aggregate ----
  agg_gather_k<<<(NN * 64) / 256, 256, 0, stream>>>(x1, rowstart, nbr, agg);

  // ---- fused conv2 + MLP + mean + min/max ----
  hipMemsetAsync(mm, 0xFF, 4, stream);
  hipMemsetAsync(mm + 1, 0x00, 4, stream);
  fused2_k<<<NROWS / 64, 256, 0, stream>>>(x1, agg, x0, agg0, Ws0, Wn0, Ws2, Wn2,
                                           W1, b1, W2, b2, W3, b3, g, mm);

  // ---- rescale + pooling ----
  hipMemsetAsync(pooled, 0, BB * 64 * sizeof(float), stream);
  pool2_k<<<(NN + 63) / 64, 256, 0, stream>>>(g, batch, mm, pooled);

  // ---- output linear ----
  out_k<<<BB, 64, 0, stream>>>(pooled, Wo, bo, out);
}

// Round 5
// 449.220 us; speedup vs baseline: 10.7170x; 1.0559x over previous
//
#include <hip/hip_runtime.h>
#include <math.h>

#define NN 50000
#define MM 4
#define EE 400000
#define BB 64
#define NROWS (NN*MM)           // 200000
#define NBLK_SCAN 98            // ceil(50000/512)

// ---------- helpers ----------

__device__ __forceinline__ unsigned enc_f(float f) {
  unsigned u = __float_as_uint(f);
  return (u & 0x80000000u) ? ~u : (u | 0x80000000u);
}
__device__ __forceinline__ float dec_f(unsigned u) {
  return (u & 0x80000000u) ? __uint_as_float(u ^ 0x80000000u) : __uint_as_float(~u);
}

__device__ __forceinline__ void axpy4(float4& a, float s, float4 w) {
  a.x = fmaf(s, w.x, a.x);
  a.y = fmaf(s, w.y, a.y);
  a.z = fmaf(s, w.z, a.z);
  a.w = fmaf(s, w.w, a.w);
}
__device__ __forceinline__ float4 relu4(float4 v) {
  return make_float4(fmaxf(v.x, 0.f), fmaxf(v.y, 0.f), fmaxf(v.z, 0.f), fmaxf(v.w, 0.f));
}

// 4x4 micro-tiled LDS GEMM step: A[i] (rows r0..r0+3, cols tc4..tc4+3) += XS rows @ Wl
// Per 4 K-steps: 8 ds_read_b128 (vs 17 in 1x16 tiling), 64 FMAs.
#define MACC4(XS, A)                                                  \
  _Pragma("unroll 4")                                                 \
  for (int k = 0; k < 64; k += 4) {                                   \
    float4 xa = *(const float4*)&XS[r0 + 0][k];                       \
    float4 xb = *(const float4*)&XS[r0 + 1][k];                       \
    float4 xc = *(const float4*)&XS[r0 + 2][k];                       \
    float4 xd = *(const float4*)&XS[r0 + 3][k];                       \
    float4 w0 = *(const float4*)&Wl[k + 0][tc4];                      \
    float4 w1 = *(const float4*)&Wl[k + 1][tc4];                      \
    float4 w2 = *(const float4*)&Wl[k + 2][tc4];                      \
    float4 w3 = *(const float4*)&Wl[k + 3][tc4];                      \
    axpy4(A[0], xa.x, w0); axpy4(A[0], xa.y, w1); axpy4(A[0], xa.z, w2); axpy4(A[0], xa.w, w3); \
    axpy4(A[1], xb.x, w0); axpy4(A[1], xb.y, w1); axpy4(A[1], xb.z, w2); axpy4(A[1], xb.w, w3); \
    axpy4(A[2], xc.x, w0); axpy4(A[2], xc.y, w1); axpy4(A[2], xc.z, w2); axpy4(A[2], xc.w, w3); \
    axpy4(A[3], xd.x, w0); axpy4(A[3], xd.y, w1); axpy4(A[3], xd.z, w2); axpy4(A[3], xd.w, w3); \
  }

// ---------- CSR build (dst-major neighbor lists) ----------

__global__ void hist_k(const int* __restrict__ ei, int* __restrict__ deg) {
  int e = blockIdx.x * blockDim.x + threadIdx.x;
  if (e < EE) atomicAdd(&deg[ei[EE + e]], 1);
}

__global__ __launch_bounds__(512) void scan1_k(const int* __restrict__ deg,
                                               int* __restrict__ rowstart,
                                               int* __restrict__ bsum) {
  __shared__ int s[512];
  int i = blockIdx.x * 512 + threadIdx.x;
  int v = (i < NN) ? deg[i] : 0;
  s[threadIdx.x] = v;
  __syncthreads();
  for (int off = 1; off < 512; off <<= 1) {
    int t = (threadIdx.x >= (unsigned)off) ? s[threadIdx.x - off] : 0;
    __syncthreads();
    s[threadIdx.x] += t;
    __syncthreads();
  }
  if (i < NN) rowstart[i] = s[threadIdx.x] - v;      // exclusive partial
  if (threadIdx.x == 511) bsum[blockIdx.x] = s[511];
}

__global__ void scan2_k(int* __restrict__ bsum) {
  if (threadIdx.x == 0) {
    int acc = 0;
    for (int k = 0; k < NBLK_SCAN; ++k) { int t = bsum[k]; bsum[k] = acc; acc += t; }
  }
}

__global__ __launch_bounds__(512) void scan3_k(int* __restrict__ rowstart,
                                               int* __restrict__ cursor,
                                               const int* __restrict__ bsum) {
  int i = blockIdx.x * 512 + threadIdx.x;
  if (i < NN) {
    int v = rowstart[i] + bsum[blockIdx.x];
    rowstart[i] = v;
    cursor[i] = v;
  }
  if (i == 0) rowstart[NN] = EE;
}

__global__ void fill_k(const int* __restrict__ ei, int* __restrict__ cursor,
                       int* __restrict__ nbr) {
  int e = blockIdx.x * blockDim.x + threadIdx.x;
  if (e >= EE) return;
  int d = ei[EE + e];
  int p = atomicAdd(&cursor[d], 1);
  nbr[p] = ei[e];
}

// ---------- aggregation 0: agg0[n*4+m] = sum_{s in N(n)} x0[s*4+m] ----------

__global__ void agg0_gather_k(const float* __restrict__ x0,
                              const int* __restrict__ rowstart,
                              const int* __restrict__ nbr,
                              float* __restrict__ agg0) {
  int idx = blockIdx.x * blockDim.x + threadIdx.x;   // NROWS
  if (idx >= NROWS) return;
  int n = idx >> 2, m = idx & 3;
  int beg = rowstart[n], end = rowstart[n + 1];
  float acc = 0.0f;
  for (int i = beg; i < end; ++i) acc += x0[nbr[i] * 4 + m];
  agg0[idx] = acc;
}

// ---------- aggregation 1 with conv0 recompute (rank-1, never materialized) ----------

__global__ void agg1_gather_k(const float* __restrict__ x0,
                              const float* __restrict__ agg0,
                              const int* __restrict__ rowstart,
                              const int* __restrict__ nbr,
                              const float* __restrict__ Ws0,
                              const float* __restrict__ Wn0,
                              float* __restrict__ agg) {
  int idx = blockIdx.x * blockDim.x + threadIdx.x;   // NN*64
  int c  = (idx & 15) << 2;
  int m  = (idx >> 4) & 3;
  int n  = idx >> 6;
  if (n >= NN) return;
  float4 ws = *(const float4*)(Ws0 + c);
  float4 wn = *(const float4*)(Wn0 + c);
  int beg = rowstart[n], end = rowstart[n + 1];
  float4 acc = {0.0f, 0.0f, 0.0f, 0.0f};
  for (int i = beg; i < end; ++i) {
    int s = nbr[i];
    float xv = x0[s * 4 + m];
    float av = agg0[s * 4 + m];
    acc.x += fmaxf(xv * ws.x + av * wn.x, 0.0f);
    acc.y += fmaxf(xv * ws.y + av * wn.y, 0.0f);
    acc.z += fmaxf(xv * ws.z + av * wn.z, 0.0f);
    acc.w += fmaxf(xv * ws.w + av * wn.w, 0.0f);
  }
  *(float4*)(agg + (size_t)(n * 4 + m) * 64 + c) = acc;
}

// ---------- conv1: x1 = relu(x0feat@Ws1 + agg1@Wn1), 4x4 micro-tile + prefetch ----------

__global__ __launch_bounds__(256, 4) void conv1_k(const float* __restrict__ x0,
                                                  const float* __restrict__ agg0,
                                                  const float* __restrict__ Ws0,
                                                  const float* __restrict__ Wn0,
                                                  const float* __restrict__ Ws1,
                                                  const float* __restrict__ Wn1,
                                                  const float* __restrict__ aggin,
                                                  float* __restrict__ x1) {
  __shared__ float XA[64][68];
  __shared__ float Wl[64][64];
  const int row0 = blockIdx.x << 6;
  const int tid = threadIdx.x;
  const int tc4 = (tid & 15) << 2;   // col offset
  const int tr  = tid >> 4;          // staging row group
  const int r0  = tr << 2;           // compute row offset

  float4 xpre[4], wpre[4];
  float xpv[4], apv[4];

  // prologue: XA <- x0feat (recomputed), Wl <- Ws1
#pragma unroll
  for (int q = 0; q < 4; ++q) {
    xpv[q] = x0[row0 + tr + (q << 4)];
    apv[q] = agg0[row0 + tr + (q << 4)];
    wpre[q] = *(const float4*)(Ws1 + (tr + (q << 4)) * 64 + tc4);
  }
  {
    float4 ws = *(const float4*)(Ws0 + tc4);
    float4 wn = *(const float4*)(Wn0 + tc4);
#pragma unroll
    for (int q = 0; q < 4; ++q) {
      float4 t;
      t.x = fmaxf(xpv[q] * ws.x + apv[q] * wn.x, 0.f);
      t.y = fmaxf(xpv[q] * ws.y + apv[q] * wn.y, 0.f);
      t.z = fmaxf(xpv[q] * ws.z + apv[q] * wn.z, 0.f);
      t.w = fmaxf(xpv[q] * ws.w + apv[q] * wn.w, 0.f);
      *(float4*)&XA[tr + (q << 4)][tc4] = t;
      *(float4*)&Wl[tr + (q << 4)][tc4] = wpre[q];
    }
  }
  // prefetch phase 2: agg1 rows + Wn1
#pragma unroll
  for (int q = 0; q < 4; ++q) {
    xpre[q] = *(const float4*)(aggin + (size_t)(row0 + tr + (q << 4)) * 64 + tc4);
    wpre[q] = *(const float4*)(Wn1 + (tr + (q << 4)) * 64 + tc4);
  }
  __syncthreads();

  float4 acc[4];
  acc[0] = acc[1] = acc[2] = acc[3] = make_float4(0.f, 0.f, 0.f, 0.f);
  MACC4(XA, acc);
  __syncthreads();
#pragma unroll
  for (int q = 0; q < 4; ++q) {
    *(float4*)&XA[tr + (q << 4)][tc4] = xpre[q];
    *(float4*)&Wl[tr + (q << 4)][tc4] = wpre[q];
  }
  __syncthreads();
  MACC4(XA, acc);

#pragma unroll
  for (int i = 0; i < 4; ++i)
    *(float4*)(x1 + (size_t)(row0 + r0 + i) * 64 + tc4) = relu4(acc[i]);
}

// ---------- aggregation 2: gather x1 (stride 64) ----------

__global__ void agg_gather_k(const float* __restrict__ xin,
                             const int* __restrict__ rowstart,
                             const int* __restrict__ nbr,
                             float* __restrict__ agg) {
  int idx = blockIdx.x * blockDim.x + threadIdx.x;   // NN*64
  int c  = (idx & 15) << 2;
  int m  = (idx >> 4) & 3;
  int n  = idx >> 6;
  if (n >= NN) return;
  int beg = rowstart[n], end = rowstart[n + 1];
  float4 acc = {0.0f, 0.0f, 0.0f, 0.0f};
  for (int i = beg; i < end; ++i) {
    int s = nbr[i];
    float4 v = *(const float4*)(xin + (size_t)(s * 4 + m) * 64 + c);
    acc.x += v.x; acc.y += v.y; acc.z += v.z; acc.w += v.w;
  }
  *(float4*)(agg + (size_t)(n * 4 + m) * 64 + c) = acc;
}

// ---------- fused conv2 + 3-layer MLP + mean over M + min/max ----------
// 4x4 micro-tile, W/X prefetched to registers during previous MACC (T14).

__global__ __launch_bounds__(256, 3) void fused2_k(const float* __restrict__ x1,
    const float* __restrict__ aggin,
    const float* __restrict__ x0, const float* __restrict__ agg0,
    const float* __restrict__ Ws0, const float* __restrict__ Wn0,
    const float* __restrict__ Ws2, const float* __restrict__ Wn2,
    const float* __restrict__ W1, const float* __restrict__ b1,
    const float* __restrict__ W2, const float* __restrict__ b2,
    const float* __restrict__ W3, const float* __restrict__ b3,
    float* __restrict__ g, unsigned* __restrict__ mm) {
  __shared__ float XA[64][68];   // x1 (P1,P4), then x0f (P5), then h1/h2/h3
  __shared__ float XB[64][68];   // agg2 (P2), then x2 (P3)
  __shared__ float Wl[64][64];
  __shared__ float red[8];
  const int row0 = blockIdx.x << 6;
  const int tid = threadIdx.x;
  const int tc4 = (tid & 15) << 2;
  const int tr  = tid >> 4;
  const int r0  = tr << 2;

  float4 xpre[4], wpre[4];
  float xpv[4], apv[4];
  float4 acc1[4], acc2[4];

  // ---- prologue: XA <- x1, Wl <- Ws2; prefetch agg2 + Wn2 ----
#pragma unroll
  for (int q = 0; q < 4; ++q) {
    xpre[q] = *(const float4*)(x1 + (size_t)(row0 + tr + (q << 4)) * 64 + tc4);
    wpre[q] = *(const float4*)(Ws2 + (tr + (q << 4)) * 64 + tc4);
  }
#pragma unroll
  for (int q = 0; q < 4; ++q) {
    *(float4*)&XA[tr + (q << 4)][tc4] = xpre[q];
    *(float4*)&Wl[tr + (q << 4)][tc4] = wpre[q];
  }
#pragma unroll
  for (int q = 0; q < 4; ++q) {
    xpre[q] = *(const float4*)(aggin + (size_t)(row0 + tr + (q << 4)) * 64 + tc4);
    wpre[q] = *(const float4*)(Wn2 + (tr + (q << 4)) * 64 + tc4);
  }
  __syncthreads();

  // ---- P1: conv2 self term: x1 @ Ws2 ----
  acc1[0] = acc1[1] = acc1[2] = acc1[3] = make_float4(0.f, 0.f, 0.f, 0.f);
  MACC4(XA, acc1);
  __syncthreads();
#pragma unroll
  for (int q = 0; q < 4; ++q) {                      // commit XB=agg2, Wl=Wn2
    *(float4*)&XB[tr + (q << 4)][tc4] = xpre[q];
    *(float4*)&Wl[tr + (q << 4)][tc4] = wpre[q];
  }
#pragma unroll
  for (int q = 0; q < 4; ++q)                        // prefetch W1c (rows 128..191)
    wpre[q] = *(const float4*)(W1 + (128 + tr + (q << 4)) * 64 + tc4);
  __syncthreads();

  // ---- P2: conv2 neighbor term: agg2 @ Wn2 ----
  MACC4(XB, acc1);
  __syncthreads();
#pragma unroll
  for (int i = 0; i < 4; ++i)                        // x2 = relu -> XB
    *(float4*)&XB[r0 + i][tc4] = relu4(acc1[i]);
#pragma unroll
  for (int q = 0; q < 4; ++q)
    *(float4*)&Wl[tr + (q << 4)][tc4] = wpre[q];     // commit W1c
#pragma unroll
  for (int q = 0; q < 4; ++q)                        // prefetch W1b (rows 64..127)
    wpre[q] = *(const float4*)(W1 + (64 + tr + (q << 4)) * 64 + tc4);
  __syncthreads();

  // ---- P3: x2 @ W1c ----
  {
    float4 bb = *(const float4*)(b1 + tc4);
    acc2[0] = acc2[1] = acc2[2] = acc2[3] = bb;
  }
  MACC4(XB, acc2);
  __syncthreads();
#pragma unroll
  for (int q = 0; q < 4; ++q)
    *(float4*)&Wl[tr + (q << 4)][tc4] = wpre[q];     // commit W1b
#pragma unroll
  for (int q = 0; q < 4; ++q) {                      // prefetch x0f scalars + W1a
    xpv[q] = x0[row0 + tr + (q << 4)];
    apv[q] = agg0[row0 + tr + (q << 4)];
    wpre[q] = *(const float4*)(W1 + (tr + (q << 4)) * 64 + tc4);
  }
  __syncthreads();

  // ---- P4: x1 @ W1b (XA still holds x1) ----
  MACC4(XA, acc2);
  __syncthreads();
  {
    float4 ws = *(const float4*)(Ws0 + tc4);
    float4 wn = *(const float4*)(Wn0 + tc4);
#pragma unroll
    for (int q = 0; q < 4; ++q) {                    // commit XA = x0feat, Wl = W1a
      float4 t;
      t.x = fmaxf(xpv[q] * ws.x + apv[q] * wn.x, 0.f);
      t.y = fmaxf(xpv[q] * ws.y + apv[q] * wn.y, 0.f);
      t.z = fmaxf(xpv[q] * ws.z + apv[q] * wn.z, 0.f);
      t.w = fmaxf(xpv[q] * ws.w + apv[q] * wn.w, 0.f);
      *(float4*)&XA[tr + (q << 4)][tc4] = t;
      *(float4*)&Wl[tr + (q << 4)][tc4] = wpre[q];
    }
  }
#pragma unroll
  for (int q = 0; q < 4; ++q)                        // prefetch W2
    wpre[q] = *(const float4*)(W2 + (tr + (q << 4)) * 64 + tc4);
  __syncthreads();

  // ---- P5: x0f @ W1a ----
  MACC4(XA, acc2);
  __syncthreads();
#pragma unroll
  for (int i = 0; i < 4; ++i)                        // h1 = relu -> XA
    *(float4*)&XA[r0 + i][tc4] = relu4(acc2[i]);
#pragma unroll
  for (int q = 0; q < 4; ++q)
    *(float4*)&Wl[tr + (q << 4)][tc4] = wpre[q];     // commit W2
#pragma unroll
  for (int q = 0; q < 4; ++q)                        // prefetch W3
    wpre[q] = *(const float4*)(W3 + (tr + (q << 4)) * 64 + tc4);
  __syncthreads();

  // ---- P6: h1 @ W2 ----
  {
    float4 bb = *(const float4*)(b2 + tc4);
    acc1[0] = acc1[1] = acc1[2] = acc1[3] = bb;
  }
  MACC4(XA, acc1);
  __syncthreads();
#pragma unroll
  for (int i = 0; i < 4; ++i)                        // h2 = relu -> XA
    *(float4*)&XA[r0 + i][tc4] = relu4(acc1[i]);
#pragma unroll
  for (int q = 0; q < 4; ++q)
    *(float4*)&Wl[tr + (q << 4)][tc4] = wpre[q];     // commit W3
  __syncthreads();

  // ---- P7: h2 @ W3 (no relu) ----
  {
    float4 bb = *(const float4*)(b3 + tc4);
    acc2[0] = acc2[1] = acc2[2] = acc2[3] = bb;
  }
  MACC4(XA, acc2);
  __syncthreads();
#pragma unroll
  for (int i = 0; i < 4; ++i)
    *(float4*)&XA[r0 + i][tc4] = acc2[i];            // h3 -> XA
  __syncthreads();

  // ---- mean over M + per-block min/max ----
  float lmin = 3.4e38f, lmax = -3.4e38f;
  for (int k = tid; k < 1024; k += 256) {
    int nl = k >> 6, c = k & 63;
    float s = 0.25f * (XA[4*nl][c] + XA[4*nl+1][c] + XA[4*nl+2][c] + XA[4*nl+3][c]);
    g[(size_t)((row0 >> 2) + nl) * 64 + c] = s;
    lmin = fminf(lmin, s);
    lmax = fmaxf(lmax, s);
  }
#pragma unroll
  for (int off = 32; off; off >>= 1) {
    lmin = fminf(lmin, __shfl_xor(lmin, off));
    lmax = fmaxf(lmax, __shfl_xor(lmax, off));
  }
  if ((tid & 63) == 0) { red[tid >> 6] = lmin; red[4 + (tid >> 6)] = lmax; }
  __syncthreads();
  if (tid == 0) {
    float m0 = fminf(fminf(red[0], red[1]), fminf(red[2], red[3]));
    float m1 = fmaxf(fmaxf(red[4], red[5]), fmaxf(red[6], red[7]));
    atomicMin(&mm[0], enc_f(m0));
    atomicMax(&mm[1], enc_f(m1));
  }
}

// ---------- rescale + pool (sorted batch -> run-length accumulate) ----------

__global__ __launch_bounds__(256) void pool2_k(const float* __restrict__ g,
                                               const int* __restrict__ batch,
                                               const unsigned* __restrict__ mm,
                                               float* __restrict__ pooled) {
  int c = threadIdx.x & 63;
  int grp = threadIdx.x >> 6;                        // 0..3
  int base = blockIdx.x * 64 + grp * 16;             // 16 consecutive nodes per group
  float gmin = dec_f(mm[0]);
  float sc = 2.0f / (dec_f(mm[1]) - gmin);
  float acc = 0.0f; int cur = -1;
  for (int i = 0; i < 16; ++i) {
    int n = base + i;
    if (n >= NN) break;
    int b = batch[n];
    if (b != cur) {
      if (cur >= 0) unsafeAtomicAdd(&pooled[(cur << 6) + c], acc);
      cur = b; acc = 0.0f;
    }
    acc += (g[(size_t)n * 64 + c] - gmin) * sc;
  }
  if (cur >= 0) unsafeAtomicAdd(&pooled[(cur << 6) + c], acc);
}

// ---------- out[b] = pooled[b,:] . Wo + bo ----------

__global__ void out_k(const float* __restrict__ pooled, const float* __restrict__ Wo,
                      const float* __restrict__ bo, float* __restrict__ out) {
  int b = blockIdx.x, l = threadIdx.x;
  float v = pooled[(b << 6) + l] * Wo[l];
#pragma unroll
  for (int off = 32; off; off >>= 1) v += __shfl_xor(v, off);
  if (l == 0) out[b] = v + bo[0];
}

// ---------- launch ----------

extern "C" void kernel_launch(void* const* d_in, const int* in_sizes, int n_in,
                              void* d_out, int out_size, void* d_ws, size_t ws_size,
                              hipStream_t stream) {
  const float* x0   = (const float*)d_in[0];
  const int*   ei   = (const int*)d_in[1];
  const int*   batch= (const int*)d_in[2];
  const float* Ws0  = (const float*)d_in[3];
  const float* Wn0  = (const float*)d_in[4];
  const float* Ws1  = (const float*)d_in[5];
  const float* Wn1  = (const float*)d_in[6];
  const float* Ws2  = (const float*)d_in[7];
  const float* Wn2  = (const float*)d_in[8];
  const float* W1   = (const float*)d_in[9];
  const float* b1   = (const float*)d_in[10];
  const float* W2   = (const float*)d_in[11];
  const float* b2   = (const float*)d_in[12];
  const float* W3   = (const float*)d_in[13];
  const float* b3   = (const float*)d_in[14];
  const float* Wo   = (const float*)d_in[15];
  const float* bo   = (const float*)d_in[16];
  float* out = (float*)d_out;

  float* x1     = (float*)d_ws;                       // [NROWS,64]
  float* agg    = x1   + (size_t)NROWS * 64;          // [NROWS,64]
  float* agg0   = agg  + (size_t)NROWS * 64;          // [NROWS]
  float* g      = agg0 + NROWS;                       // [NN,64]
  float* pooled = g    + (size_t)NN * 64;             // [BB,64]
  unsigned* mm  = (unsigned*)(pooled + BB * 64);      // [2]
  int* deg      = (int*)(mm + 2);                     // [NN]
  int* rowstart = deg + NN;                           // [NN+1]
  int* cursor   = rowstart + NN + 1;                  // [NN]
  int* nbr      = cursor + NN;                        // [EE]
  int* bsum     = nbr + EE;                           // [NBLK_SCAN]

  // ---- CSR build ----
  hipMemsetAsync(deg, 0, NN * sizeof(int), stream);
  hist_k<<<(EE + 255) / 256, 256, 0, stream>>>(ei, deg);
  scan1_k<<<NBLK_SCAN, 512, 0, stream>>>(deg, rowstart, bsum);
  scan2_k<<<1, 64, 0, stream>>>(bsum);
  scan3_k<<<NBLK_SCAN, 512, 0, stream>>>(rowstart, cursor, bsum);
  fill_k<<<(EE + 255) / 256, 256, 0, stream>>>(ei, cursor, nbr);

  // ---- layer 0 aggregate (scalar) ----
  agg0_gather_k<<<(NROWS + 255) / 256, 256, 0, stream>>>(x0, rowstart, nbr, agg0);

  // ---- layer 1: gather with conv0 recompute, then conv1 -> x1 ----
  agg1_gather_k<<<(NN * 64) / 256, 256, 0, stream>>>(x0, agg0, rowstart, nbr, Ws0, Wn0, agg);
  conv1_k<<<NROWS / 64, 256, 0, stream>>>(x0, agg0, Ws0, Wn0, Ws1, Wn1, agg, x1);

  // ---- layer 2 aggregate ----
  agg_gather_k<<<(NN * 64) / 256, 256, 0, stream>>>(x1, rowstart, nbr, agg);

  // ---- fused conv2 + MLP + mean + min/max ----
  hipMemsetAsync(mm, 0xFF, 4, stream);
  hipMemsetAsync(mm + 1, 0x00, 4, stream);
  fused2_k<<<NROWS / 64, 256, 0, stream>>>(x1, agg, x0, agg0, Ws0, Wn0, Ws2, Wn2,
                                           W1, b1, W2, b2, W3, b3, g, mm);

  // ---- rescale + pooling ----
  hipMemsetAsync(pooled, 0, BB * 64 * sizeof(float), stream);
  pool2_k<<<(NN + 63) / 64, 256, 0, stream>>>(g, batch, mm, pooled);

  // ---- output linear ----
  out_k<<<BB, 64, 0, stream>>>(pooled, Wo, bo, out);
}

// Round 6
// 433.446 us; speedup vs baseline: 11.1070x; 1.0364x over previous
//
#include <hip/hip_runtime.h>
#include <math.h>

#define NN 50000
#define MM 4
#define EE 400000
#define BB 64
#define NROWS (NN*MM)           // 200000
#define NBLK_SCAN 98            // ceil(50000/512)

// ---------- helpers ----------

__device__ __forceinline__ unsigned enc_f(float f) {
  unsigned u = __float_as_uint(f);
  return (u & 0x80000000u) ? ~u : (u | 0x80000000u);
}
__device__ __forceinline__ float dec_f(unsigned u) {
  return (u & 0x80000000u) ? __uint_as_float(u ^ 0x80000000u) : __uint_as_float(~u);
}

__device__ __forceinline__ void axpy4(float4& a, float s, float4 w) {
  a.x = fmaf(s, w.x, a.x);
  a.y = fmaf(s, w.y, a.y);
  a.z = fmaf(s, w.z, a.z);
  a.w = fmaf(s, w.w, a.w);
}
__device__ __forceinline__ float4 relu4(float4 v) {
  return make_float4(fmaxf(v.x, 0.f), fmaxf(v.y, 0.f), fmaxf(v.z, 0.f), fmaxf(v.w, 0.f));
}

// 4x4 micro-tiled LDS GEMM step. X reads: 4 distinct addrs/wave (broadcast);
// W reads: 16 distinct float4/wave (one row, broadcast x4). Conflict-free.
#define MACC4(XS, A)                                                  \
  _Pragma("unroll 4")                                                 \
  for (int k = 0; k < 64; k += 4) {                                   \
    float4 xa = *(const float4*)&XS[r0 + 0][k];                       \
    float4 xb = *(const float4*)&XS[r0 + 1][k];                       \
    float4 xc = *(const float4*)&XS[r0 + 2][k];                       \
    float4 xd = *(const float4*)&XS[r0 + 3][k];                       \
    float4 w0 = *(const float4*)&Wl[k + 0][tc4];                      \
    float4 w1 = *(const float4*)&Wl[k + 1][tc4];                      \
    float4 w2 = *(const float4*)&Wl[k + 2][tc4];                      \
    float4 w3 = *(const float4*)&Wl[k + 3][tc4];                      \
    axpy4(A[0], xa.x, w0); axpy4(A[0], xa.y, w1); axpy4(A[0], xa.z, w2); axpy4(A[0], xa.w, w3); \
    axpy4(A[1], xb.x, w0); axpy4(A[1], xb.y, w1); axpy4(A[1], xb.z, w2); axpy4(A[1], xb.w, w3); \
    axpy4(A[2], xc.x, w0); axpy4(A[2], xc.y, w1); axpy4(A[2], xc.z, w2); axpy4(A[2], xc.w, w3); \
    axpy4(A[3], xd.x, w0); axpy4(A[3], xd.y, w1); axpy4(A[3], xd.z, w2); axpy4(A[3], xd.w, w3); \
  }

// ---------- CSR build (dst-major neighbor lists) ----------

__global__ void hist_k(const int* __restrict__ ei, int* __restrict__ deg) {
  int e = blockIdx.x * blockDim.x + threadIdx.x;
  if (e < EE) atomicAdd(&deg[ei[EE + e]], 1);
}

__global__ __launch_bounds__(512) void scan1_k(const int* __restrict__ deg,
                                               int* __restrict__ rowstart,
                                               int* __restrict__ bsum) {
  __shared__ int s[512];
  int i = blockIdx.x * 512 + threadIdx.x;
  int v = (i < NN) ? deg[i] : 0;
  s[threadIdx.x] = v;
  __syncthreads();
  for (int off = 1; off < 512; off <<= 1) {
    int t = (threadIdx.x >= (unsigned)off) ? s[threadIdx.x - off] : 0;
    __syncthreads();
    s[threadIdx.x] += t;
    __syncthreads();
  }
  if (i < NN) rowstart[i] = s[threadIdx.x] - v;      // exclusive partial
  if (threadIdx.x == 511) bsum[blockIdx.x] = s[511];
}

__global__ void scan2_k(int* __restrict__ bsum) {
  if (threadIdx.x == 0) {
    int acc = 0;
    for (int k = 0; k < NBLK_SCAN; ++k) { int t = bsum[k]; bsum[k] = acc; acc += t; }
  }
}

__global__ __launch_bounds__(512) void scan3_k(int* __restrict__ rowstart,
                                               int* __restrict__ cursor,
                                               const int* __restrict__ bsum) {
  int i = blockIdx.x * 512 + threadIdx.x;
  if (i < NN) {
    int v = rowstart[i] + bsum[blockIdx.x];
    rowstart[i] = v;
    cursor[i] = v;
  }
  if (i == 0) rowstart[NN] = EE;
}

__global__ void fill_k(const int* __restrict__ ei, int* __restrict__ cursor,
                       int* __restrict__ nbr) {
  int e = blockIdx.x * blockDim.x + threadIdx.x;
  if (e >= EE) return;
  int d = ei[EE + e];
  int p = atomicAdd(&cursor[d], 1);
  nbr[p] = ei[e];
}

// ---------- aggregation 0: agg0[n*4+m] = sum_{s in N(n)} x0[s*4+m] ----------

__global__ void agg0_gather_k(const float* __restrict__ x0,
                              const int* __restrict__ rowstart,
                              const int* __restrict__ nbr,
                              float* __restrict__ agg0) {
  int idx = blockIdx.x * blockDim.x + threadIdx.x;   // NROWS
  if (idx >= NROWS) return;
  int n = idx >> 2, m = idx & 3;
  int beg = rowstart[n], end = rowstart[n + 1];
  float acc = 0.0f;
  for (int i = beg; i < end; ++i) acc += x0[nbr[i] * 4 + m];
  agg0[idx] = acc;
}

// ---------- aggregation 1 with conv0 recompute (rank-1, never materialized) ----------

__global__ void agg1_gather_k(const float* __restrict__ x0,
                              const float* __restrict__ agg0,
                              const int* __restrict__ rowstart,
                              const int* __restrict__ nbr,
                              const float* __restrict__ Ws0,
                              const float* __restrict__ Wn0,
                              float* __restrict__ agg) {
  int idx = blockIdx.x * blockDim.x + threadIdx.x;   // NN*64
  int c  = (idx & 15) << 2;
  int m  = (idx >> 4) & 3;
  int n  = idx >> 6;
  if (n >= NN) return;
  float4 ws = *(const float4*)(Ws0 + c);
  float4 wn = *(const float4*)(Wn0 + c);
  int beg = rowstart[n], end = rowstart[n + 1];
  float4 acc = {0.0f, 0.0f, 0.0f, 0.0f};
  for (int i = beg; i < end; ++i) {
    int s = nbr[i];
    float xv = x0[s * 4 + m];
    float av = agg0[s * 4 + m];
    acc.x += fmaxf(xv * ws.x + av * wn.x, 0.0f);
    acc.y += fmaxf(xv * ws.y + av * wn.y, 0.0f);
    acc.z += fmaxf(xv * ws.z + av * wn.z, 0.0f);
    acc.w += fmaxf(xv * ws.w + av * wn.w, 0.0f);
  }
  *(float4*)(agg + (size_t)(n * 4 + m) * 64 + c) = acc;
}

// ---------- conv1: x1 = relu(x0feat@Ws1 + agg1@Wn1), 4x4 micro-tile + prefetch ----------

__global__ __launch_bounds__(256, 4) void conv1_k(const float* __restrict__ x0,
                                                  const float* __restrict__ agg0,
                                                  const float* __restrict__ Ws0,
                                                  const float* __restrict__ Wn0,
                                                  const float* __restrict__ Ws1,
                                                  const float* __restrict__ Wn1,
                                                  const float* __restrict__ aggin,
                                                  float* __restrict__ x1) {
  __shared__ float XA[64][68];
  __shared__ float Wl[64][64];
  const int row0 = blockIdx.x << 6;
  const int tid = threadIdx.x;
  const int tc4 = (tid & 15) << 2;   // col offset
  const int tr  = tid >> 4;          // staging row group
  const int r0  = tr << 2;           // compute row offset

  float4 xpre[4], wpre[4];
  float xpv[4], apv[4];

  // prologue: XA <- x0feat (recomputed), Wl <- Ws1
#pragma unroll
  for (int q = 0; q < 4; ++q) {
    xpv[q] = x0[row0 + tr + (q << 4)];
    apv[q] = agg0[row0 + tr + (q << 4)];
    wpre[q] = *(const float4*)(Ws1 + (tr + (q << 4)) * 64 + tc4);
  }
  {
    float4 ws = *(const float4*)(Ws0 + tc4);
    float4 wn = *(const float4*)(Wn0 + tc4);
#pragma unroll
    for (int q = 0; q < 4; ++q) {
      float4 t;
      t.x = fmaxf(xpv[q] * ws.x + apv[q] * wn.x, 0.f);
      t.y = fmaxf(xpv[q] * ws.y + apv[q] * wn.y, 0.f);
      t.z = fmaxf(xpv[q] * ws.z + apv[q] * wn.z, 0.f);
      t.w = fmaxf(xpv[q] * ws.w + apv[q] * wn.w, 0.f);
      *(float4*)&XA[tr + (q << 4)][tc4] = t;
      *(float4*)&Wl[tr + (q << 4)][tc4] = wpre[q];
    }
  }
  // prefetch phase 2: agg1 rows + Wn1
#pragma unroll
  for (int q = 0; q < 4; ++q) {
    xpre[q] = *(const float4*)(aggin + (size_t)(row0 + tr + (q << 4)) * 64 + tc4);
    wpre[q] = *(const float4*)(Wn1 + (tr + (q << 4)) * 64 + tc4);
  }
  __syncthreads();

  float4 acc[4];
  acc[0] = acc[1] = acc[2] = acc[3] = make_float4(0.f, 0.f, 0.f, 0.f);
  MACC4(XA, acc);
  __syncthreads();
#pragma unroll
  for (int q = 0; q < 4; ++q) {
    *(float4*)&XA[tr + (q << 4)][tc4] = xpre[q];
    *(float4*)&Wl[tr + (q << 4)][tc4] = wpre[q];
  }
  __syncthreads();
  MACC4(XA, acc);

#pragma unroll
  for (int i = 0; i < 4; ++i)
    *(float4*)(x1 + (size_t)(row0 + r0 + i) * 64 + tc4) = relu4(acc[i]);
}

// ---------- aggregation 2: gather x1 (stride 64) ----------

__global__ void agg_gather_k(const float* __restrict__ xin,
                             const int* __restrict__ rowstart,
                             const int* __restrict__ nbr,
                             float* __restrict__ agg) {
  int idx = blockIdx.x * blockDim.x + threadIdx.x;   // NN*64
  int c  = (idx & 15) << 2;
  int m  = (idx >> 4) & 3;
  int n  = idx >> 6;
  if (n >= NN) return;
  int beg = rowstart[n], end = rowstart[n + 1];
  float4 acc = {0.0f, 0.0f, 0.0f, 0.0f};
  for (int i = beg; i < end; ++i) {
    int s = nbr[i];
    float4 v = *(const float4*)(xin + (size_t)(s * 4 + m) * 64 + c);
    acc.x += v.x; acc.y += v.y; acc.z += v.z; acc.w += v.w;
  }
  *(float4*)(agg + (size_t)(n * 4 + m) * 64 + c) = acc;
}

// ---------- fused conv2 + 3-layer MLP + mean over M + min/max ----------
// Single X tile (XA) + single W tile: 33.8 KB LDS -> 4 blocks/CU.
// Phase order (sums re-associated so x1 is consumed before being evicted):
//   P1 x1@Ws2->acc1 | P2 x1@W1b->acc2 | P3 agg2@Wn2->acc1, x2=relu(acc1)
//   P4 x2@W1c->acc2 | P5 x0f@W1a->acc2, h1=relu | P6 h1@W2 | P7 h2@W3

__global__ __launch_bounds__(256, 4) void fused2_k(const float* __restrict__ x1,
    const float* __restrict__ aggin,
    const float* __restrict__ x0, const float* __restrict__ agg0,
    const float* __restrict__ Ws0, const float* __restrict__ Wn0,
    const float* __restrict__ Ws2, const float* __restrict__ Wn2,
    const float* __restrict__ W1, const float* __restrict__ b1,
    const float* __restrict__ W2, const float* __restrict__ b2,
    const float* __restrict__ W3, const float* __restrict__ b3,
    float* __restrict__ g, unsigned* __restrict__ mm) {
  __shared__ float XA[64][68];
  __shared__ float Wl[64][64];
  __shared__ float red[8];
  const int row0 = blockIdx.x << 6;
  const int tid = threadIdx.x;
  const int tc4 = (tid & 15) << 2;
  const int tr  = tid >> 4;
  const int r0  = tr << 2;

  float4 xpre[4], wpre[4];
  float xpv[4], apv[4];
  float4 acc1[4], acc2[4];

  // ---- prologue: XA <- x1, Wl <- Ws2; prefetch W1b ----
#pragma unroll
  for (int q = 0; q < 4; ++q) {
    xpre[q] = *(const float4*)(x1 + (size_t)(row0 + tr + (q << 4)) * 64 + tc4);
    wpre[q] = *(const float4*)(Ws2 + (tr + (q << 4)) * 64 + tc4);
  }
#pragma unroll
  for (int q = 0; q < 4; ++q) {
    *(float4*)&XA[tr + (q << 4)][tc4] = xpre[q];
    *(float4*)&Wl[tr + (q << 4)][tc4] = wpre[q];
  }
#pragma unroll
  for (int q = 0; q < 4; ++q)                        // prefetch W1b (rows 64..127)
    wpre[q] = *(const float4*)(W1 + (64 + tr + (q << 4)) * 64 + tc4);
  __syncthreads();

  // ---- P1: acc1 = x1 @ Ws2 ----
  acc1[0] = acc1[1] = acc1[2] = acc1[3] = make_float4(0.f, 0.f, 0.f, 0.f);
  MACC4(XA, acc1);
  __syncthreads();
#pragma unroll
  for (int q = 0; q < 4; ++q)
    *(float4*)&Wl[tr + (q << 4)][tc4] = wpre[q];     // commit W1b (XA untouched)
#pragma unroll
  for (int q = 0; q < 4; ++q) {                      // prefetch agg2 + Wn2
    xpre[q] = *(const float4*)(aggin + (size_t)(row0 + tr + (q << 4)) * 64 + tc4);
    wpre[q] = *(const float4*)(Wn2 + (tr + (q << 4)) * 64 + tc4);
  }
  __syncthreads();

  // ---- P2: acc2 = b1 + x1 @ W1b ----
  {
    float4 bb = *(const float4*)(b1 + tc4);
    acc2[0] = acc2[1] = acc2[2] = acc2[3] = bb;
  }
  MACC4(XA, acc2);
  __syncthreads();
#pragma unroll
  for (int q = 0; q < 4; ++q) {                      // commit XA=agg2, Wl=Wn2
    *(float4*)&XA[tr + (q << 4)][tc4] = xpre[q];
    *(float4*)&Wl[tr + (q << 4)][tc4] = wpre[q];
  }
#pragma unroll
  for (int q = 0; q < 4; ++q)                        // prefetch W1c (rows 128..191)
    wpre[q] = *(const float4*)(W1 + (128 + tr + (q << 4)) * 64 + tc4);
  __syncthreads();

  // ---- P3: acc1 += agg2 @ Wn2 ; x2 = relu(acc1) ----
  MACC4(XA, acc1);
  __syncthreads();
#pragma unroll
  for (int i = 0; i < 4; ++i)                        // x2 -> XA
    *(float4*)&XA[r0 + i][tc4] = relu4(acc1[i]);
#pragma unroll
  for (int q = 0; q < 4; ++q)
    *(float4*)&Wl[tr + (q << 4)][tc4] = wpre[q];     // commit W1c
#pragma unroll
  for (int q = 0; q < 4; ++q) {                      // prefetch x0f scalars + W1a
    xpv[q] = x0[row0 + tr + (q << 4)];
    apv[q] = agg0[row0 + tr + (q << 4)];
    wpre[q] = *(const float4*)(W1 + (tr + (q << 4)) * 64 + tc4);
  }
  __syncthreads();

  // ---- P4: acc2 += x2 @ W1c ----
  MACC4(XA, acc2);
  __syncthreads();
  {
    float4 ws = *(const float4*)(Ws0 + tc4);
    float4 wn = *(const float4*)(Wn0 + tc4);
#pragma unroll
    for (int q = 0; q < 4; ++q) {                    // commit XA = x0feat, Wl = W1a
      float4 t;
      t.x = fmaxf(xpv[q] * ws.x + apv[q] * wn.x, 0.f);
      t.y = fmaxf(xpv[q] * ws.y + apv[q] * wn.y, 0.f);
      t.z = fmaxf(xpv[q] * ws.z + apv[q] * wn.z, 0.f);
      t.w = fmaxf(xpv[q] * ws.w + apv[q] * wn.w, 0.f);
      *(float4*)&XA[tr + (q << 4)][tc4] = t;
      *(float4*)&Wl[tr + (q << 4)][tc4] = wpre[q];
    }
  }
#pragma unroll
  for (int q = 0; q < 4; ++q)                        // prefetch W2
    wpre[q] = *(const float4*)(W2 + (tr + (q << 4)) * 64 + tc4);
  __syncthreads();

  // ---- P5: acc2 += x0f @ W1a ; h1 = relu(acc2) ----
  MACC4(XA, acc2);
  __syncthreads();
#pragma unroll
  for (int i = 0; i < 4; ++i)                        // h1 -> XA
    *(float4*)&XA[r0 + i][tc4] = relu4(acc2[i]);
#pragma unroll
  for (int q = 0; q < 4; ++q)
    *(float4*)&Wl[tr + (q << 4)][tc4] = wpre[q];     // commit W2
#pragma unroll
  for (int q = 0; q < 4; ++q)                        // prefetch W3
    wpre[q] = *(const float4*)(W3 + (tr + (q << 4)) * 64 + tc4);
  __syncthreads();

  // ---- P6: acc1 = b2 + h1 @ W2 ; h2 = relu ----
  {
    float4 bb = *(const float4*)(b2 + tc4);
    acc1[0] = acc1[1] = acc1[2] = acc1[3] = bb;
  }
  MACC4(XA, acc1);
  __syncthreads();
#pragma unroll
  for (int i = 0; i < 4; ++i)                        // h2 -> XA
    *(float4*)&XA[r0 + i][tc4] = relu4(acc1[i]);
#pragma unroll
  for (int q = 0; q < 4; ++q)
    *(float4*)&Wl[tr + (q << 4)][tc4] = wpre[q];     // commit W3
  __syncthreads();

  // ---- P7: acc2 = b3 + h2 @ W3 (no relu) ----
  {
    float4 bb = *(const float4*)(b3 + tc4);
    acc2[0] = acc2[1] = acc2[2] = acc2[3] = bb;
  }
  MACC4(XA, acc2);
  __syncthreads();
#pragma unroll
  for (int i = 0; i < 4; ++i)
    *(float4*)&XA[r0 + i][tc4] = acc2[i];            // h3 -> XA
  __syncthreads();

  // ---- mean over M + per-block min/max ----
  float lmin = 3.4e38f, lmax = -3.4e38f;
  for (int k = tid; k < 1024; k += 256) {
    int nl = k >> 6, c = k & 63;
    float s = 0.25f * (XA[4*nl][c] + XA[4*nl+1][c] + XA[4*nl+2][c] + XA[4*nl+3][c]);
    g[(size_t)((row0 >> 2) + nl) * 64 + c] = s;
    lmin = fminf(lmin, s);
    lmax = fmaxf(lmax, s);
  }
#pragma unroll
  for (int off = 32; off; off >>= 1) {
    lmin = fminf(lmin, __shfl_xor(lmin, off));
    lmax = fmaxf(lmax, __shfl_xor(lmax, off));
  }
  if ((tid & 63) == 0) { red[tid >> 6] = lmin; red[4 + (tid >> 6)] = lmax; }
  __syncthreads();
  if (tid == 0) {
    float m0 = fminf(fminf(red[0], red[1]), fminf(red[2], red[3]));
    float m1 = fmaxf(fmaxf(red[4], red[5]), fmaxf(red[6], red[7]));
    atomicMin(&mm[0], enc_f(m0));
    atomicMax(&mm[1], enc_f(m1));
  }
}

// ---------- rescale + pool (sorted batch -> run-length accumulate) ----------

__global__ __launch_bounds__(256) void pool2_k(const float* __restrict__ g,
                                               const int* __restrict__ batch,
                                               const unsigned* __restrict__ mm,
                                               float* __restrict__ pooled) {
  int c = threadIdx.x & 63;
  int grp = threadIdx.x >> 6;                        // 0..3
  int base = blockIdx.x * 64 + grp * 16;             // 16 consecutive nodes per group
  float gmin = dec_f(mm[0]);
  float sc = 2.0f / (dec_f(mm[1]) - gmin);
  float acc = 0.0f; int cur = -1;
  for (int i = 0; i < 16; ++i) {
    int n = base + i;
    if (n >= NN) break;
    int b = batch[n];
    if (b != cur) {
      if (cur >= 0) unsafeAtomicAdd(&pooled[(cur << 6) + c], acc);
      cur = b; acc = 0.0f;
    }
    acc += (g[(size_t)n * 64 + c] - gmin) * sc;
  }
  if (cur >= 0) unsafeAtomicAdd(&pooled[(cur << 6) + c], acc);
}

// ---------- out[b] = pooled[b,:] . Wo + bo ----------

__global__ void out_k(const float* __restrict__ pooled, const float* __restrict__ Wo,
                      const float* __restrict__ bo, float* __restrict__ out) {
  int b = blockIdx.x, l = threadIdx.x;
  float v = pooled[(b << 6) + l] * Wo[l];
#pragma unroll
  for (int off = 32; off; off >>= 1) v += __shfl_xor(v, off);
  if (l == 0) out[b] = v + bo[0];
}

// ---------- launch ----------

extern "C" void kernel_launch(void* const* d_in, const int* in_sizes, int n_in,
                              void* d_out, int out_size, void* d_ws, size_t ws_size,
                              hipStream_t stream) {
  const float* x0   = (const float*)d_in[0];
  const int*   ei   = (const int*)d_in[1];
  const int*   batch= (const int*)d_in[2];
  const float* Ws0  = (const float*)d_in[3];
  const float* Wn0  = (const float*)d_in[4];
  const float* Ws1  = (const float*)d_in[5];
  const float* Wn1  = (const float*)d_in[6];
  const float* Ws2  = (const float*)d_in[7];
  const float* Wn2  = (const float*)d_in[8];
  const float* W1   = (const float*)d_in[9];
  const float* b1   = (const float*)d_in[10];
  const float* W2   = (const float*)d_in[11];
  const float* b2   = (const float*)d_in[12];
  const float* W3   = (const float*)d_in[13];
  const float* b3   = (const float*)d_in[14];
  const float* Wo   = (const float*)d_in[15];
  const float* bo   = (const float*)d_in[16];
  float* out = (float*)d_out;

  float* x1     = (float*)d_ws;                       // [NROWS,64]
  float* agg    = x1   + (size_t)NROWS * 64;          // [NROWS,64]
  float* agg0   = agg  + (size_t)NROWS * 64;          // [NROWS]
  float* g      = agg0 + NROWS;                       // [NN,64]
  float* pooled = g    + (size_t)NN * 64;             // [BB,64]
  unsigned* mm  = (unsigned*)(pooled + BB * 64);      // [2]
  int* deg      = (int*)(mm + 2);                     // [NN]
  int* rowstart = deg + NN;                           // [NN+1]
  int* cursor   = rowstart + NN + 1;                  // [NN]
  int* nbr      = cursor + NN;                        // [EE]
  int* bsum     = nbr + EE;                           // [NBLK_SCAN]

  // ---- CSR build ----
  hipMemsetAsync(deg, 0, NN * sizeof(int), stream);
  hist_k<<<(EE + 255) / 256, 256, 0, stream>>>(ei, deg);
  scan1_k<<<NBLK_SCAN, 512, 0, stream>>>(deg, rowstart, bsum);
  scan2_k<<<1, 64, 0, stream>>>(bsum);
  scan3_k<<<NBLK_SCAN, 512, 0, stream>>>(rowstart, cursor, bsum);
  fill_k<<<(EE + 255) / 256, 256, 0, stream>>>(ei, cursor, nbr);

  // ---- layer 0 aggregate (scalar) ----
  agg0_gather_k<<<(NROWS + 255) / 256, 256, 0, stream>>>(x0, rowstart, nbr, agg0);

  // ---- layer 1: gather with conv0 recompute, then conv1 -> x1 ----
  agg1_gather_k<<<(NN * 64) / 256, 256, 0, stream>>>(x0, agg0, rowstart, nbr, Ws0, Wn0, agg);
  conv1_k<<<NROWS / 64, 256, 0, stream>>>(x0, agg0, Ws0, Wn0, Ws1, Wn1, agg, x1);

  // ---- layer 2 aggregate ----
  agg_gather_k<<<(NN * 64) / 256, 256, 0, stream>>>(x1, rowstart, nbr, agg);

  // ---- fused conv2 + MLP + mean + min/max ----
  hipMemsetAsync(mm, 0xFF, 4, stream);
  hipMemsetAsync(mm + 1, 0x00, 4, stream);
  fused2_k<<<NROWS / 64, 256, 0, stream>>>(x1, agg, x0, agg0, Ws0, Wn0, Ws2, Wn2,
                                           W1, b1, W2, b2, W3, b3, g, mm);

  // ---- rescale + pooling ----
  hipMemsetAsync(pooled, 0, BB * 64 * sizeof(float), stream);
  pool2_k<<<(NN + 63) / 64, 256, 0, stream>>>(g, batch, mm, pooled);

  // ---- output linear ----
  out_k<<<BB, 64, 0, stream>>>(pooled, Wo, bo, out);
}

// Round 7
// 423.020 us; speedup vs baseline: 11.3807x; 1.0246x over previous
//
#include <hip/hip_runtime.h>
#include <math.h>

#define NN 50000
#define MM 4
#define EE 400000
#define BB 64
#define NROWS (NN*MM)           // 200000
#define NBLK_SCAN 98            // ceil(50000/512)

// ---------- helpers ----------

__device__ __forceinline__ unsigned enc_f(float f) {
  unsigned u = __float_as_uint(f);
  return (u & 0x80000000u) ? ~u : (u | 0x80000000u);
}
__device__ __forceinline__ float dec_f(unsigned u) {
  return (u & 0x80000000u) ? __uint_as_float(u ^ 0x80000000u) : __uint_as_float(~u);
}

__device__ __forceinline__ void axpy4(float4& a, float s, float4 w) {
  a.x = fmaf(s, w.x, a.x);
  a.y = fmaf(s, w.y, a.y);
  a.z = fmaf(s, w.z, a.z);
  a.w = fmaf(s, w.w, a.w);
}
__device__ __forceinline__ float4 relu4(float4 v) {
  return make_float4(fmaxf(v.x, 0.f), fmaxf(v.y, 0.f), fmaxf(v.z, 0.f), fmaxf(v.w, 0.f));
}

// 4x4 micro-tiled LDS GEMM step. Conflict-free (X: 4 bcast addrs/wave; W: 16 float4 row slice).
#define MACC4(XS, A)                                                  \
  _Pragma("unroll 4")                                                 \
  for (int k = 0; k < 64; k += 4) {                                   \
    float4 xa = *(const float4*)&XS[r0 + 0][k];                       \
    float4 xb = *(const float4*)&XS[r0 + 1][k];                       \
    float4 xc = *(const float4*)&XS[r0 + 2][k];                       \
    float4 xd = *(const float4*)&XS[r0 + 3][k];                       \
    float4 w0 = *(const float4*)&Wl[k + 0][tc4];                      \
    float4 w1 = *(const float4*)&Wl[k + 1][tc4];                      \
    float4 w2 = *(const float4*)&Wl[k + 2][tc4];                      \
    float4 w3 = *(const float4*)&Wl[k + 3][tc4];                      \
    axpy4(A[0], xa.x, w0); axpy4(A[0], xa.y, w1); axpy4(A[0], xa.z, w2); axpy4(A[0], xa.w, w3); \
    axpy4(A[1], xb.x, w0); axpy4(A[1], xb.y, w1); axpy4(A[1], xb.z, w2); axpy4(A[1], xb.w, w3); \
    axpy4(A[2], xc.x, w0); axpy4(A[2], xc.y, w1); axpy4(A[2], xc.z, w2); axpy4(A[2], xc.w, w3); \
    axpy4(A[3], xd.x, w0); axpy4(A[3], xd.y, w1); axpy4(A[3], xd.z, w2); axpy4(A[3], xd.w, w3); \
  }

// ---------- CSR build (dst-major neighbor lists) ----------

__global__ void hist_k(const int* __restrict__ ei, int* __restrict__ deg) {
  int e = blockIdx.x * blockDim.x + threadIdx.x;
  if (e < EE) atomicAdd(&deg[ei[EE + e]], 1);
}

__global__ __launch_bounds__(512) void scan1_k(const int* __restrict__ deg,
                                               int* __restrict__ rowstart,
                                               int* __restrict__ bsum) {
  __shared__ int s[512];
  int i = blockIdx.x * 512 + threadIdx.x;
  int v = (i < NN) ? deg[i] : 0;
  s[threadIdx.x] = v;
  __syncthreads();
  for (int off = 1; off < 512; off <<= 1) {
    int t = (threadIdx.x >= (unsigned)off) ? s[threadIdx.x - off] : 0;
    __syncthreads();
    s[threadIdx.x] += t;
    __syncthreads();
  }
  if (i < NN) rowstart[i] = s[threadIdx.x] - v;      // exclusive partial
  if (threadIdx.x == 511) bsum[blockIdx.x] = s[511];
}

__global__ void scan2_k(int* __restrict__ bsum) {
  if (threadIdx.x == 0) {
    int acc = 0;
    for (int k = 0; k < NBLK_SCAN; ++k) { int t = bsum[k]; bsum[k] = acc; acc += t; }
  }
}

__global__ __launch_bounds__(512) void scan3_k(int* __restrict__ rowstart,
                                               int* __restrict__ cursor,
                                               const int* __restrict__ bsum) {
  int i = blockIdx.x * 512 + threadIdx.x;
  if (i < NN) {
    int v = rowstart[i] + bsum[blockIdx.x];
    rowstart[i] = v;
    cursor[i] = v;
  }
  if (i == 0) rowstart[NN] = EE;
}

__global__ void fill_k(const int* __restrict__ ei, int* __restrict__ cursor,
                       int* __restrict__ nbr) {
  int e = blockIdx.x * blockDim.x + threadIdx.x;
  if (e >= EE) return;
  int d = ei[EE + e];
  int p = atomicAdd(&cursor[d], 1);
  nbr[p] = ei[e];
}

// ---------- aggregation 0: agg0[n*4+m] = sum_{s in N(n)} x0[s*4+m] ----------

__global__ void agg0_gather_k(const float* __restrict__ x0,
                              const int* __restrict__ rowstart,
                              const int* __restrict__ nbr,
                              float* __restrict__ agg0) {
  int idx = blockIdx.x * blockDim.x + threadIdx.x;   // NROWS
  if (idx >= NROWS) return;
  int n = idx >> 2, m = idx & 3;
  int beg = rowstart[n], end = rowstart[n + 1];
  float acc = 0.0f;
  for (int i = beg; i < end; ++i) acc += x0[nbr[i] * 4 + m];
  agg0[idx] = acc;
}

// ---------- conv1 (gather fused): x1 = relu(x0f@Ws1 + agg1@Wn1) ----------
// agg1 row (n,m) = sum_{s in N(n)} relu(x0[s4+m]*Ws0 + agg0[s4+m]*Wn0), gathered
// in-registers per thread for exactly the 4 XA cells it commits.

__global__ __launch_bounds__(256, 4) void conv1_k(const float* __restrict__ x0,
                                                  const float* __restrict__ agg0,
                                                  const int* __restrict__ rowstart,
                                                  const int* __restrict__ nbr,
                                                  const float* __restrict__ Ws0,
                                                  const float* __restrict__ Wn0,
                                                  const float* __restrict__ Ws1,
                                                  const float* __restrict__ Wn1,
                                                  float* __restrict__ x1) {
  __shared__ float XA[64][68];
  __shared__ float Wl[64][64];
  const int row0 = blockIdx.x << 6;
  const int nb0  = blockIdx.x << 4;
  const int tid = threadIdx.x;
  const int tc4 = (tid & 15) << 2;
  const int tr  = tid >> 4;
  const int r0  = tr << 2;

  float4 ws = *(const float4*)(Ws0 + tc4);
  float4 wn = *(const float4*)(Wn0 + tc4);

  // prologue: XA <- x0feat (recomputed), Wl <- Ws1
#pragma unroll
  for (int q = 0; q < 4; ++q) {
    int rr = tr + (q << 4);
    float xv = x0[row0 + rr], av = agg0[row0 + rr];
    float4 t;
    t.x = fmaxf(xv * ws.x + av * wn.x, 0.f);
    t.y = fmaxf(xv * ws.y + av * wn.y, 0.f);
    t.z = fmaxf(xv * ws.z + av * wn.z, 0.f);
    t.w = fmaxf(xv * ws.w + av * wn.w, 0.f);
    *(float4*)&XA[rr][tc4] = t;
    *(float4*)&Wl[rr][tc4] = *(const float4*)(Ws1 + rr * 64 + tc4);
  }

  // gather agg1 for my 4 cells (runs before P1; latency hidden by other waves)
  float4 gacc[4];
#pragma unroll
  for (int q = 0; q < 4; ++q) {
    int rr = tr + (q << 4);
    int n = nb0 + (rr >> 2), m = rr & 3;
    int beg = rowstart[n], end = rowstart[n + 1];
    float4 a = {0.f, 0.f, 0.f, 0.f};
    for (int i = beg; i < end; ++i) {
      int s4 = nbr[i] * 4 + m;
      float xv = x0[s4], av = agg0[s4];
      a.x += fmaxf(xv * ws.x + av * wn.x, 0.f);
      a.y += fmaxf(xv * ws.y + av * wn.y, 0.f);
      a.z += fmaxf(xv * ws.z + av * wn.z, 0.f);
      a.w += fmaxf(xv * ws.w + av * wn.w, 0.f);
    }
    gacc[q] = a;
  }
  float4 wpre[4];
#pragma unroll
  for (int q = 0; q < 4; ++q)
    wpre[q] = *(const float4*)(Wn1 + (tr + (q << 4)) * 64 + tc4);
  __syncthreads();

  // P1: x0f @ Ws1
  float4 acc[4];
  acc[0] = acc[1] = acc[2] = acc[3] = make_float4(0.f, 0.f, 0.f, 0.f);
  MACC4(XA, acc);
  __syncthreads();
#pragma unroll
  for (int q = 0; q < 4; ++q) {                      // commit XA=agg1, Wl=Wn1
    *(float4*)&XA[tr + (q << 4)][tc4] = gacc[q];
    *(float4*)&Wl[tr + (q << 4)][tc4] = wpre[q];
  }
  __syncthreads();

  // P2: agg1 @ Wn1
  MACC4(XA, acc);

#pragma unroll
  for (int i = 0; i < 4; ++i)
    *(float4*)(x1 + (size_t)(row0 + r0 + i) * 64 + tc4) = relu4(acc[i]);
}

// ---------- fused conv2 + 3-layer MLP + mean over M + min/max (gather fused) ----------
// agg2 gathered in-registers from x1 (L3-resident). Phase order as r5:
//   P1 x1@Ws2->acc1 | P2 x1@W1b->acc2 | P3 agg2@Wn2->acc1, x2=relu(acc1)
//   P4 x2@W1c->acc2 | P5 x0f@W1a->acc2, h1=relu | P6 h1@W2 | P7 h2@W3

__global__ __launch_bounds__(256, 4) void fused2_k(const float* __restrict__ x1,
    const int* __restrict__ rowstart, const int* __restrict__ nbr,
    const float* __restrict__ x0, const float* __restrict__ agg0,
    const float* __restrict__ Ws0, const float* __restrict__ Wn0,
    const float* __restrict__ Ws2, const float* __restrict__ Wn2,
    const float* __restrict__ W1, const float* __restrict__ b1,
    const float* __restrict__ W2, const float* __restrict__ b2,
    const float* __restrict__ W3, const float* __restrict__ b3,
    float* __restrict__ g, unsigned* __restrict__ mm) {
  __shared__ float XA[64][68];
  __shared__ float Wl[64][64];
  __shared__ float red[8];
  const int row0 = blockIdx.x << 6;
  const int nb0  = blockIdx.x << 4;
  const int tid = threadIdx.x;
  const int tc4 = (tid & 15) << 2;
  const int tr  = tid >> 4;
  const int r0  = tr << 2;

  float4 wpre[4], gacc[4];
  float xpv[4], apv[4];
  float4 acc1[4], acc2[4];

  // ---- prologue: XA <- x1, Wl <- Ws2 ----
#pragma unroll
  for (int q = 0; q < 4; ++q) {
    int rr = tr + (q << 4);
    *(float4*)&XA[rr][tc4] = *(const float4*)(x1 + (size_t)(row0 + rr) * 64 + tc4);
    *(float4*)&Wl[rr][tc4] = *(const float4*)(Ws2 + rr * 64 + tc4);
  }

  // gather agg2 for my 4 cells from x1 (random rows, L2/L3 hits)
#pragma unroll
  for (int q = 0; q < 4; ++q) {
    int rr = tr + (q << 4);
    int n = nb0 + (rr >> 2), m = rr & 3;
    int beg = rowstart[n], end = rowstart[n + 1];
    float4 a = {0.f, 0.f, 0.f, 0.f};
    for (int i = beg; i < end; ++i) {
      float4 v = *(const float4*)(x1 + (size_t)(nbr[i] * 4 + m) * 64 + tc4);
      a.x += v.x; a.y += v.y; a.z += v.z; a.w += v.w;
    }
    gacc[q] = a;
  }
#pragma unroll
  for (int q = 0; q < 4; ++q)                        // prefetch W1b (rows 64..127)
    wpre[q] = *(const float4*)(W1 + (64 + tr + (q << 4)) * 64 + tc4);
  __syncthreads();

  // ---- P1: acc1 = x1 @ Ws2 ----
  acc1[0] = acc1[1] = acc1[2] = acc1[3] = make_float4(0.f, 0.f, 0.f, 0.f);
  MACC4(XA, acc1);
  __syncthreads();
#pragma unroll
  for (int q = 0; q < 4; ++q)
    *(float4*)&Wl[tr + (q << 4)][tc4] = wpre[q];     // commit W1b (XA untouched)
#pragma unroll
  for (int q = 0; q < 4; ++q)                        // prefetch Wn2
    wpre[q] = *(const float4*)(Wn2 + (tr + (q << 4)) * 64 + tc4);
  __syncthreads();

  // ---- P2: acc2 = b1 + x1 @ W1b ----
  {
    float4 bb = *(const float4*)(b1 + tc4);
    acc2[0] = acc2[1] = acc2[2] = acc2[3] = bb;
  }
  MACC4(XA, acc2);
  __syncthreads();
#pragma unroll
  for (int q = 0; q < 4; ++q) {                      // commit XA=agg2(gathered), Wl=Wn2
    *(float4*)&XA[tr + (q << 4)][tc4] = gacc[q];
    *(float4*)&Wl[tr + (q << 4)][tc4] = wpre[q];
  }
#pragma unroll
  for (int q = 0; q < 4; ++q)                        // prefetch W1c (rows 128..191)
    wpre[q] = *(const float4*)(W1 + (128 + tr + (q << 4)) * 64 + tc4);
  __syncthreads();

  // ---- P3: acc1 += agg2 @ Wn2 ; x2 = relu(acc1) ----
  MACC4(XA, acc1);
  __syncthreads();
#pragma unroll
  for (int i = 0; i < 4; ++i)                        // x2 -> XA
    *(float4*)&XA[r0 + i][tc4] = relu4(acc1[i]);
#pragma unroll
  for (int q = 0; q < 4; ++q)
    *(float4*)&Wl[tr + (q << 4)][tc4] = wpre[q];     // commit W1c
#pragma unroll
  for (int q = 0; q < 4; ++q) {                      // prefetch x0f scalars + W1a
    xpv[q] = x0[row0 + tr + (q << 4)];
    apv[q] = agg0[row0 + tr + (q << 4)];
    wpre[q] = *(const float4*)(W1 + (tr + (q << 4)) * 64 + tc4);
  }
  __syncthreads();

  // ---- P4: acc2 += x2 @ W1c ----
  MACC4(XA, acc2);
  __syncthreads();
  {
    float4 ws = *(const float4*)(Ws0 + tc4);
    float4 wn = *(const float4*)(Wn0 + tc4);
#pragma unroll
    for (int q = 0; q < 4; ++q) {                    // commit XA = x0feat, Wl = W1a
      float4 t;
      t.x = fmaxf(xpv[q] * ws.x + apv[q] * wn.x, 0.f);
      t.y = fmaxf(xpv[q] * ws.y + apv[q] * wn.y, 0.f);
      t.z = fmaxf(xpv[q] * ws.z + apv[q] * wn.z, 0.f);
      t.w = fmaxf(xpv[q] * ws.w + apv[q] * wn.w, 0.f);
      *(float4*)&XA[tr + (q << 4)][tc4] = t;
      *(float4*)&Wl[tr + (q << 4)][tc4] = wpre[q];
    }
  }
#pragma unroll
  for (int q = 0; q < 4; ++q)                        // prefetch W2
    wpre[q] = *(const float4*)(W2 + (tr + (q << 4)) * 64 + tc4);
  __syncthreads();

  // ---- P5: acc2 += x0f @ W1a ; h1 = relu(acc2) ----
  MACC4(XA, acc2);
  __syncthreads();
#pragma unroll
  for (int i = 0; i < 4; ++i)                        // h1 -> XA
    *(float4*)&XA[r0 + i][tc4] = relu4(acc2[i]);
#pragma unroll
  for (int q = 0; q < 4; ++q)
    *(float4*)&Wl[tr + (q << 4)][tc4] = wpre[q];     // commit W2
#pragma unroll
  for (int q = 0; q < 4; ++q)                        // prefetch W3
    wpre[q] = *(const float4*)(W3 + (tr + (q << 4)) * 64 + tc4);
  __syncthreads();

  // ---- P6: acc1 = b2 + h1 @ W2 ; h2 = relu ----
  {
    float4 bb = *(const float4*)(b2 + tc4);
    acc1[0] = acc1[1] = acc1[2] = acc1[3] = bb;
  }
  MACC4(XA, acc1);
  __syncthreads();
#pragma unroll
  for (int i = 0; i < 4; ++i)                        // h2 -> XA
    *(float4*)&XA[r0 + i][tc4] = relu4(acc1[i]);
#pragma unroll
  for (int q = 0; q < 4; ++q)
    *(float4*)&Wl[tr + (q << 4)][tc4] = wpre[q];     // commit W3
  __syncthreads();

  // ---- P7: acc2 = b3 + h2 @ W3 (no relu) ----
  {
    float4 bb = *(const float4*)(b3 + tc4);
    acc2[0] = acc2[1] = acc2[2] = acc2[3] = bb;
  }
  MACC4(XA, acc2);
  __syncthreads();
#pragma unroll
  for (int i = 0; i < 4; ++i)
    *(float4*)&XA[r0 + i][tc4] = acc2[i];            // h3 -> XA
  __syncthreads();

  // ---- mean over M + per-block min/max ----
  float lmin = 3.4e38f, lmax = -3.4e38f;
  for (int k = tid; k < 1024; k += 256) {
    int nl = k >> 6, c = k & 63;
    float s = 0.25f * (XA[4*nl][c] + XA[4*nl+1][c] + XA[4*nl+2][c] + XA[4*nl+3][c]);
    g[(size_t)((row0 >> 2) + nl) * 64 + c] = s;
    lmin = fminf(lmin, s);
    lmax = fmaxf(lmax, s);
  }
#pragma unroll
  for (int off = 32; off; off >>= 1) {
    lmin = fminf(lmin, __shfl_xor(lmin, off));
    lmax = fmaxf(lmax, __shfl_xor(lmax, off));
  }
  if ((tid & 63) == 0) { red[tid >> 6] = lmin; red[4 + (tid >> 6)] = lmax; }
  __syncthreads();
  if (tid == 0) {
    float m0 = fminf(fminf(red[0], red[1]), fminf(red[2], red[3]));
    float m1 = fmaxf(fmaxf(red[4], red[5]), fmaxf(red[6], red[7]));
    atomicMin(&mm[0], enc_f(m0));
    atomicMax(&mm[1], enc_f(m1));
  }
}

// ---------- rescale + pool (sorted batch -> run-length accumulate) ----------

__global__ __launch_bounds__(256) void pool2_k(const float* __restrict__ g,
                                               const int* __restrict__ batch,
                                               const unsigned* __restrict__ mm,
                                               float* __restrict__ pooled) {
  int c = threadIdx.x & 63;
  int grp = threadIdx.x >> 6;                        // 0..3
  int base = blockIdx.x * 64 + grp * 16;             // 16 consecutive nodes per group
  float gmin = dec_f(mm[0]);
  float sc = 2.0f / (dec_f(mm[1]) - gmin);
  float acc = 0.0f; int cur = -1;
  for (int i = 0; i < 16; ++i) {
    int n = base + i;
    if (n >= NN) break;
    int b = batch[n];
    if (b != cur) {
      if (cur >= 0) unsafeAtomicAdd(&pooled[(cur << 6) + c], acc);
      cur = b; acc = 0.0f;
    }
    acc += (g[(size_t)n * 64 + c] - gmin) * sc;
  }
  if (cur >= 0) unsafeAtomicAdd(&pooled[(cur << 6) + c], acc);
}

// ---------- out[b] = pooled[b,:] . Wo + bo ----------

__global__ void out_k(const float* __restrict__ pooled, const float* __restrict__ Wo,
                      const float* __restrict__ bo, float* __restrict__ out) {
  int b = blockIdx.x, l = threadIdx.x;
  float v = pooled[(b << 6) + l] * Wo[l];
#pragma unroll
  for (int off = 32; off; off >>= 1) v += __shfl_xor(v, off);
  if (l == 0) out[b] = v + bo[0];
}

// ---------- launch ----------

extern "C" void kernel_launch(void* const* d_in, const int* in_sizes, int n_in,
                              void* d_out, int out_size, void* d_ws, size_t ws_size,
                              hipStream_t stream) {
  const float* x0   = (const float*)d_in[0];
  const int*   ei   = (const int*)d_in[1];
  const int*   batch= (const int*)d_in[2];
  const float* Ws0  = (const float*)d_in[3];
  const float* Wn0  = (const float*)d_in[4];
  const float* Ws1  = (const float*)d_in[5];
  const float* Wn1  = (const float*)d_in[6];
  const float* Ws2  = (const float*)d_in[7];
  const float* Wn2  = (const float*)d_in[8];
  const float* W1   = (const float*)d_in[9];
  const float* b1   = (const float*)d_in[10];
  const float* W2   = (const float*)d_in[11];
  const float* b2   = (const float*)d_in[12];
  const float* W3   = (const float*)d_in[13];
  const float* b3   = (const float*)d_in[14];
  const float* Wo   = (const float*)d_in[15];
  const float* bo   = (const float*)d_in[16];
  float* out = (float*)d_out;

  float* x1     = (float*)d_ws;                       // [NROWS,64]
  float* agg0   = x1   + (size_t)NROWS * 64;          // [NROWS]
  float* g      = agg0 + NROWS;                       // [NN,64]
  float* pooled = g    + (size_t)NN * 64;             // [BB,64]
  unsigned* mm  = (unsigned*)(pooled + BB * 64);      // [2]
  int* deg      = (int*)(mm + 2);                     // [NN]
  int* rowstart = deg + NN;                           // [NN+1]
  int* cursor   = rowstart + NN + 1;                  // [NN]
  int* nbr      = cursor + NN;                        // [EE]
  int* bsum     = nbr + EE;                           // [NBLK_SCAN]

  // ---- CSR build ----
  hipMemsetAsync(deg, 0, NN * sizeof(int), stream);
  hist_k<<<(EE + 255) / 256, 256, 0, stream>>>(ei, deg);
  scan1_k<<<NBLK_SCAN, 512, 0, stream>>>(deg, rowstart, bsum);
  scan2_k<<<1, 64, 0, stream>>>(bsum);
  scan3_k<<<NBLK_SCAN, 512, 0, stream>>>(rowstart, cursor, bsum);
  fill_k<<<(EE + 255) / 256, 256, 0, stream>>>(ei, cursor, nbr);

  // ---- layer 0 aggregate (scalar) ----
  agg0_gather_k<<<(NROWS + 255) / 256, 256, 0, stream>>>(x0, rowstart, nbr, agg0);

  // ---- layer 1 (agg1 gather fused) -> x1 ----
  conv1_k<<<NROWS / 64, 256, 0, stream>>>(x0, agg0, rowstart, nbr,
                                          Ws0, Wn0, Ws1, Wn1, x1);

  // ---- fused conv2 + MLP + mean + min/max (agg2 gather fused) ----
  hipMemsetAsync(mm, 0xFF, 4, stream);
  hipMemsetAsync(mm + 1, 0x00, 4, stream);
  fused2_k<<<NROWS / 64, 256, 0, stream>>>(x1, rowstart, nbr, x0, agg0,
                                           Ws0, Wn0, Ws2, Wn2,
                                           W1, b1, W2, b2, W3, b3, g, mm);

  // ---- rescale + pooling ----
  hipMemsetAsync(pooled, 0, BB * 64 * sizeof(float), stream);
  pool2_k<<<(NN + 63) / 64, 256, 0, stream>>>(g, batch, mm, pooled);

  // ---- output linear ----
  out_k<<<BB, 64, 0, stream>>>(pooled, Wo, bo, out);
}

// Round 8
// 379.947 us; speedup vs baseline: 12.6709x; 1.1134x over previous
//
#include <hip/hip_runtime.h>
#include <math.h>

#define NN 50000
#define MM 4
#define EE 400000
#define BB 64
#define NROWS (NN*MM)           // 200000
#define NBLK_SCAN 98            // ceil(50000/512)

// ---------- helpers ----------

__device__ __forceinline__ unsigned enc_f(float f) {
  unsigned u = __float_as_uint(f);
  return (u & 0x80000000u) ? ~u : (u | 0x80000000u);
}
__device__ __forceinline__ float dec_f(unsigned u) {
  return (u & 0x80000000u) ? __uint_as_float(u ^ 0x80000000u) : __uint_as_float(~u);
}

__device__ __forceinline__ void axpy4(float4& a, float s, float4 w) {
  a.x = fmaf(s, w.x, a.x);
  a.y = fmaf(s, w.y, a.y);
  a.z = fmaf(s, w.z, a.z);
  a.w = fmaf(s, w.w, a.w);
}
__device__ __forceinline__ float4 relu4(float4 v) {
  return make_float4(fmaxf(v.x, 0.f), fmaxf(v.y, 0.f), fmaxf(v.z, 0.f), fmaxf(v.w, 0.f));
}
__device__ __forceinline__ float4 add4(float4 a, float4 b) {
  return make_float4(a.x + b.x, a.y + b.y, a.z + b.z, a.w + b.w);
}
__device__ __forceinline__ float4 conv0f(float xv, float av, float4 ws, float4 wn) {
  float4 t;
  t.x = fmaxf(fmaf(xv, ws.x, av * wn.x), 0.f);
  t.y = fmaxf(fmaf(xv, ws.y, av * wn.y), 0.f);
  t.z = fmaxf(fmaf(xv, ws.z, av * wn.z), 0.f);
  t.w = fmaxf(fmaf(xv, ws.w, av * wn.w), 0.f);
  return t;
}

// 2x4 micro-tiled LDS GEMM step (512-thread blocks). X reads: 4-addr broadcast;
// W reads: 16x16B row slice. Conflict-free (row strides 136/68 dw = 8/4 mod 32).
#define MACC2(XS, A)                                                  \
  _Pragma("unroll 2")                                                 \
  for (int k = 0; k < 64; k += 4) {                                   \
    float4 xa = *(const float4*)&XS[r0 + 0][k];                       \
    float4 xb = *(const float4*)&XS[r0 + 1][k];                       \
    float4 w0 = *(const float4*)&Wl[k + 0][tc4];                      \
    float4 w1 = *(const float4*)&Wl[k + 1][tc4];                      \
    float4 w2 = *(const float4*)&Wl[k + 2][tc4];                      \
    float4 w3 = *(const float4*)&Wl[k + 3][tc4];                      \
    axpy4(A[0], xa.x, w0); axpy4(A[0], xa.y, w1); axpy4(A[0], xa.z, w2); axpy4(A[0], xa.w, w3); \
    axpy4(A[1], xb.x, w0); axpy4(A[1], xb.y, w1); axpy4(A[1], xb.z, w2); axpy4(A[1], xb.w, w3); \
  }

// ---------- CSR build (dst-major neighbor lists) ----------

__global__ void hist_k(const int* __restrict__ ei, int* __restrict__ deg) {
  int e = blockIdx.x * blockDim.x + threadIdx.x;
  if (e < EE) atomicAdd(&deg[ei[EE + e]], 1);
}

__global__ __launch_bounds__(512) void scan1_k(const int* __restrict__ deg,
                                               int* __restrict__ rowstart,
                                               int* __restrict__ bsum) {
  __shared__ int s[512];
  int i = blockIdx.x * 512 + threadIdx.x;
  int v = (i < NN) ? deg[i] : 0;
  s[threadIdx.x] = v;
  __syncthreads();
  for (int off = 1; off < 512; off <<= 1) {
    int t = (threadIdx.x >= (unsigned)off) ? s[threadIdx.x - off] : 0;
    __syncthreads();
    s[threadIdx.x] += t;
    __syncthreads();
  }
  if (i < NN) rowstart[i] = s[threadIdx.x] - v;      // exclusive partial
  if (threadIdx.x == 511) bsum[blockIdx.x] = s[511];
}

__global__ void scan2_k(int* __restrict__ bsum) {
  if (threadIdx.x == 0) {
    int acc = 0;
    for (int k = 0; k < NBLK_SCAN; ++k) { int t = bsum[k]; bsum[k] = acc; acc += t; }
  }
}

__global__ __launch_bounds__(512) void scan3_k(int* __restrict__ rowstart,
                                               int* __restrict__ cursor,
                                               const int* __restrict__ bsum) {
  int i = blockIdx.x * 512 + threadIdx.x;
  if (i < NN) {
    int v = rowstart[i] + bsum[blockIdx.x];
    rowstart[i] = v;
    cursor[i] = v;
  }
  if (i == 0) rowstart[NN] = EE;
}

__global__ void fill_k(const int* __restrict__ ei, int* __restrict__ cursor,
                       int* __restrict__ nbr) {
  int e = blockIdx.x * blockDim.x + threadIdx.x;
  if (e >= EE) return;
  int d = ei[EE + e];
  int p = atomicAdd(&cursor[d], 1);
  nbr[p] = ei[e];
}

// ---------- aggregation 0: agg0[n*4+m] = sum_{s in N(n)} x0[s*4+m] ----------

__global__ void agg0_gather_k(const float* __restrict__ x0,
                              const int* __restrict__ rowstart,
                              const int* __restrict__ nbr,
                              float* __restrict__ agg0) {
  int idx = blockIdx.x * blockDim.x + threadIdx.x;   // NROWS
  if (idx >= NROWS) return;
  int n = idx >> 2, m = idx & 3;
  int beg = rowstart[n], end = rowstart[n + 1];
  float acc = 0.0f;
  for (int i = beg; i < end; ++i) acc += x0[nbr[i] * 4 + m];
  agg0[idx] = acc;
}

// ---------- conv1 (gather fused, 512 thr): x1 = relu(x0f@Ws1 + agg1@Wn1) ----------

__global__ __launch_bounds__(512, 8) void conv1_k(const float* __restrict__ x0,
                                                  const float* __restrict__ agg0,
                                                  const int* __restrict__ rowstart,
                                                  const int* __restrict__ nbr,
                                                  const float* __restrict__ Ws0,
                                                  const float* __restrict__ Wn0,
                                                  const float* __restrict__ Ws1,
                                                  const float* __restrict__ Wn1,
                                                  float* __restrict__ x1) {
  __shared__ float XA[64][68];
  __shared__ float Wl[64][64];
  const int row0 = blockIdx.x << 6;
  const int nb0  = blockIdx.x << 4;
  const int tid = threadIdx.x;
  const int tc4 = (tid & 15) << 2;
  const int tr  = tid >> 4;          // 0..31
  const int r0  = tr << 1;

  float4 ws = *(const float4*)(Ws0 + tc4);
  float4 wn = *(const float4*)(Wn0 + tc4);

  // stage XA = x0feat (recomputed), Wl = Ws1
#pragma unroll
  for (int q = 0; q < 2; ++q) {
    int rr = tr + (q << 5);
    *(float4*)&XA[rr][tc4] = conv0f(x0[row0 + rr], agg0[row0 + rr], ws, wn);
    *(float4*)&Wl[rr][tc4] = *(const float4*)(Ws1 + rr * 64 + tc4);
  }

  // gather agg1 (2 nodes/thread, unroll 4 for MLP)
  float4 gacc[2];
#pragma unroll
  for (int q = 0; q < 2; ++q) {
    int rr = tr + (q << 5);
    int n = nb0 + (rr >> 2), m = rr & 3;
    int beg = rowstart[n], end = rowstart[n + 1];
    float4 a0 = {0.f,0.f,0.f,0.f}, a1 = {0.f,0.f,0.f,0.f};
    float4 a2 = {0.f,0.f,0.f,0.f}, a3 = {0.f,0.f,0.f,0.f};
    int i = beg;
    for (; i + 4 <= end; i += 4) {
      int s0 = nbr[i] * 4 + m, s1 = nbr[i+1] * 4 + m;
      int s2 = nbr[i+2] * 4 + m, s3 = nbr[i+3] * 4 + m;
      float xv0 = x0[s0], av0 = agg0[s0];
      float xv1 = x0[s1], av1 = agg0[s1];
      float xv2 = x0[s2], av2 = agg0[s2];
      float xv3 = x0[s3], av3 = agg0[s3];
      a0 = add4(a0, conv0f(xv0, av0, ws, wn));
      a1 = add4(a1, conv0f(xv1, av1, ws, wn));
      a2 = add4(a2, conv0f(xv2, av2, ws, wn));
      a3 = add4(a3, conv0f(xv3, av3, ws, wn));
    }
    for (; i < end; ++i) {
      int s0 = nbr[i] * 4 + m;
      a0 = add4(a0, conv0f(x0[s0], agg0[s0], ws, wn));
    }
    gacc[q] = add4(add4(a0, a1), add4(a2, a3));
  }
  __syncthreads();

  // P1: x0f @ Ws1
  float4 acc[2];
  acc[0] = acc[1] = make_float4(0.f, 0.f, 0.f, 0.f);
  MACC2(XA, acc);
  __syncthreads();
#pragma unroll
  for (int q = 0; q < 2; ++q) {                      // commit XA=agg1, Wl=Wn1
    int rr = tr + (q << 5);
    *(float4*)&XA[rr][tc4] = gacc[q];
    *(float4*)&Wl[rr][tc4] = *(const float4*)(Wn1 + rr * 64 + tc4);
  }
  __syncthreads();

  // P2: agg1 @ Wn1
  MACC2(XA, acc);

#pragma unroll
  for (int i = 0; i < 2; ++i)
    *(float4*)(x1 + (size_t)(row0 + r0 + i) * 64 + tc4) = relu4(acc[i]);
}

// ---------- fused conv2 + 3-layer MLP + mean + min/max (512 thr, gather fused) ----------
//   P1 x1@Ws2->acc1 | P2 x1@W1b->acc2 | P3 agg2@Wn2->acc1, x2=relu(acc1)
//   P4 x2@W1c->acc2 | P5 x0f@W1a->acc2, h1=relu | P6 h1@W2 | P7 h2@W3

__global__ __launch_bounds__(512, 8) void fused2_k(const float* __restrict__ x1,
    const int* __restrict__ rowstart, const int* __restrict__ nbr,
    const float* __restrict__ x0, const float* __restrict__ agg0,
    const float* __restrict__ Ws0, const float* __restrict__ Wn0,
    const float* __restrict__ Ws2, const float* __restrict__ Wn2,
    const float* __restrict__ W1, const float* __restrict__ b1,
    const float* __restrict__ W2, const float* __restrict__ b2,
    const float* __restrict__ W3, const float* __restrict__ b3,
    float* __restrict__ g, unsigned* __restrict__ mm) {
  __shared__ float XA[64][68];
  __shared__ float Wl[64][64];
  __shared__ float red[16];
  const int row0 = blockIdx.x << 6;
  const int nb0  = blockIdx.x << 4;
  const int tid = threadIdx.x;
  const int tc4 = (tid & 15) << 2;
  const int tr  = tid >> 4;          // 0..31
  const int r0  = tr << 1;

  float4 gacc[2], acc1[2], acc2[2];

  // ---- prologue: XA <- x1, Wl <- Ws2 ----
#pragma unroll
  for (int q = 0; q < 2; ++q) {
    int rr = tr + (q << 5);
    *(float4*)&XA[rr][tc4] = *(const float4*)(x1 + (size_t)(row0 + rr) * 64 + tc4);
    *(float4*)&Wl[rr][tc4] = *(const float4*)(Ws2 + rr * 64 + tc4);
  }

  // ---- gather agg2 from x1 (2 nodes/thread, 4-deep MLP) ----
#pragma unroll
  for (int q = 0; q < 2; ++q) {
    int rr = tr + (q << 5);
    int n = nb0 + (rr >> 2), m = rr & 3;
    int beg = rowstart[n], end = rowstart[n + 1];
    float4 a0 = {0.f,0.f,0.f,0.f}, a1 = {0.f,0.f,0.f,0.f};
    float4 a2 = {0.f,0.f,0.f,0.f}, a3 = {0.f,0.f,0.f,0.f};
    int i = beg;
    for (; i + 4 <= end; i += 4) {
      float4 v0 = *(const float4*)(x1 + (size_t)(nbr[i]   * 4 + m) * 64 + tc4);
      float4 v1 = *(const float4*)(x1 + (size_t)(nbr[i+1] * 4 + m) * 64 + tc4);
      float4 v2 = *(const float4*)(x1 + (size_t)(nbr[i+2] * 4 + m) * 64 + tc4);
      float4 v3 = *(const float4*)(x1 + (size_t)(nbr[i+3] * 4 + m) * 64 + tc4);
      a0 = add4(a0, v0); a1 = add4(a1, v1); a2 = add4(a2, v2); a3 = add4(a3, v3);
    }
    for (; i < end; ++i)
      a0 = add4(a0, *(const float4*)(x1 + (size_t)(nbr[i] * 4 + m) * 64 + tc4));
    gacc[q] = add4(add4(a0, a1), add4(a2, a3));
  }
  __syncthreads();

  // ---- P1: acc1 = x1 @ Ws2 ----
  acc1[0] = acc1[1] = make_float4(0.f, 0.f, 0.f, 0.f);
  MACC2(XA, acc1);
  __syncthreads();
#pragma unroll
  for (int q = 0; q < 2; ++q) {                      // commit W1b (XA untouched)
    int rr = tr + (q << 5);
    *(float4*)&Wl[rr][tc4] = *(const float4*)(W1 + (64 + rr) * 64 + tc4);
  }
  __syncthreads();

  // ---- P2: acc2 = b1 + x1 @ W1b ----
  {
    float4 bb = *(const float4*)(b1 + tc4);
    acc2[0] = acc2[1] = bb;
  }
  MACC2(XA, acc2);
  __syncthreads();
#pragma unroll
  for (int q = 0; q < 2; ++q) {                      // commit XA=agg2, Wl=Wn2
    int rr = tr + (q << 5);
    *(float4*)&XA[rr][tc4] = gacc[q];
    *(float4*)&Wl[rr][tc4] = *(const float4*)(Wn2 + rr * 64 + tc4);
  }
  __syncthreads();

  // ---- P3: acc1 += agg2 @ Wn2 ; x2 = relu(acc1) ----
  MACC2(XA, acc1);
  __syncthreads();
#pragma unroll
  for (int i = 0; i < 2; ++i)                        // x2 -> XA
    *(float4*)&XA[r0 + i][tc4] = relu4(acc1[i]);
#pragma unroll
  for (int q = 0; q < 2; ++q) {                      // commit W1c
    int rr = tr + (q << 5);
    *(float4*)&Wl[rr][tc4] = *(const float4*)(W1 + (128 + rr) * 64 + tc4);
  }
  __syncthreads();

  // ---- P4: acc2 += x2 @ W1c ----
  MACC2(XA, acc2);
  __syncthreads();
  {
    float4 ws = *(const float4*)(Ws0 + tc4);
    float4 wn = *(const float4*)(Wn0 + tc4);
#pragma unroll
    for (int q = 0; q < 2; ++q) {                    // commit XA = x0feat, Wl = W1a
      int rr = tr + (q << 5);
      *(float4*)&XA[rr][tc4] = conv0f(x0[row0 + rr], agg0[row0 + rr], ws, wn);
      *(float4*)&Wl[rr][tc4] = *(const float4*)(W1 + rr * 64 + tc4);
    }
  }
  __syncthreads();

  // ---- P5: acc2 += x0f @ W1a ; h1 = relu(acc2) ----
  MACC2(XA, acc2);
  __syncthreads();
#pragma unroll
  for (int i = 0; i < 2; ++i)                        // h1 -> XA
    *(float4*)&XA[r0 + i][tc4] = relu4(acc2[i]);
#pragma unroll
  for (int q = 0; q < 2; ++q) {                      // commit W2
    int rr = tr + (q << 5);
    *(float4*)&Wl[rr][tc4] = *(const float4*)(W2 + rr * 64 + tc4);
  }
  __syncthreads();

  // ---- P6: acc1 = b2 + h1 @ W2 ; h2 = relu ----
  {
    float4 bb = *(const float4*)(b2 + tc4);
    acc1[0] = acc1[1] = bb;
  }
  MACC2(XA, acc1);
  __syncthreads();
#pragma unroll
  for (int i = 0; i < 2; ++i)                        // h2 -> XA
    *(float4*)&XA[r0 + i][tc4] = relu4(acc1[i]);
#pragma unroll
  for (int q = 0; q < 2; ++q) {                      // commit W3
    int rr = tr + (q << 5);
    *(float4*)&Wl[rr][tc4] = *(const float4*)(W3 + rr * 64 + tc4);
  }
  __syncthreads();

  // ---- P7: acc2 = b3 + h2 @ W3 (no relu) ----
  {
    float4 bb = *(const float4*)(b3 + tc4);
    acc2[0] = acc2[1] = bb;
  }
  MACC2(XA, acc2);
  __syncthreads();
#pragma unroll
  for (int i = 0; i < 2; ++i)
    *(float4*)&XA[r0 + i][tc4] = acc2[i];            // h3 -> XA
  __syncthreads();

  // ---- mean over M + per-block min/max ----
  float lmin = 3.4e38f, lmax = -3.4e38f;
  for (int k = tid; k < 1024; k += 512) {
    int nl = k >> 6, c = k & 63;
    float s = 0.25f * (XA[4*nl][c] + XA[4*nl+1][c] + XA[4*nl+2][c] + XA[4*nl+3][c]);
    g[(size_t)((row0 >> 2) + nl) * 64 + c] = s;
    lmin = fminf(lmin, s);
    lmax = fmaxf(lmax, s);
  }
#pragma unroll
  for (int off = 32; off; off >>= 1) {
    lmin = fminf(lmin, __shfl_xor(lmin, off));
    lmax = fmaxf(lmax, __shfl_xor(lmax, off));
  }
  if ((tid & 63) == 0) { red[tid >> 6] = lmin; red[8 + (tid >> 6)] = lmax; }
  __syncthreads();
  if (tid == 0) {
    float m0 = red[0], m1 = red[8];
#pragma unroll
    for (int w = 1; w < 8; ++w) {
      m0 = fminf(m0, red[w]);
      m1 = fmaxf(m1, red[8 + w]);
    }
    atomicMin(&mm[0], enc_f(m0));
    atomicMax(&mm[1], enc_f(m1));
  }
}

// ---------- rescale + pool (sorted batch -> run-length accumulate) ----------

__global__ __launch_bounds__(256) void pool2_k(const float* __restrict__ g,
                                               const int* __restrict__ batch,
                                               const unsigned* __restrict__ mm,
                                               float* __restrict__ pooled) {
  int c = threadIdx.x & 63;
  int grp = threadIdx.x >> 6;                        // 0..3
  int base = blockIdx.x * 64 + grp * 16;             // 16 consecutive nodes per group
  float gmin = dec_f(mm[0]);
  float sc = 2.0f / (dec_f(mm[1]) - gmin);
  float acc = 0.0f; int cur = -1;
  for (int i = 0; i < 16; ++i) {
    int n = base + i;
    if (n >= NN) break;
    int b = batch[n];
    if (b != cur) {
      if (cur >= 0) unsafeAtomicAdd(&pooled[(cur << 6) + c], acc);
      cur = b; acc = 0.0f;
    }
    acc += (g[(size_t)n * 64 + c] - gmin) * sc;
  }
  if (cur >= 0) unsafeAtomicAdd(&pooled[(cur << 6) + c], acc);
}

// ---------- out[b] = pooled[b,:] . Wo + bo ----------

__global__ void out_k(const float* __restrict__ pooled, const float* __restrict__ Wo,
                      const float* __restrict__ bo, float* __restrict__ out) {
  int b = blockIdx.x, l = threadIdx.x;
  float v = pooled[(b << 6) + l] * Wo[l];
#pragma unroll
  for (int off = 32; off; off >>= 1) v += __shfl_xor(v, off);
  if (l == 0) out[b] = v + bo[0];
}

// ---------- launch ----------

extern "C" void kernel_launch(void* const* d_in, const int* in_sizes, int n_in,
                              void* d_out, int out_size, void* d_ws, size_t ws_size,
                              hipStream_t stream) {
  const float* x0   = (const float*)d_in[0];
  const int*   ei   = (const int*)d_in[1];
  const int*   batch= (const int*)d_in[2];
  const float* Ws0  = (const float*)d_in[3];
  const float* Wn0  = (const float*)d_in[4];
  const float* Ws1  = (const float*)d_in[5];
  const float* Wn1  = (const float*)d_in[6];
  const float* Ws2  = (const float*)d_in[7];
  const float* Wn2  = (const float*)d_in[8];
  const float* W1   = (const float*)d_in[9];
  const float* b1   = (const float*)d_in[10];
  const float* W2   = (const float*)d_in[11];
  const float* b2   = (const float*)d_in[12];
  const float* W3   = (const float*)d_in[13];
  const float* b3   = (const float*)d_in[14];
  const float* Wo   = (const float*)d_in[15];
  const float* bo   = (const float*)d_in[16];
  float* out = (float*)d_out;

  float* x1     = (float*)d_ws;                       // [NROWS,64]
  float* agg0   = x1   + (size_t)NROWS * 64;          // [NROWS]
  float* g      = agg0 + NROWS;                       // [NN,64]
  float* pooled = g    + (size_t)NN * 64;             // [BB,64]
  unsigned* mm  = (unsigned*)(pooled + BB * 64);      // [2]
  int* deg      = (int*)(mm + 2);                     // [NN]
  int* rowstart = deg + NN;                           // [NN+1]
  int* cursor   = rowstart + NN + 1;                  // [NN]
  int* nbr      = cursor + NN;                        // [EE]
  int* bsum     = nbr + EE;                           // [NBLK_SCAN]

  // ---- CSR build ----
  hipMemsetAsync(deg, 0, NN * sizeof(int), stream);
  hist_k<<<(EE + 255) / 256, 256, 0, stream>>>(ei, deg);
  scan1_k<<<NBLK_SCAN, 512, 0, stream>>>(deg, rowstart, bsum);
  scan2_k<<<1, 64, 0, stream>>>(bsum);
  scan3_k<<<NBLK_SCAN, 512, 0, stream>>>(rowstart, cursor, bsum);
  fill_k<<<(EE + 255) / 256, 256, 0, stream>>>(ei, cursor, nbr);

  // ---- layer 0 aggregate (scalar) ----
  agg0_gather_k<<<(NROWS + 255) / 256, 256, 0, stream>>>(x0, rowstart, nbr, agg0);

  // ---- layer 1 (agg1 gather fused) -> x1 ----
  conv1_k<<<NROWS / 64, 512, 0, stream>>>(x0, agg0, rowstart, nbr,
                                          Ws0, Wn0, Ws1, Wn1, x1);

  // ---- fused conv2 + MLP + mean + min/max (agg2 gather fused) ----
  hipMemsetAsync(mm, 0xFF, 4, stream);
  hipMemsetAsync(mm + 1, 0x00, 4, stream);
  fused2_k<<<NROWS / 64, 512, 0, stream>>>(x1, rowstart, nbr, x0, agg0,
                                           Ws0, Wn0, Ws2, Wn2,
                                           W1, b1, W2, b2, W3, b3, g, mm);

  // ---- rescale + pooling ----
  hipMemsetAsync(pooled, 0, BB * 64 * sizeof(float), stream);
  pool2_k<<<(NN + 63) / 64, 256, 0, stream>>>(g, batch, mm, pooled);

  // ---- output linear ----
  out_k<<<BB, 64, 0, stream>>>(pooled, Wo, bo, out);
}

// Round 9
// 361.966 us; speedup vs baseline: 13.3004x; 1.0497x over previous
//
#include <hip/hip_runtime.h>
#include <math.h>

#define NN 50000
#define MM 4
#define EE 400000
#define BB 64
#define NROWS (NN*MM)           // 200000
#define NBLK_SCAN 98            // ceil(50000/512)

// ---------- helpers ----------

__device__ __forceinline__ unsigned enc_f(float f) {
  unsigned u = __float_as_uint(f);
  return (u & 0x80000000u) ? ~u : (u | 0x80000000u);
}
__device__ __forceinline__ float dec_f(unsigned u) {
  return (u & 0x80000000u) ? __uint_as_float(u ^ 0x80000000u) : __uint_as_float(~u);
}

__device__ __forceinline__ void axpy4(float4& a, float s, float4 w) {
  a.x = fmaf(s, w.x, a.x);
  a.y = fmaf(s, w.y, a.y);
  a.z = fmaf(s, w.z, a.z);
  a.w = fmaf(s, w.w, a.w);
}
__device__ __forceinline__ float4 relu4(float4 v) {
  return make_float4(fmaxf(v.x, 0.f), fmaxf(v.y, 0.f), fmaxf(v.z, 0.f), fmaxf(v.w, 0.f));
}
__device__ __forceinline__ float4 add4(float4 a, float4 b) {
  return make_float4(a.x + b.x, a.y + b.y, a.z + b.z, a.w + b.w);
}
__device__ __forceinline__ float4 conv0f(float xv, float av, float4 ws, float4 wn) {
  float4 t;
  t.x = fmaxf(fmaf(xv, ws.x, av * wn.x), 0.f);
  t.y = fmaxf(fmaf(xv, ws.y, av * wn.y), 0.f);
  t.z = fmaxf(fmaf(xv, ws.z, av * wn.z), 0.f);
  t.w = fmaxf(fmaf(xv, ws.w, av * wn.w), 0.f);
  return t;
}

// bf16 pack/unpack (RNE)
__device__ __forceinline__ unsigned short bf16rn(float f) {
  unsigned u = __float_as_uint(f);
  return (unsigned short)((u + 0x7FFFu + ((u >> 16) & 1u)) >> 16);
}
__device__ __forceinline__ float bf2f(unsigned short h) {
  return __uint_as_float(((unsigned)h) << 16);
}
__device__ __forceinline__ float4 b2f4(ushort4 h) {
  return make_float4(bf2f(h.x), bf2f(h.y), bf2f(h.z), bf2f(h.w));
}

// 2x4 micro-tiled LDS GEMM step (512-thread blocks). X reads: 4-addr broadcast;
// W reads: 16x16B row slice. Conflict-free (row strides 136/68 dw = 8/4 mod 32).
#define MACC2(XS, A)                                                  \
  _Pragma("unroll 2")                                                 \
  for (int k = 0; k < 64; k += 4) {                                   \
    float4 xa = *(const float4*)&XS[r0 + 0][k];                       \
    float4 xb = *(const float4*)&XS[r0 + 1][k];                       \
    float4 w0 = *(const float4*)&Wl[k + 0][tc4];                      \
    float4 w1 = *(const float4*)&Wl[k + 1][tc4];                      \
    float4 w2 = *(const float4*)&Wl[k + 2][tc4];                      \
    float4 w3 = *(const float4*)&Wl[k + 3][tc4];                      \
    axpy4(A[0], xa.x, w0); axpy4(A[0], xa.y, w1); axpy4(A[0], xa.z, w2); axpy4(A[0], xa.w, w3); \
    axpy4(A[1], xb.x, w0); axpy4(A[1], xb.y, w1); axpy4(A[1], xb.z, w2); axpy4(A[1], xb.w, w3); \
  }

// ---------- CSR build (dst-major neighbor lists) ----------

__global__ void hist_k(const int* __restrict__ ei, int* __restrict__ deg) {
  int e = blockIdx.x * blockDim.x + threadIdx.x;
  if (e < EE) atomicAdd(&deg[ei[EE + e]], 1);
}

__global__ __launch_bounds__(512) void scan1_k(const int* __restrict__ deg,
                                               int* __restrict__ rowstart,
                                               int* __restrict__ bsum) {
  __shared__ int s[512];
  int i = blockIdx.x * 512 + threadIdx.x;
  int v = (i < NN) ? deg[i] : 0;
  s[threadIdx.x] = v;
  __syncthreads();
  for (int off = 1; off < 512; off <<= 1) {
    int t = (threadIdx.x >= (unsigned)off) ? s[threadIdx.x - off] : 0;
    __syncthreads();
    s[threadIdx.x] += t;
    __syncthreads();
  }
  if (i < NN) rowstart[i] = s[threadIdx.x] - v;      // exclusive partial
  if (threadIdx.x == 511) bsum[blockIdx.x] = s[511];
}

__global__ void scan2_k(int* __restrict__ bsum) {
  if (threadIdx.x == 0) {
    int acc = 0;
    for (int k = 0; k < NBLK_SCAN; ++k) { int t = bsum[k]; bsum[k] = acc; acc += t; }
  }
}

__global__ __launch_bounds__(512) void scan3_k(int* __restrict__ rowstart,
                                               int* __restrict__ cursor,
                                               const int* __restrict__ bsum) {
  int i = blockIdx.x * 512 + threadIdx.x;
  if (i < NN) {
    int v = rowstart[i] + bsum[blockIdx.x];
    rowstart[i] = v;
    cursor[i] = v;
  }
  if (i == 0) rowstart[NN] = EE;
}

__global__ void fill_k(const int* __restrict__ ei, int* __restrict__ cursor,
                       int* __restrict__ nbr) {
  int e = blockIdx.x * blockDim.x + threadIdx.x;
  if (e >= EE) return;
  int d = ei[EE + e];
  int p = atomicAdd(&cursor[d], 1);
  nbr[p] = ei[e];
}

// ---------- aggregation 0: agg0[n*4+m] = sum_{s in N(n)} x0[s*4+m] ----------

__global__ void agg0_gather_k(const float* __restrict__ x0,
                              const int* __restrict__ rowstart,
                              const int* __restrict__ nbr,
                              float* __restrict__ agg0) {
  int idx = blockIdx.x * blockDim.x + threadIdx.x;   // NROWS
  if (idx >= NROWS) return;
  int n = idx >> 2, m = idx & 3;
  int beg = rowstart[n], end = rowstart[n + 1];
  float acc = 0.0f;
  for (int i = beg; i < end; ++i) acc += x0[nbr[i] * 4 + m];
  agg0[idx] = acc;
}

// ---------- conv1 (gather fused, 512 thr): x1 = relu(x0f@Ws1 + agg1@Wn1) -> bf16 ----------

__global__ __launch_bounds__(512, 8) void conv1_k(const float* __restrict__ x0,
                                                  const float* __restrict__ agg0,
                                                  const int* __restrict__ rowstart,
                                                  const int* __restrict__ nbr,
                                                  const float* __restrict__ Ws0,
                                                  const float* __restrict__ Wn0,
                                                  const float* __restrict__ Ws1,
                                                  const float* __restrict__ Wn1,
                                                  unsigned short* __restrict__ x1b) {
  __shared__ float XA[64][68];
  __shared__ float Wl[64][64];
  const int row0 = blockIdx.x << 6;
  const int nb0  = blockIdx.x << 4;
  const int tid = threadIdx.x;
  const int tc4 = (tid & 15) << 2;
  const int tr  = tid >> 4;          // 0..31
  const int r0  = tr << 1;

  float4 ws = *(const float4*)(Ws0 + tc4);
  float4 wn = *(const float4*)(Wn0 + tc4);

  // stage XA = x0feat (recomputed), Wl = Ws1
#pragma unroll
  for (int q = 0; q < 2; ++q) {
    int rr = tr + (q << 5);
    *(float4*)&XA[rr][tc4] = conv0f(x0[row0 + rr], agg0[row0 + rr], ws, wn);
    *(float4*)&Wl[rr][tc4] = *(const float4*)(Ws1 + rr * 64 + tc4);
  }

  // gather agg1 (2 nodes/thread, unroll 4 for MLP)
  float4 gacc[2];
#pragma unroll
  for (int q = 0; q < 2; ++q) {
    int rr = tr + (q << 5);
    int n = nb0 + (rr >> 2), m = rr & 3;
    int beg = rowstart[n], end = rowstart[n + 1];
    float4 a0 = {0.f,0.f,0.f,0.f}, a1 = {0.f,0.f,0.f,0.f};
    float4 a2 = {0.f,0.f,0.f,0.f}, a3 = {0.f,0.f,0.f,0.f};
    int i = beg;
    for (; i + 4 <= end; i += 4) {
      int s0 = nbr[i] * 4 + m, s1 = nbr[i+1] * 4 + m;
      int s2 = nbr[i+2] * 4 + m, s3 = nbr[i+3] * 4 + m;
      float xv0 = x0[s0], av0 = agg0[s0];
      float xv1 = x0[s1], av1 = agg0[s1];
      float xv2 = x0[s2], av2 = agg0[s2];
      float xv3 = x0[s3], av3 = agg0[s3];
      a0 = add4(a0, conv0f(xv0, av0, ws, wn));
      a1 = add4(a1, conv0f(xv1, av1, ws, wn));
      a2 = add4(a2, conv0f(xv2, av2, ws, wn));
      a3 = add4(a3, conv0f(xv3, av3, ws, wn));
    }
    for (; i < end; ++i) {
      int s0 = nbr[i] * 4 + m;
      a0 = add4(a0, conv0f(x0[s0], agg0[s0], ws, wn));
    }
    gacc[q] = add4(add4(a0, a1), add4(a2, a3));
  }
  __syncthreads();

  // P1: x0f @ Ws1
  float4 acc[2];
  acc[0] = acc[1] = make_float4(0.f, 0.f, 0.f, 0.f);
  MACC2(XA, acc);
  __syncthreads();
#pragma unroll
  for (int q = 0; q < 2; ++q) {                      // commit XA=agg1, Wl=Wn1
    int rr = tr + (q << 5);
    *(float4*)&XA[rr][tc4] = gacc[q];
    *(float4*)&Wl[rr][tc4] = *(const float4*)(Wn1 + rr * 64 + tc4);
  }
  __syncthreads();

  // P2: agg1 @ Wn1
  MACC2(XA, acc);

#pragma unroll
  for (int i = 0; i < 2; ++i) {
    float4 v = relu4(acc[i]);
    ushort4 h;
    h.x = bf16rn(v.x); h.y = bf16rn(v.y); h.z = bf16rn(v.z); h.w = bf16rn(v.w);
    *(ushort4*)(x1b + (size_t)(row0 + r0 + i) * 64 + tc4) = h;
  }
}

// ---------- fused conv2 + 3-layer MLP + mean + min/max (512 thr, bf16 x1 gather) ----------
//   P1 x1@Ws2->acc1 | P2 x1@W1b->acc2 | P3 agg2@Wn2->acc1, x2=relu(acc1)
//   P4 x2@W1c->acc2 | P5 x0f@W1a->acc2, h1=relu | P6 h1@W2 | P7 h2@W3

__global__ __launch_bounds__(512, 8) void fused2_k(const unsigned short* __restrict__ x1b,
    const int* __restrict__ rowstart, const int* __restrict__ nbr,
    const float* __restrict__ x0, const float* __restrict__ agg0,
    const float* __restrict__ Ws0, const float* __restrict__ Wn0,
    const float* __restrict__ Ws2, const float* __restrict__ Wn2,
    const float* __restrict__ W1, const float* __restrict__ b1,
    const float* __restrict__ W2, const float* __restrict__ b2,
    const float* __restrict__ W3, const float* __restrict__ b3,
    float* __restrict__ g, unsigned* __restrict__ mm) {
  __shared__ float XA[64][68];
  __shared__ float Wl[64][64];
  __shared__ float red[16];
  const int row0 = blockIdx.x << 6;
  const int nb0  = blockIdx.x << 4;
  const int tid = threadIdx.x;
  const int tc4 = (tid & 15) << 2;
  const int tr  = tid >> 4;          // 0..31
  const int r0  = tr << 1;

  float4 gacc[2], acc1[2], acc2[2];

  // ---- prologue: XA <- x1 (bf16->f32), Wl <- Ws2 ----
#pragma unroll
  for (int q = 0; q < 2; ++q) {
    int rr = tr + (q << 5);
    ushort4 h = *(const ushort4*)(x1b + (size_t)(row0 + rr) * 64 + tc4);
    *(float4*)&XA[rr][tc4] = b2f4(h);
    *(float4*)&Wl[rr][tc4] = *(const float4*)(Ws2 + rr * 64 + tc4);
  }

  // ---- gather agg2 from bf16 x1 (2 nodes/thread, 4-deep MLP) ----
#pragma unroll
  for (int q = 0; q < 2; ++q) {
    int rr = tr + (q << 5);
    int n = nb0 + (rr >> 2), m = rr & 3;
    int beg = rowstart[n], end = rowstart[n + 1];
    float4 a0 = {0.f,0.f,0.f,0.f}, a1 = {0.f,0.f,0.f,0.f};
    float4 a2 = {0.f,0.f,0.f,0.f}, a3 = {0.f,0.f,0.f,0.f};
    int i = beg;
    for (; i + 4 <= end; i += 4) {
      ushort4 v0 = *(const ushort4*)(x1b + (size_t)(nbr[i]   * 4 + m) * 64 + tc4);
      ushort4 v1 = *(const ushort4*)(x1b + (size_t)(nbr[i+1] * 4 + m) * 64 + tc4);
      ushort4 v2 = *(const ushort4*)(x1b + (size_t)(nbr[i+2] * 4 + m) * 64 + tc4);
      ushort4 v3 = *(const ushort4*)(x1b + (size_t)(nbr[i+3] * 4 + m) * 64 + tc4);
      a0 = add4(a0, b2f4(v0)); a1 = add4(a1, b2f4(v1));
      a2 = add4(a2, b2f4(v2)); a3 = add4(a3, b2f4(v3));
    }
    for (; i < end; ++i)
      a0 = add4(a0, b2f4(*(const ushort4*)(x1b + (size_t)(nbr[i] * 4 + m) * 64 + tc4)));
    gacc[q] = add4(add4(a0, a1), add4(a2, a3));
  }
  __syncthreads();

  // ---- P1: acc1 = x1 @ Ws2 ----
  acc1[0] = acc1[1] = make_float4(0.f, 0.f, 0.f, 0.f);
  MACC2(XA, acc1);
  __syncthreads();
#pragma unroll
  for (int q = 0; q < 2; ++q) {                      // commit W1b (XA untouched)
    int rr = tr + (q << 5);
    *(float4*)&Wl[rr][tc4] = *(const float4*)(W1 + (64 + rr) * 64 + tc4);
  }
  __syncthreads();

  // ---- P2: acc2 = b1 + x1 @ W1b ----
  {
    float4 bb = *(const float4*)(b1 + tc4);
    acc2[0] = acc2[1] = bb;
  }
  MACC2(XA, acc2);
  __syncthreads();
#pragma unroll
  for (int q = 0; q < 2; ++q) {                      // commit XA=agg2, Wl=Wn2
    int rr = tr + (q << 5);
    *(float4*)&XA[rr][tc4] = gacc[q];
    *(float4*)&Wl[rr][tc4] = *(const float4*)(Wn2 + rr * 64 + tc4);
  }
  __syncthreads();

  // ---- P3: acc1 += agg2 @ Wn2 ; x2 = relu(acc1) ----
  MACC2(XA, acc1);
  __syncthreads();
#pragma unroll
  for (int i = 0; i < 2; ++i)                        // x2 -> XA
    *(float4*)&XA[r0 + i][tc4] = relu4(acc1[i]);
#pragma unroll
  for (int q = 0; q < 2; ++q) {                      // commit W1c
    int rr = tr + (q << 5);
    *(float4*)&Wl[rr][tc4] = *(const float4*)(W1 + (128 + rr) * 64 + tc4);
  }
  __syncthreads();

  // ---- P4: acc2 += x2 @ W1c ----
  MACC2(XA, acc2);
  __syncthreads();
  {
    float4 ws = *(const float4*)(Ws0 + tc4);
    float4 wn = *(const float4*)(Wn0 + tc4);
#pragma unroll
    for (int q = 0; q < 2; ++q) {                    // commit XA = x0feat, Wl = W1a
      int rr = tr + (q << 5);
      *(float4*)&XA[rr][tc4] = conv0f(x0[row0 + rr], agg0[row0 + rr], ws, wn);
      *(float4*)&Wl[rr][tc4] = *(const float4*)(W1 + rr * 64 + tc4);
    }
  }
  __syncthreads();

  // ---- P5: acc2 += x0f @ W1a ; h1 = relu(acc2) ----
  MACC2(XA, acc2);
  __syncthreads();
#pragma unroll
  for (int i = 0; i < 2; ++i)                        // h1 -> XA
    *(float4*)&XA[r0 + i][tc4] = relu4(acc2[i]);
#pragma unroll
  for (int q = 0; q < 2; ++q) {                      // commit W2
    int rr = tr + (q << 5);
    *(float4*)&Wl[rr][tc4] = *(const float4*)(W2 + rr * 64 + tc4);
  }
  __syncthreads();

  // ---- P6: acc1 = b2 + h1 @ W2 ; h2 = relu ----
  {
    float4 bb = *(const float4*)(b2 + tc4);
    acc1[0] = acc1[1] = bb;
  }
  MACC2(XA, acc1);
  __syncthreads();
#pragma unroll
  for (int i = 0; i < 2; ++i)                        // h2 -> XA
    *(float4*)&XA[r0 + i][tc4] = relu4(acc1[i]);
#pragma unroll
  for (int q = 0; q < 2; ++q) {                      // commit W3
    int rr = tr + (q << 5);
    *(float4*)&Wl[rr][tc4] = *(const float4*)(W3 + rr * 64 + tc4);
  }
  __syncthreads();

  // ---- P7: acc2 = b3 + h2 @ W3 (no relu) ----
  {
    float4 bb = *(const float4*)(b3 + tc4);
    acc2[0] = acc2[1] = bb;
  }
  MACC2(XA, acc2);
  __syncthreads();
#pragma unroll
  for (int i = 0; i < 2; ++i)
    *(float4*)&XA[r0 + i][tc4] = acc2[i];            // h3 -> XA
  __syncthreads();

  // ---- mean over M + per-block min/max ----
  float lmin = 3.4e38f, lmax = -3.4e38f;
  for (int k = tid; k < 1024; k += 512) {
    int nl = k >> 6, c = k & 63;
    float s = 0.25f * (XA[4*nl][c] + XA[4*nl+1][c] + XA[4*nl+2][c] + XA[4*nl+3][c]);
    g[(size_t)((row0 >> 2) + nl) * 64 + c] = s;
    lmin = fminf(lmin, s);
    lmax = fmaxf(lmax, s);
  }
#pragma unroll
  for (int off = 32; off; off >>= 1) {
    lmin = fminf(lmin, __shfl_xor(lmin, off));
    lmax = fmaxf(lmax, __shfl_xor(lmax, off));
  }
  if ((tid & 63) == 0) { red[tid >> 6] = lmin; red[8 + (tid >> 6)] = lmax; }
  __syncthreads();
  if (tid == 0) {
    float m0 = red[0], m1 = red[8];
#pragma unroll
    for (int w = 1; w < 8; ++w) {
      m0 = fminf(m0, red[w]);
      m1 = fmaxf(m1, red[8 + w]);
    }
    atomicMin(&mm[0], enc_f(m0));
    atomicMax(&mm[1], enc_f(m1));
  }
}

// ---------- rescale + pool (sorted batch -> run-length accumulate) ----------

__global__ __launch_bounds__(256) void pool2_k(const float* __restrict__ g,
                                               const int* __restrict__ batch,
                                               const unsigned* __restrict__ mm,
                                               float* __restrict__ pooled) {
  int c = threadIdx.x & 63;
  int grp = threadIdx.x >> 6;                        // 0..3
  int base = blockIdx.x * 64 + grp * 16;             // 16 consecutive nodes per group
  float gmin = dec_f(mm[0]);
  float sc = 2.0f / (dec_f(mm[1]) - gmin);
  float acc = 0.0f; int cur = -1;
  for (int i = 0; i < 16; ++i) {
    int n = base + i;
    if (n >= NN) break;
    int b = batch[n];
    if (b != cur) {
      if (cur >= 0) unsafeAtomicAdd(&pooled[(cur << 6) + c], acc);
      cur = b; acc = 0.0f;
    }
    acc += (g[(size_t)n * 64 + c] - gmin) * sc;
  }
  if (cur >= 0) unsafeAtomicAdd(&pooled[(cur << 6) + c], acc);
}

// ---------- out[b] = pooled[b,:] . Wo + bo ----------

__global__ void out_k(const float* __restrict__ pooled, const float* __restrict__ Wo,
                      const float* __restrict__ bo, float* __restrict__ out) {
  int b = blockIdx.x, l = threadIdx.x;
  float v = pooled[(b << 6) + l] * Wo[l];
#pragma unroll
  for (int off = 32; off; off >>= 1) v += __shfl_xor(v, off);
  if (l == 0) out[b] = v + bo[0];
}

// ---------- launch ----------

extern "C" void kernel_launch(void* const* d_in, const int* in_sizes, int n_in,
                              void* d_out, int out_size, void* d_ws, size_t ws_size,
                              hipStream_t stream) {
  const float* x0   = (const float*)d_in[0];
  const int*   ei   = (const int*)d_in[1];
  const int*   batch= (const int*)d_in[2];
  const float* Ws0  = (const float*)d_in[3];
  const float* Wn0  = (const float*)d_in[4];
  const float* Ws1  = (const float*)d_in[5];
  const float* Wn1  = (const float*)d_in[6];
  const float* Ws2  = (const float*)d_in[7];
  const float* Wn2  = (const float*)d_in[8];
  const float* W1   = (const float*)d_in[9];
  const float* b1   = (const float*)d_in[10];
  const float* W2   = (const float*)d_in[11];
  const float* b2   = (const float*)d_in[12];
  const float* W3   = (const float*)d_in[13];
  const float* b3   = (const float*)d_in[14];
  const float* Wo   = (const float*)d_in[15];
  const float* bo   = (const float*)d_in[16];
  float* out = (float*)d_out;

  unsigned short* x1b = (unsigned short*)d_ws;        // [NROWS,64] bf16
  float* agg0   = (float*)(x1b + (size_t)NROWS * 64); // [NROWS]
  float* g      = agg0 + NROWS;                       // [NN,64]
  float* pooled = g    + (size_t)NN * 64;             // [BB,64]
  unsigned* mm  = (unsigned*)(pooled + BB * 64);      // [2]
  int* deg      = (int*)(mm + 2);                     // [NN]
  int* rowstart = deg + NN;                           // [NN+1]
  int* cursor   = rowstart + NN + 1;                  // [NN]
  int* nbr      = cursor + NN;                        // [EE]
  int* bsum     = nbr + EE;                           // [NBLK_SCAN]

  // ---- CSR build ----
  hipMemsetAsync(deg, 0, NN * sizeof(int), stream);
  hist_k<<<(EE + 255) / 256, 256, 0, stream>>>(ei, deg);
  scan1_k<<<NBLK_SCAN, 512, 0, stream>>>(deg, rowstart, bsum);
  scan2_k<<<1, 64, 0, stream>>>(bsum);
  scan3_k<<<NBLK_SCAN, 512, 0, stream>>>(rowstart, cursor, bsum);
  fill_k<<<(EE + 255) / 256, 256, 0, stream>>>(ei, cursor, nbr);

  // ---- layer 0 aggregate (scalar) ----
  agg0_gather_k<<<(NROWS + 255) / 256, 256, 0, stream>>>(x0, rowstart, nbr, agg0);

  // ---- layer 1 (agg1 gather fused) -> x1 (bf16) ----
  conv1_k<<<NROWS / 64, 512, 0, stream>>>(x0, agg0, rowstart, nbr,
                                          Ws0, Wn0, Ws1, Wn1, x1b);

  // ---- fused conv2 + MLP + mean + min/max (agg2 gather fused, bf16 reads) ----
  hipMemsetAsync(mm, 0xFF, 4, stream);
  hipMemsetAsync(mm + 1, 0x00, 4, stream);
  fused2_k<<<NROWS / 64, 512, 0, stream>>>(x1b, rowstart, nbr, x0, agg0,
                                           Ws0, Wn0, Ws2, Wn2,
                                           W1, b1, W2, b2, W3, b3, g, mm);

  // ---- rescale + pooling ----
  hipMemsetAsync(pooled, 0, BB * 64 * sizeof(float), stream);
  pool2_k<<<(NN + 63) / 64, 256, 0, stream>>>(g, batch, mm, pooled);

  // ---- output linear ----
  out_k<<<BB, 64, 0, stream>>>(pooled, Wo, bo, out);
}

// Round 10
// 348.057 us; speedup vs baseline: 13.8319x; 1.0400x over previous
//
#include <hip/hip_runtime.h>
#include <math.h>

#define NN 50000
#define MM 4
#define EE 400000
#define BB 64
#define NROWS (NN*MM)           // 200000
#define NBLK_SCAN 98            // ceil(50000/512)

// ---------- helpers ----------

__device__ __forceinline__ unsigned enc_f(float f) {
  unsigned u = __float_as_uint(f);
  return (u & 0x80000000u) ? ~u : (u | 0x80000000u);
}
__device__ __forceinline__ float dec_f(unsigned u) {
  return (u & 0x80000000u) ? __uint_as_float(u ^ 0x80000000u) : __uint_as_float(~u);
}

__device__ __forceinline__ void axpy4(float4& a, float s, float4 w) {
  a.x = fmaf(s, w.x, a.x);
  a.y = fmaf(s, w.y, a.y);
  a.z = fmaf(s, w.z, a.z);
  a.w = fmaf(s, w.w, a.w);
}
__device__ __forceinline__ float4 relu4(float4 v) {
  return make_float4(fmaxf(v.x, 0.f), fmaxf(v.y, 0.f), fmaxf(v.z, 0.f), fmaxf(v.w, 0.f));
}
__device__ __forceinline__ float4 add4(float4 a, float4 b) {
  return make_float4(a.x + b.x, a.y + b.y, a.z + b.z, a.w + b.w);
}
__device__ __forceinline__ float4 conv0f(float xv, float av, float4 ws, float4 wn) {
  float4 t;
  t.x = fmaxf(fmaf(xv, ws.x, av * wn.x), 0.f);
  t.y = fmaxf(fmaf(xv, ws.y, av * wn.y), 0.f);
  t.z = fmaxf(fmaf(xv, ws.z, av * wn.z), 0.f);
  t.w = fmaxf(fmaf(xv, ws.w, av * wn.w), 0.f);
  return t;
}

// bf16 pack/unpack (RNE)
__device__ __forceinline__ unsigned short bf16rn(float f) {
  unsigned u = __float_as_uint(f);
  return (unsigned short)((u + 0x7FFFu + ((u >> 16) & 1u)) >> 16);
}
__device__ __forceinline__ float bf2f(unsigned short h) {
  return __uint_as_float(((unsigned)h) << 16);
}
__device__ __forceinline__ float4 b2f4(ushort4 h) {
  return make_float4(bf2f(h.x), bf2f(h.y), bf2f(h.z), bf2f(h.w));
}

// 2x4 micro-tiled LDS GEMM step (512-thread blocks). X reads: 4-addr broadcast;
// W reads: 16x16B row slice. Conflict-free (row strides 136/68 dw = 8/4 mod 32).
#define MACC2(XS, A)                                                  \
  _Pragma("unroll 2")                                                 \
  for (int k = 0; k < 64; k += 4) {                                   \
    float4 xa = *(const float4*)&XS[r0 + 0][k];                       \
    float4 xb = *(const float4*)&XS[r0 + 1][k];                       \
    float4 w0 = *(const float4*)&Wl[k + 0][tc4];                      \
    float4 w1 = *(const float4*)&Wl[k + 1][tc4];                      \
    float4 w2 = *(const float4*)&Wl[k + 2][tc4];                      \
    float4 w3 = *(const float4*)&Wl[k + 3][tc4];                      \
    axpy4(A[0], xa.x, w0); axpy4(A[0], xa.y, w1); axpy4(A[0], xa.z, w2); axpy4(A[0], xa.w, w3); \
    axpy4(A[1], xb.x, w0); axpy4(A[1], xb.y, w1); axpy4(A[1], xb.z, w2); axpy4(A[1], xb.w, w3); \
  }

// ---------- CSR build (dst-major neighbor lists) ----------

__global__ void hist_k(const int* __restrict__ ei, int* __restrict__ deg) {
  int e = blockIdx.x * blockDim.x + threadIdx.x;
  if (e < EE) atomicAdd(&deg[ei[EE + e]], 1);
}

__global__ __launch_bounds__(512) void scan1_k(const int* __restrict__ deg,
                                               int* __restrict__ rowstart,
                                               int* __restrict__ bsum) {
  __shared__ int s[512];
  int i = blockIdx.x * 512 + threadIdx.x;
  int v = (i < NN) ? deg[i] : 0;
  s[threadIdx.x] = v;
  __syncthreads();
  for (int off = 1; off < 512; off <<= 1) {
    int t = (threadIdx.x >= (unsigned)off) ? s[threadIdx.x - off] : 0;
    __syncthreads();
    s[threadIdx.x] += t;
    __syncthreads();
  }
  if (i < NN) rowstart[i] = s[threadIdx.x] - v;      // exclusive partial
  if (threadIdx.x == 511) bsum[blockIdx.x] = s[511];
}

__global__ void scan2_k(int* __restrict__ bsum) {
  if (threadIdx.x == 0) {
    int acc = 0;
    for (int k = 0; k < NBLK_SCAN; ++k) { int t = bsum[k]; bsum[k] = acc; acc += t; }
  }
}

__global__ __launch_bounds__(512) void scan3_k(int* __restrict__ rowstart,
                                               int* __restrict__ cursor,
                                               const int* __restrict__ bsum) {
  int i = blockIdx.x * 512 + threadIdx.x;
  if (i < NN) {
    int v = rowstart[i] + bsum[blockIdx.x];
    rowstart[i] = v;
    cursor[i] = v;
  }
  if (i == 0) rowstart[NN] = EE;
}

__global__ void fill_k(const int* __restrict__ ei, int* __restrict__ cursor,
                       int* __restrict__ nbr) {
  int e = blockIdx.x * blockDim.x + threadIdx.x;
  if (e >= EE) return;
  int d = ei[EE + e];
  int p = atomicAdd(&cursor[d], 1);
  nbr[p] = ei[e];
}

// ---------- aggregation 0: agg0[n*4+m] = sum_{s in N(n)} x0[s*4+m] ----------

__global__ void agg0_gather_k(const float* __restrict__ x0,
                              const int* __restrict__ rowstart,
                              const int* __restrict__ nbr,
                              float* __restrict__ agg0) {
  int idx = blockIdx.x * blockDim.x + threadIdx.x;   // NROWS
  if (idx >= NROWS) return;
  int n = idx >> 2, m = idx & 3;
  int beg = rowstart[n], end = rowstart[n + 1];
  float acc = 0.0f;
  for (int i = beg; i < end; ++i) acc += x0[nbr[i] * 4 + m];
  agg0[idx] = acc;
}

// ---------- conv1 (gather fused, 512 thr): x1 = relu(x0f@Ws1 + agg1@Wn1) -> bf16 ----------

__global__ __launch_bounds__(512, 4) void conv1_k(const float* __restrict__ x0,
                                                  const float* __restrict__ agg0,
                                                  const int* __restrict__ rowstart,
                                                  const int* __restrict__ nbr,
                                                  const float* __restrict__ Ws0,
                                                  const float* __restrict__ Wn0,
                                                  const float* __restrict__ Ws1,
                                                  const float* __restrict__ Wn1,
                                                  unsigned short* __restrict__ x1b) {
  __shared__ float XA[64][68];
  __shared__ float Wl[64][64];
  const int row0 = blockIdx.x << 6;
  const int nb0  = blockIdx.x << 4;
  const int tid = threadIdx.x;
  const int tc4 = (tid & 15) << 2;
  const int tr  = tid >> 4;          // 0..31
  const int r0  = tr << 1;

  float4 ws = *(const float4*)(Ws0 + tc4);
  float4 wn = *(const float4*)(Wn0 + tc4);

  // stage XA = x0feat (recomputed), Wl = Ws1
#pragma unroll
  for (int q = 0; q < 2; ++q) {
    int rr = tr + (q << 5);
    *(float4*)&XA[rr][tc4] = conv0f(x0[row0 + rr], agg0[row0 + rr], ws, wn);
    *(float4*)&Wl[rr][tc4] = *(const float4*)(Ws1 + rr * 64 + tc4);
  }

  // gather agg1 (2 nodes/thread, unroll 4 for MLP)
  float4 gacc[2];
#pragma unroll
  for (int q = 0; q < 2; ++q) {
    int rr = tr + (q << 5);
    int n = nb0 + (rr >> 2), m = rr & 3;
    int beg = rowstart[n], end = rowstart[n + 1];
    float4 a0 = {0.f,0.f,0.f,0.f}, a1 = {0.f,0.f,0.f,0.f};
    float4 a2 = {0.f,0.f,0.f,0.f}, a3 = {0.f,0.f,0.f,0.f};
    int i = beg;
    for (; i + 4 <= end; i += 4) {
      int s0 = nbr[i] * 4 + m, s1 = nbr[i+1] * 4 + m;
      int s2 = nbr[i+2] * 4 + m, s3 = nbr[i+3] * 4 + m;
      float xv0 = x0[s0], av0 = agg0[s0];
      float xv1 = x0[s1], av1 = agg0[s1];
      float xv2 = x0[s2], av2 = agg0[s2];
      float xv3 = x0[s3], av3 = agg0[s3];
      a0 = add4(a0, conv0f(xv0, av0, ws, wn));
      a1 = add4(a1, conv0f(xv1, av1, ws, wn));
      a2 = add4(a2, conv0f(xv2, av2, ws, wn));
      a3 = add4(a3, conv0f(xv3, av3, ws, wn));
    }
    for (; i < end; ++i) {
      int s0 = nbr[i] * 4 + m;
      a0 = add4(a0, conv0f(x0[s0], agg0[s0], ws, wn));
    }
    gacc[q] = add4(add4(a0, a1), add4(a2, a3));
  }
  __syncthreads();

  // P1: x0f @ Ws1
  float4 acc[2];
  acc[0] = acc[1] = make_float4(0.f, 0.f, 0.f, 0.f);
  MACC2(XA, acc);
  __syncthreads();
#pragma unroll
  for (int q = 0; q < 2; ++q) {                      // commit XA=agg1, Wl=Wn1
    int rr = tr + (q << 5);
    *(float4*)&XA[rr][tc4] = gacc[q];
    *(float4*)&Wl[rr][tc4] = *(const float4*)(Wn1 + rr * 64 + tc4);
  }
  __syncthreads();

  // P2: agg1 @ Wn1
  MACC2(XA, acc);

#pragma unroll
  for (int i = 0; i < 2; ++i) {
    float4 v = relu4(acc[i]);
    ushort4 h;
    h.x = bf16rn(v.x); h.y = bf16rn(v.y); h.z = bf16rn(v.z); h.w = bf16rn(v.w);
    *(ushort4*)(x1b + (size_t)(row0 + r0 + i) * 64 + tc4) = h;
  }
}

// ---------- fused conv2 + 3-layer MLP + mean + min/max (512 thr, bf16 x1 gather) ----------
//   P1 x1@Ws2->acc1 | P2 x1@W1b->acc2 | P3 agg2@Wn2->acc1, x2=relu(acc1)
//   P4 x2@W1c->acc2 | P5 x0f@W1a->acc2, h1=relu | P6 h1@W2 | P7 h2@W3

__global__ __launch_bounds__(512, 4) void fused2_k(const unsigned short* __restrict__ x1b,
    const int* __restrict__ rowstart, const int* __restrict__ nbr,
    const float* __restrict__ x0, const float* __restrict__ agg0,
    const float* __restrict__ Ws0, const float* __restrict__ Wn0,
    const float* __restrict__ Ws2, const float* __restrict__ Wn2,
    const float* __restrict__ W1, const float* __restrict__ b1,
    const float* __restrict__ W2, const float* __restrict__ b2,
    const float* __restrict__ W3, const float* __restrict__ b3,
    float* __restrict__ g, unsigned* __restrict__ mm) {
  __shared__ float XA[64][68];
  __shared__ float Wl[64][64];
  __shared__ float red[16];
  const int row0 = blockIdx.x << 6;
  const int nb0  = blockIdx.x << 4;
  const int tid = threadIdx.x;
  const int tc4 = (tid & 15) << 2;
  const int tr  = tid >> 4;          // 0..31
  const int r0  = tr << 1;

  float4 gacc[2], acc1[2], acc2[2];

  // ---- prologue: XA <- x1 (bf16->f32), Wl <- Ws2 ----
#pragma unroll
  for (int q = 0; q < 2; ++q) {
    int rr = tr + (q << 5);
    ushort4 h = *(const ushort4*)(x1b + (size_t)(row0 + rr) * 64 + tc4);
    *(float4*)&XA[rr][tc4] = b2f4(h);
    *(float4*)&Wl[rr][tc4] = *(const float4*)(Ws2 + rr * 64 + tc4);
  }

  // ---- gather agg2 from bf16 x1 (2 nodes/thread, 4-deep MLP) ----
#pragma unroll
  for (int q = 0; q < 2; ++q) {
    int rr = tr + (q << 5);
    int n = nb0 + (rr >> 2), m = rr & 3;
    int beg = rowstart[n], end = rowstart[n + 1];
    float4 a0 = {0.f,0.f,0.f,0.f}, a1 = {0.f,0.f,0.f,0.f};
    float4 a2 = {0.f,0.f,0.f,0.f}, a3 = {0.f,0.f,0.f,0.f};
    int i = beg;
    for (; i + 4 <= end; i += 4) {
      ushort4 v0 = *(const ushort4*)(x1b + (size_t)(nbr[i]   * 4 + m) * 64 + tc4);
      ushort4 v1 = *(const ushort4*)(x1b + (size_t)(nbr[i+1] * 4 + m) * 64 + tc4);
      ushort4 v2 = *(const ushort4*)(x1b + (size_t)(nbr[i+2] * 4 + m) * 64 + tc4);
      ushort4 v3 = *(const ushort4*)(x1b + (size_t)(nbr[i+3] * 4 + m) * 64 + tc4);
      a0 = add4(a0, b2f4(v0)); a1 = add4(a1, b2f4(v1));
      a2 = add4(a2, b2f4(v2)); a3 = add4(a3, b2f4(v3));
    }
    for (; i < end; ++i)
      a0 = add4(a0, b2f4(*(const ushort4*)(x1b + (size_t)(nbr[i] * 4 + m) * 64 + tc4)));
    gacc[q] = add4(add4(a0, a1), add4(a2, a3));
  }
  __syncthreads();

  // ---- P1: acc1 = x1 @ Ws2 ----
  acc1[0] = acc1[1] = make_float4(0.f, 0.f, 0.f, 0.f);
  MACC2(XA, acc1);
  __syncthreads();
#pragma unroll
  for (int q = 0; q < 2; ++q) {                      // commit W1b (XA untouched)
    int rr = tr + (q << 5);
    *(float4*)&Wl[rr][tc4] = *(const float4*)(W1 + (64 + rr) * 64 + tc4);
  }
  __syncthreads();

  // ---- P2: acc2 = b1 + x1 @ W1b ----
  {
    float4 bb = *(const float4*)(b1 + tc4);
    acc2[0] = acc2[1] = bb;
  }
  MACC2(XA, acc2);
  __syncthreads();
#pragma unroll
  for (int q = 0; q < 2; ++q) {                      // commit XA=agg2, Wl=Wn2
    int rr = tr + (q << 5);
    *(float4*)&XA[rr][tc4] = gacc[q];
    *(float4*)&Wl[rr][tc4] = *(const float4*)(Wn2 + rr * 64 + tc4);
  }
  __syncthreads();

  // ---- P3: acc1 += agg2 @ Wn2 ; x2 = relu(acc1) ----
  MACC2(XA, acc1);
  __syncthreads();
#pragma unroll
  for (int i = 0; i < 2; ++i)                        // x2 -> XA
    *(float4*)&XA[r0 + i][tc4] = relu4(acc1[i]);
#pragma unroll
  for (int q = 0; q < 2; ++q) {                      // commit W1c
    int rr = tr + (q << 5);
    *(float4*)&Wl[rr][tc4] = *(const float4*)(W1 + (128 + rr) * 64 + tc4);
  }
  __syncthreads();

  // ---- P4: acc2 += x2 @ W1c ----
  MACC2(XA, acc2);
  __syncthreads();
  {
    float4 ws = *(const float4*)(Ws0 + tc4);
    float4 wn = *(const float4*)(Wn0 + tc4);
#pragma unroll
    for (int q = 0; q < 2; ++q) {                    // commit XA = x0feat, Wl = W1a
      int rr = tr + (q << 5);
      *(float4*)&XA[rr][tc4] = conv0f(x0[row0 + rr], agg0[row0 + rr], ws, wn);
      *(float4*)&Wl[rr][tc4] = *(const float4*)(W1 + rr * 64 + tc4);
    }
  }
  __syncthreads();

  // ---- P5: acc2 += x0f @ W1a ; h1 = relu(acc2) ----
  MACC2(XA, acc2);
  __syncthreads();
#pragma unroll
  for (int i = 0; i < 2; ++i)                        // h1 -> XA
    *(float4*)&XA[r0 + i][tc4] = relu4(acc2[i]);
#pragma unroll
  for (int q = 0; q < 2; ++q) {                      // commit W2
    int rr = tr + (q << 5);
    *(float4*)&Wl[rr][tc4] = *(const float4*)(W2 + rr * 64 + tc4);
  }
  __syncthreads();

  // ---- P6: acc1 = b2 + h1 @ W2 ; h2 = relu ----
  {
    float4 bb = *(const float4*)(b2 + tc4);
    acc1[0] = acc1[1] = bb;
  }
  MACC2(XA, acc1);
  __syncthreads();
#pragma unroll
  for (int i = 0; i < 2; ++i)                        // h2 -> XA
    *(float4*)&XA[r0 + i][tc4] = relu4(acc1[i]);
#pragma unroll
  for (int q = 0; q < 2; ++q) {                      // commit W3
    int rr = tr + (q << 5);
    *(float4*)&Wl[rr][tc4] = *(const float4*)(W3 + rr * 64 + tc4);
  }
  __syncthreads();

  // ---- P7: acc2 = b3 + h2 @ W3 (no relu) ----
  {
    float4 bb = *(const float4*)(b3 + tc4);
    acc2[0] = acc2[1] = bb;
  }
  MACC2(XA, acc2);
  __syncthreads();
#pragma unroll
  for (int i = 0; i < 2; ++i)
    *(float4*)&XA[r0 + i][tc4] = acc2[i];            // h3 -> XA
  __syncthreads();

  // ---- mean over M + per-block min/max ----
  float lmin = 3.4e38f, lmax = -3.4e38f;
  for (int k = tid; k < 1024; k += 512) {
    int nl = k >> 6, c = k & 63;
    float s = 0.25f * (XA[4*nl][c] + XA[4*nl+1][c] + XA[4*nl+2][c] + XA[4*nl+3][c]);
    g[(size_t)((row0 >> 2) + nl) * 64 + c] = s;
    lmin = fminf(lmin, s);
    lmax = fmaxf(lmax, s);
  }
#pragma unroll
  for (int off = 32; off; off >>= 1) {
    lmin = fminf(lmin, __shfl_xor(lmin, off));
    lmax = fmaxf(lmax, __shfl_xor(lmax, off));
  }
  if ((tid & 63) == 0) { red[tid >> 6] = lmin; red[8 + (tid >> 6)] = lmax; }
  __syncthreads();
  if (tid == 0) {
    float m0 = red[0], m1 = red[8];
#pragma unroll
    for (int w = 1; w < 8; ++w) {
      m0 = fminf(m0, red[w]);
      m1 = fmaxf(m1, red[8 + w]);
    }
    atomicMin(&mm[0], enc_f(m0));
    atomicMax(&mm[1], enc_f(m1));
  }
}

// ---------- rescale + pool (sorted batch -> run-length accumulate) ----------

__global__ __launch_bounds__(256) void pool2_k(const float* __restrict__ g,
                                               const int* __restrict__ batch,
                                               const unsigned* __restrict__ mm,
                                               float* __restrict__ pooled) {
  int c = threadIdx.x & 63;
  int grp = threadIdx.x >> 6;                        // 0..3
  int base = blockIdx.x * 64 + grp * 16;             // 16 consecutive nodes per group
  float gmin = dec_f(mm[0]);
  float sc = 2.0f / (dec_f(mm[1]) - gmin);
  float acc = 0.0f; int cur = -1;
  for (int i = 0; i < 16; ++i) {
    int n = base + i;
    if (n >= NN) break;
    int b = batch[n];
    if (b != cur) {
      if (cur >= 0) unsafeAtomicAdd(&pooled[(cur << 6) + c], acc);
      cur = b; acc = 0.0f;
    }
    acc += (g[(size_t)n * 64 + c] - gmin) * sc;
  }
  if (cur >= 0) unsafeAtomicAdd(&pooled[(cur << 6) + c], acc);
}

// ---------- out[b] = pooled[b,:] . Wo + bo ----------

__global__ void out_k(const float* __restrict__ pooled, const float* __restrict__ Wo,
                      const float* __restrict__ bo, float* __restrict__ out) {
  int b = blockIdx.x, l = threadIdx.x;
  float v = pooled[(b << 6) + l] * Wo[l];
#pragma unroll
  for (int off = 32; off; off >>= 1) v += __shfl_xor(v, off);
  if (l == 0) out[b] = v + bo[0];
}

// ---------- launch ----------

extern "C" void kernel_launch(void* const* d_in, const int* in_sizes, int n_in,
                              void* d_out, int out_size, void* d_ws, size_t ws_size,
                              hipStream_t stream) {
  const float* x0   = (const float*)d_in[0];
  const int*   ei   = (const int*)d_in[1];
  const int*   batch= (const int*)d_in[2];
  const float* Ws0  = (const float*)d_in[3];
  const float* Wn0  = (const float*)d_in[4];
  const float* Ws1  = (const float*)d_in[5];
  const float* Wn1  = (const float*)d_in[6];
  const float* Ws2  = (const float*)d_in[7];
  const float* Wn2  = (const float*)d_in[8];
  const float* W1   = (const float*)d_in[9];
  const float* b1   = (const float*)d_in[10];
  const float* W2   = (const float*)d_in[11];
  const float* b2   = (const float*)d_in[12];
  const float* W3   = (const float*)d_in[13];
  const float* b3   = (const float*)d_in[14];
  const float* Wo   = (const float*)d_in[15];
  const float* bo   = (const float*)d_in[16];
  float* out = (float*)d_out;

  unsigned short* x1b = (unsigned short*)d_ws;        // [NROWS,64] bf16
  float* agg0   = (float*)(x1b + (size_t)NROWS * 64); // [NROWS]
  float* g      = agg0 + NROWS;                       // [NN,64]
  float* pooled = g    + (size_t)NN * 64;             // [BB,64]
  unsigned* mm  = (unsigned*)(pooled + BB * 64);      // [2]
  int* deg      = (int*)(mm + 2);                     // [NN]
  int* rowstart = deg + NN;                           // [NN+1]
  int* cursor   = rowstart + NN + 1;                  // [NN]
  int* nbr      = cursor + NN;                        // [EE]
  int* bsum     = nbr + EE;                           // [NBLK_SCAN]

  // ---- CSR build ----
  hipMemsetAsync(deg, 0, NN * sizeof(int), stream);
  hist_k<<<(EE + 255) / 256, 256, 0, stream>>>(ei, deg);
  scan1_k<<<NBLK_SCAN, 512, 0, stream>>>(deg, rowstart, bsum);
  scan2_k<<<1, 64, 0, stream>>>(bsum);
  scan3_k<<<NBLK_SCAN, 512, 0, stream>>>(rowstart, cursor, bsum);
  fill_k<<<(EE + 255) / 256, 256, 0, stream>>>(ei, cursor, nbr);

  // ---- layer 0 aggregate (scalar) ----
  agg0_gather_k<<<(NROWS + 255) / 256, 256, 0, stream>>>(x0, rowstart, nbr, agg0);

  // ---- layer 1 (agg1 gather fused) -> x1 (bf16) ----
  conv1_k<<<NROWS / 64, 512, 0, stream>>>(x0, agg0, rowstart, nbr,
                                          Ws0, Wn0, Ws1, Wn1, x1b);

  // ---- fused conv2 + MLP + mean + min/max (agg2 gather fused, bf16 reads) ----
  hipMemsetAsync(mm, 0xFF, 4, stream);
  hipMemsetAsync(mm + 1, 0x00, 4, stream);
  fused2_k<<<NROWS / 64, 512, 0, stream>>>(x1b, rowstart, nbr, x0, agg0,
                                           Ws0, Wn0, Ws2, Wn2,
                                           W1, b1, W2, b2, W3, b3, g, mm);

  // ---- rescale + pooling ----
  hipMemsetAsync(pooled, 0, BB * 64 * sizeof(float), stream);
  pool2_k<<<(NN + 63) / 64, 256, 0, stream>>>(g, batch, mm, pooled);

  // ---- output linear ----
  out_k<<<BB, 64, 0, stream>>>(pooled, Wo, bo, out);
}

// Round 11
// 283.821 us; speedup vs baseline: 16.9624x; 1.2263x over previous
//
#include <hip/hip_runtime.h>
#include <math.h>

#define NN 50000
#define MM 4
#define EE 400000
#define BB 64
#define NROWS (NN*MM)           // 200000
#define NBLK_SCAN 98            // ceil(50000/512)

typedef __attribute__((ext_vector_type(8))) short bf16x8;
typedef __attribute__((ext_vector_type(4))) float f32x4;

// ---------- helpers ----------

__device__ __forceinline__ unsigned enc_f(float f) {
  unsigned u = __float_as_uint(f);
  return (u & 0x80000000u) ? ~u : (u | 0x80000000u);
}
__device__ __forceinline__ float dec_f(unsigned u) {
  return (u & 0x80000000u) ? __uint_as_float(u ^ 0x80000000u) : __uint_as_float(~u);
}

__device__ __forceinline__ void axpy4(float4& a, float s, float4 w) {
  a.x = fmaf(s, w.x, a.x);
  a.y = fmaf(s, w.y, a.y);
  a.z = fmaf(s, w.z, a.z);
  a.w = fmaf(s, w.w, a.w);
}
__device__ __forceinline__ float4 relu4(float4 v) {
  return make_float4(fmaxf(v.x, 0.f), fmaxf(v.y, 0.f), fmaxf(v.z, 0.f), fmaxf(v.w, 0.f));
}
__device__ __forceinline__ float4 add4(float4 a, float4 b) {
  return make_float4(a.x + b.x, a.y + b.y, a.z + b.z, a.w + b.w);
}
__device__ __forceinline__ float4 conv0f(float xv, float av, float4 ws, float4 wn) {
  float4 t;
  t.x = fmaxf(fmaf(xv, ws.x, av * wn.x), 0.f);
  t.y = fmaxf(fmaf(xv, ws.y, av * wn.y), 0.f);
  t.z = fmaxf(fmaf(xv, ws.z, av * wn.z), 0.f);
  t.w = fmaxf(fmaf(xv, ws.w, av * wn.w), 0.f);
  return t;
}

// bf16 pack/unpack (RNE)
__device__ __forceinline__ unsigned short bf16rn(float f) {
  unsigned u = __float_as_uint(f);
  return (unsigned short)((u + 0x7FFFu + ((u >> 16) & 1u)) >> 16);
}
__device__ __forceinline__ float bf2f(unsigned short h) {
  return __uint_as_float(((unsigned)h) << 16);
}
__device__ __forceinline__ float4 b2f4(ushort4 h) {
  return make_float4(bf2f(h.x), bf2f(h.y), bf2f(h.z), bf2f(h.w));
}

// read 8 consecutive f32 from LDS, convert to bf16x8 MFMA fragment
__device__ __forceinline__ bf16x8 fragf32(const float* p) {
  float4 lo = *(const float4*)p;
  float4 hi = *(const float4*)(p + 4);
  bf16x8 f;
  f[0] = (short)bf16rn(lo.x); f[1] = (short)bf16rn(lo.y);
  f[2] = (short)bf16rn(lo.z); f[3] = (short)bf16rn(lo.w);
  f[4] = (short)bf16rn(hi.x); f[5] = (short)bf16rn(hi.y);
  f[6] = (short)bf16rn(hi.z); f[7] = (short)bf16rn(hi.w);
  return f;
}

// 2x4 micro-tiled f32 LDS GEMM step (conv1 keeps the VALU path)
#define MACC2(XS, A)                                                  \
  _Pragma("unroll 2")                                                 \
  for (int k = 0; k < 64; k += 4) {                                   \
    float4 xa = *(const float4*)&XS[r0 + 0][k];                       \
    float4 xb = *(const float4*)&XS[r0 + 1][k];                       \
    float4 w0 = *(const float4*)&Wl[k + 0][tc4];                      \
    float4 w1 = *(const float4*)&Wl[k + 1][tc4];                      \
    float4 w2 = *(const float4*)&Wl[k + 2][tc4];                      \
    float4 w3 = *(const float4*)&Wl[k + 3][tc4];                      \
    axpy4(A[0], xa.x, w0); axpy4(A[0], xa.y, w1); axpy4(A[0], xa.z, w2); axpy4(A[0], xa.w, w3); \
    axpy4(A[1], xb.x, w0); axpy4(A[1], xb.y, w1); axpy4(A[1], xb.z, w2); axpy4(A[1], xb.w, w3); \
  }

// ---------- CSR build (dst-major neighbor lists) ----------

__global__ void hist_k(const int* __restrict__ ei, int* __restrict__ deg) {
  int e = blockIdx.x * blockDim.x + threadIdx.x;
  if (e < EE) atomicAdd(&deg[ei[EE + e]], 1);
}

__global__ __launch_bounds__(512) void scan1_k(const int* __restrict__ deg,
                                               int* __restrict__ rowstart,
                                               int* __restrict__ bsum) {
  __shared__ int s[512];
  int i = blockIdx.x * 512 + threadIdx.x;
  int v = (i < NN) ? deg[i] : 0;
  s[threadIdx.x] = v;
  __syncthreads();
  for (int off = 1; off < 512; off <<= 1) {
    int t = (threadIdx.x >= (unsigned)off) ? s[threadIdx.x - off] : 0;
    __syncthreads();
    s[threadIdx.x] += t;
    __syncthreads();
  }
  if (i < NN) rowstart[i] = s[threadIdx.x] - v;      // exclusive partial
  if (threadIdx.x == 511) bsum[blockIdx.x] = s[511];
}

__global__ void scan2_k(int* __restrict__ bsum) {
  if (threadIdx.x == 0) {
    int acc = 0;
    for (int k = 0; k < NBLK_SCAN; ++k) { int t = bsum[k]; bsum[k] = acc; acc += t; }
  }
}

__global__ __launch_bounds__(512) void scan3_k(int* __restrict__ rowstart,
                                               int* __restrict__ cursor,
                                               const int* __restrict__ bsum) {
  int i = blockIdx.x * 512 + threadIdx.x;
  if (i < NN) {
    int v = rowstart[i] + bsum[blockIdx.x];
    rowstart[i] = v;
    cursor[i] = v;
  }
  if (i == 0) rowstart[NN] = EE;
}

__global__ void fill_k(const int* __restrict__ ei, int* __restrict__ cursor,
                       int* __restrict__ nbr) {
  int e = blockIdx.x * blockDim.x + threadIdx.x;
  if (e >= EE) return;
  int d = ei[EE + e];
  int p = atomicAdd(&cursor[d], 1);
  nbr[p] = ei[e];
}

// ---------- aggregation 0: agg0[n*4+m] = sum_{s in N(n)} x0[s*4+m] ----------

__global__ void agg0_gather_k(const float* __restrict__ x0,
                              const int* __restrict__ rowstart,
                              const int* __restrict__ nbr,
                              float* __restrict__ agg0) {
  int idx = blockIdx.x * blockDim.x + threadIdx.x;   // NROWS
  if (idx >= NROWS) return;
  int n = idx >> 2, m = idx & 3;
  int beg = rowstart[n], end = rowstart[n + 1];
  float acc = 0.0f;
  for (int i = beg; i < end; ++i) acc += x0[nbr[i] * 4 + m];
  agg0[idx] = acc;
}

// ---------- conv1 (gather fused, 512 thr): x1 = relu(x0f@Ws1 + agg1@Wn1) -> bf16 ----------

__global__ __launch_bounds__(512, 4) void conv1_k(const float* __restrict__ x0,
                                                  const float* __restrict__ agg0,
                                                  const int* __restrict__ rowstart,
                                                  const int* __restrict__ nbr,
                                                  const float* __restrict__ Ws0,
                                                  const float* __restrict__ Wn0,
                                                  const float* __restrict__ Ws1,
                                                  const float* __restrict__ Wn1,
                                                  unsigned short* __restrict__ x1b) {
  __shared__ float XA[64][68];
  __shared__ float Wl[64][64];
  const int row0 = blockIdx.x << 6;
  const int nb0  = blockIdx.x << 4;
  const int tid = threadIdx.x;
  const int tc4 = (tid & 15) << 2;
  const int tr  = tid >> 4;          // 0..31
  const int r0  = tr << 1;

  float4 ws = *(const float4*)(Ws0 + tc4);
  float4 wn = *(const float4*)(Wn0 + tc4);

  // stage XA = x0feat (recomputed), Wl = Ws1
#pragma unroll
  for (int q = 0; q < 2; ++q) {
    int rr = tr + (q << 5);
    *(float4*)&XA[rr][tc4] = conv0f(x0[row0 + rr], agg0[row0 + rr], ws, wn);
    *(float4*)&Wl[rr][tc4] = *(const float4*)(Ws1 + rr * 64 + tc4);
  }

  // gather agg1 (2 nodes/thread, 4-deep MLP)
  float4 gacc[2];
#pragma unroll
  for (int q = 0; q < 2; ++q) {
    int rr = tr + (q << 5);
    int n = nb0 + (rr >> 2), m = rr & 3;
    int beg = rowstart[n], end = rowstart[n + 1];
    float4 a0 = {0.f,0.f,0.f,0.f}, a1 = {0.f,0.f,0.f,0.f};
    float4 a2 = {0.f,0.f,0.f,0.f}, a3 = {0.f,0.f,0.f,0.f};
    int i = beg;
    for (; i + 4 <= end; i += 4) {
      int s0 = nbr[i] * 4 + m, s1 = nbr[i+1] * 4 + m;
      int s2 = nbr[i+2] * 4 + m, s3 = nbr[i+3] * 4 + m;
      float xv0 = x0[s0], av0 = agg0[s0];
      float xv1 = x0[s1], av1 = agg0[s1];
      float xv2 = x0[s2], av2 = agg0[s2];
      float xv3 = x0[s3], av3 = agg0[s3];
      a0 = add4(a0, conv0f(xv0, av0, ws, wn));
      a1 = add4(a1, conv0f(xv1, av1, ws, wn));
      a2 = add4(a2, conv0f(xv2, av2, ws, wn));
      a3 = add4(a3, conv0f(xv3, av3, ws, wn));
    }
    for (; i < end; ++i) {
      int s0 = nbr[i] * 4 + m;
      a0 = add4(a0, conv0f(x0[s0], agg0[s0], ws, wn));
    }
    gacc[q] = add4(add4(a0, a1), add4(a2, a3));
  }
  __syncthreads();

  // P1: x0f @ Ws1
  float4 acc[2];
  acc[0] = acc[1] = make_float4(0.f, 0.f, 0.f, 0.f);
  MACC2(XA, acc);
  __syncthreads();
#pragma unroll
  for (int q = 0; q < 2; ++q) {                      // commit XA=agg1, Wl=Wn1
    int rr = tr + (q << 5);
    *(float4*)&XA[rr][tc4] = gacc[q];
    *(float4*)&Wl[rr][tc4] = *(const float4*)(Wn1 + rr * 64 + tc4);
  }
  __syncthreads();

  // P2: agg1 @ Wn1
  MACC2(XA, acc);

#pragma unroll
  for (int i = 0; i < 2; ++i) {
    float4 v = relu4(acc[i]);
    ushort4 h;
    h.x = bf16rn(v.x); h.y = bf16rn(v.y); h.z = bf16rn(v.z); h.w = bf16rn(v.w);
    *(ushort4*)(x1b + (size_t)(row0 + r0 + i) * 64 + tc4) = h;
  }
}

// ---------- fused conv2 + 3-layer MLP + mean + min/max (512 thr, MFMA) ----------
// 8 waves; wave w owns D-subtiles (mrow0 = (w>>1)*16, ncols ncol0/ncol0+16, ncol0=(w&1)*32).
// W staged TRANSPOSED (WT[c][k]) so A and B frags are both contiguous 8-f32 reads.
//   P1 x1@Ws2->accP | P2 x1@W1b->accQ | P3 agg2@Wn2->accP, x2=relu(accP)
//   P4 x2@W1c->accQ | P5 x0f@W1a->accQ, h1=relu | P6 h1@W2 | P7 h2@W3

__global__ __launch_bounds__(512, 4) void fused2_k(const unsigned short* __restrict__ x1b,
    const int* __restrict__ rowstart, const int* __restrict__ nbr,
    const float* __restrict__ x0, const float* __restrict__ agg0,
    const float* __restrict__ Ws0, const float* __restrict__ Wn0,
    const float* __restrict__ Ws2, const float* __restrict__ Wn2,
    const float* __restrict__ W1, const float* __restrict__ b1,
    const float* __restrict__ W2, const float* __restrict__ b2,
    const float* __restrict__ W3, const float* __restrict__ b3,
    float* __restrict__ g, unsigned* __restrict__ mm) {
  __shared__ float XA[64][68];
  __shared__ float WT[64][68];   // WT[c][k] = W[k][c]
  __shared__ float red[16];
  const int row0 = blockIdx.x << 6;
  const int nb0  = blockIdx.x << 4;
  const int tid = threadIdx.x;
  const int tc4 = (tid & 15) << 2;
  const int tr  = tid >> 4;            // 0..31 (staging/gather row group)
  // MFMA lane decomposition
  const int lane  = tid & 63;
  const int wid   = tid >> 6;          // 0..7
  const int mrow0 = (wid >> 1) << 4;   // 0,16,32,48
  const int ncol0 = (wid & 1) << 5;    // 0 or 32
  const int fl    = lane & 15;
  const int fk    = (lane >> 4) << 3;  // 0,8,16,24
  const int drow  = mrow0 + ((lane >> 4) << 2);
  const int dc0   = ncol0 + fl, dc1 = ncol0 + 16 + fl;

#define STAGE_WT(Wsrc)                                                \
  _Pragma("unroll")                                                   \
  for (int q = 0; q < 2; ++q) {                                       \
    int kk = tr + (q << 5);                                           \
    float4 w = *(const float4*)((Wsrc) + kk * 64 + tc4);              \
    WT[tc4 + 0][kk] = w.x; WT[tc4 + 1][kk] = w.y;                     \
    WT[tc4 + 2][kk] = w.z; WT[tc4 + 3][kk] = w.w;                     \
  }

#define MFMA_PHASE(A0, A1)                                            \
  _Pragma("unroll")                                                   \
  for (int kh = 0; kh < 2; ++kh) {                                    \
    bf16x8 af  = fragf32(&XA[mrow0 + fl][(kh << 5) + fk]);            \
    bf16x8 bf0 = fragf32(&WT[ncol0 + fl][(kh << 5) + fk]);            \
    bf16x8 bf1 = fragf32(&WT[ncol0 + 16 + fl][(kh << 5) + fk]);       \
    A0 = __builtin_amdgcn_mfma_f32_16x16x32_bf16(af, bf0, A0, 0, 0, 0); \
    A1 = __builtin_amdgcn_mfma_f32_16x16x32_bf16(af, bf1, A1, 0, 0, 0); \
  }

#define DCOMMIT_RELU(A0, A1)                                          \
  _Pragma("unroll")                                                   \
  for (int j = 0; j < 4; ++j) {                                       \
    XA[drow + j][dc0] = fmaxf(A0[j], 0.f);                            \
    XA[drow + j][dc1] = fmaxf(A1[j], 0.f);                            \
  }

  // ---- prologue: XA <- x1 (bf16->f32), WT <- Ws2^T ----
#pragma unroll
  for (int q = 0; q < 2; ++q) {
    int rr = tr + (q << 5);
    ushort4 h = *(const ushort4*)(x1b + (size_t)(row0 + rr) * 64 + tc4);
    *(float4*)&XA[rr][tc4] = b2f4(h);
  }
  STAGE_WT(Ws2);

  // ---- gather agg2 from bf16 x1 (2 nodes/thread, 4-deep MLP) ----
  float4 gacc[2];
#pragma unroll
  for (int q = 0; q < 2; ++q) {
    int rr = tr + (q << 5);
    int n = nb0 + (rr >> 2), m = rr & 3;
    int beg = rowstart[n], end = rowstart[n + 1];
    float4 a0 = {0.f,0.f,0.f,0.f}, a1 = {0.f,0.f,0.f,0.f};
    float4 a2 = {0.f,0.f,0.f,0.f}, a3 = {0.f,0.f,0.f,0.f};
    int i = beg;
    for (; i + 4 <= end; i += 4) {
      ushort4 v0 = *(const ushort4*)(x1b + (size_t)(nbr[i]   * 4 + m) * 64 + tc4);
      ushort4 v1 = *(const ushort4*)(x1b + (size_t)(nbr[i+1] * 4 + m) * 64 + tc4);
      ushort4 v2 = *(const ushort4*)(x1b + (size_t)(nbr[i+2] * 4 + m) * 64 + tc4);
      ushort4 v3 = *(const ushort4*)(x1b + (size_t)(nbr[i+3] * 4 + m) * 64 + tc4);
      a0 = add4(a0, b2f4(v0)); a1 = add4(a1, b2f4(v1));
      a2 = add4(a2, b2f4(v2)); a3 = add4(a3, b2f4(v3));
    }
    for (; i < end; ++i)
      a0 = add4(a0, b2f4(*(const ushort4*)(x1b + (size_t)(nbr[i] * 4 + m) * 64 + tc4)));
    gacc[q] = add4(add4(a0, a1), add4(a2, a3));
  }
  __syncthreads();

  // ---- P1: accP = x1 @ Ws2 ----
  f32x4 accP0 = {0.f,0.f,0.f,0.f}, accP1 = {0.f,0.f,0.f,0.f};
  MFMA_PHASE(accP0, accP1);
  __syncthreads();
  STAGE_WT(W1 + 64 * 64);                            // W1b (rows 64..127)
  __syncthreads();

  // ---- P2: accQ = b1 + x1 @ W1b ----
  f32x4 accQ0, accQ1;
  {
    float bv0 = b1[dc0], bv1 = b1[dc1];
    accQ0[0]=bv0; accQ0[1]=bv0; accQ0[2]=bv0; accQ0[3]=bv0;
    accQ1[0]=bv1; accQ1[1]=bv1; accQ1[2]=bv1; accQ1[3]=bv1;
  }
  MFMA_PHASE(accQ0, accQ1);
  __syncthreads();
#pragma unroll
  for (int q = 0; q < 2; ++q)                        // commit XA = agg2
    *(float4*)&XA[tr + (q << 5)][tc4] = gacc[q];
  STAGE_WT(Wn2);
  __syncthreads();

  // ---- P3: accP += agg2 @ Wn2 ; x2 = relu(accP) ----
  MFMA_PHASE(accP0, accP1);
  __syncthreads();
  DCOMMIT_RELU(accP0, accP1);                        // x2 -> XA
  STAGE_WT(W1 + 128 * 64);                           // W1c
  __syncthreads();

  // ---- P4: accQ += x2 @ W1c ----
  MFMA_PHASE(accQ0, accQ1);
  __syncthreads();
  {
    float4 ws = *(const float4*)(Ws0 + tc4);
    float4 wn = *(const float4*)(Wn0 + tc4);
#pragma unroll
    for (int q = 0; q < 2; ++q) {                    // commit XA = x0feat
      int rr = tr + (q << 5);
      *(float4*)&XA[rr][tc4] = conv0f(x0[row0 + rr], agg0[row0 + rr], ws, wn);
    }
  }
  STAGE_WT(W1);                                      // W1a
  __syncthreads();

  // ---- P5: accQ += x0f @ W1a ; h1 = relu(accQ) ----
  MFMA_PHASE(accQ0, accQ1);
  __syncthreads();
  DCOMMIT_RELU(accQ0, accQ1);                        // h1 -> XA
  STAGE_WT(W2);
  __syncthreads();

  // ---- P6: accR = b2 + h1 @ W2 ; h2 = relu ----
  f32x4 accR0, accR1;
  {
    float bv0 = b2[dc0], bv1 = b2[dc1];
    accR0[0]=bv0; accR0[1]=bv0; accR0[2]=bv0; accR0[3]=bv0;
    accR1[0]=bv1; accR1[1]=bv1; accR1[2]=bv1; accR1[3]=bv1;
  }
  MFMA_PHASE(accR0, accR1);
  __syncthreads();
  DCOMMIT_RELU(accR0, accR1);                        // h2 -> XA
  STAGE_WT(W3);
  __syncthreads();

  // ---- P7: accS = b3 + h2 @ W3 (no relu) ----
  f32x4 accS0, accS1;
  {
    float bv0 = b3[dc0], bv1 = b3[dc1];
    accS0[0]=bv0; accS0[1]=bv0; accS0[2]=bv0; accS0[3]=bv0;
    accS1[0]=bv1; accS1[1]=bv1; accS1[2]=bv1; accS1[3]=bv1;
  }
  MFMA_PHASE(accS0, accS1);
  __syncthreads();
#pragma unroll
  for (int j = 0; j < 4; ++j) {                      // h3 -> XA (no relu)
    XA[drow + j][dc0] = accS0[j];
    XA[drow + j][dc1] = accS1[j];
  }
  __syncthreads();

  // ---- mean over M + per-block min/max ----
  float lmin = 3.4e38f, lmax = -3.4e38f;
  for (int k = tid; k < 1024; k += 512) {
    int nl = k >> 6, c = k & 63;
    float s = 0.25f * (XA[4*nl][c] + XA[4*nl+1][c] + XA[4*nl+2][c] + XA[4*nl+3][c]);
    g[(size_t)((row0 >> 2) + nl) * 64 + c] = s;
    lmin = fminf(lmin, s);
    lmax = fmaxf(lmax, s);
  }
#pragma unroll
  for (int off = 32; off; off >>= 1) {
    lmin = fminf(lmin, __shfl_xor(lmin, off));
    lmax = fmaxf(lmax, __shfl_xor(lmax, off));
  }
  if ((tid & 63) == 0) { red[tid >> 6] = lmin; red[8 + (tid >> 6)] = lmax; }
  __syncthreads();
  if (tid == 0) {
    float m0 = red[0], m1 = red[8];
#pragma unroll
    for (int w = 1; w < 8; ++w) {
      m0 = fminf(m0, red[w]);
      m1 = fmaxf(m1, red[8 + w]);
    }
    atomicMin(&mm[0], enc_f(m0));
    atomicMax(&mm[1], enc_f(m1));
  }
#undef STAGE_WT
#undef MFMA_PHASE
#undef DCOMMIT_RELU
}

// ---------- rescale + pool (sorted batch -> run-length accumulate) ----------

__global__ __launch_bounds__(256) void pool2_k(const float* __restrict__ g,
                                               const int* __restrict__ batch,
                                               const unsigned* __restrict__ mm,
                                               float* __restrict__ pooled) {
  int c = threadIdx.x & 63;
  int grp = threadIdx.x >> 6;                        // 0..3
  int base = blockIdx.x * 64 + grp * 16;             // 16 consecutive nodes per group
  float gmin = dec_f(mm[0]);
  float sc = 2.0f / (dec_f(mm[1]) - gmin);
  float acc = 0.0f; int cur = -1;
  for (int i = 0; i < 16; ++i) {
    int n = base + i;
    if (n >= NN) break;
    int b = batch[n];
    if (b != cur) {
      if (cur >= 0) unsafeAtomicAdd(&pooled[(cur << 6) + c], acc);
      cur = b; acc = 0.0f;
    }
    acc += (g[(size_t)n * 64 + c] - gmin) * sc;
  }
  if (cur >= 0) unsafeAtomicAdd(&pooled[(cur << 6) + c], acc);
}

// ---------- out[b] = pooled[b,:] . Wo + bo ----------

__global__ void out_k(const float* __restrict__ pooled, const float* __restrict__ Wo,
                      const float* __restrict__ bo, float* __restrict__ out) {
  int b = blockIdx.x, l = threadIdx.x;
  float v = pooled[(b << 6) + l] * Wo[l];
#pragma unroll
  for (int off = 32; off; off >>= 1) v += __shfl_xor(v, off);
  if (l == 0) out[b] = v + bo[0];
}

// ---------- launch ----------

extern "C" void kernel_launch(void* const* d_in, const int* in_sizes, int n_in,
                              void* d_out, int out_size, void* d_ws, size_t ws_size,
                              hipStream_t stream) {
  const float* x0   = (const float*)d_in[0];
  const int*   ei   = (const int*)d_in[1];
  const int*   batch= (const int*)d_in[2];
  const float* Ws0  = (const float*)d_in[3];
  const float* Wn0  = (const float*)d_in[4];
  const float* Ws1  = (const float*)d_in[5];
  const float* Wn1  = (const float*)d_in[6];
  const float* Ws2  = (const float*)d_in[7];
  const float* Wn2  = (const float*)d_in[8];
  const float* W1   = (const float*)d_in[9];
  const float* b1   = (const float*)d_in[10];
  const float* W2   = (const float*)d_in[11];
  const float* b2   = (const float*)d_in[12];
  const float* W3   = (const float*)d_in[13];
  const float* b3   = (const float*)d_in[14];
  const float* Wo   = (const float*)d_in[15];
  const float* bo   = (const float*)d_in[16];
  float* out = (float*)d_out;

  unsigned short* x1b = (unsigned short*)d_ws;        // [NROWS,64] bf16
  float* agg0   = (float*)(x1b + (size_t)NROWS * 64); // [NROWS]
  float* g      = agg0 + NROWS;                       // [NN,64]
  float* pooled = g    + (size_t)NN * 64;             // [BB,64]
  unsigned* mm  = (unsigned*)(pooled + BB * 64);      // [2]
  int* deg      = (int*)(mm + 2);                     // [NN]
  int* rowstart = deg + NN;                           // [NN+1]
  int* cursor   = rowstart + NN + 1;                  // [NN]
  int* nbr      = cursor + NN;                        // [EE]
  int* bsum     = nbr + EE;                           // [NBLK_SCAN]

  // ---- CSR build ----
  hipMemsetAsync(deg, 0, NN * sizeof(int), stream);
  hist_k<<<(EE + 255) / 256, 256, 0, stream>>>(ei, deg);
  scan1_k<<<NBLK_SCAN, 512, 0, stream>>>(deg, rowstart, bsum);
  scan2_k<<<1, 64, 0, stream>>>(bsum);
  scan3_k<<<NBLK_SCAN, 512, 0, stream>>>(rowstart, cursor, bsum);
  fill_k<<<(EE + 255) / 256, 256, 0, stream>>>(ei, cursor, nbr);

  // ---- layer 0 aggregate (scalar) ----
  agg0_gather_k<<<(NROWS + 255) / 256, 256, 0, stream>>>(x0, rowstart, nbr, agg0);

  // ---- layer 1 (agg1 gather fused) -> x1 (bf16) ----
  conv1_k<<<NROWS / 64, 512, 0, stream>>>(x0, agg0, rowstart, nbr,
                                          Ws0, Wn0, Ws1, Wn1, x1b);

  // ---- fused conv2 + MLP + mean + min/max (MFMA) ----
  hipMemsetAsync(mm, 0xFF, 4, stream);
  hipMemsetAsync(mm + 1, 0x00, 4, stream);
  fused2_k<<<NROWS / 64, 512, 0, stream>>>(x1b, rowstart, nbr, x0, agg0,
                                           Ws0, Wn0, Ws2, Wn2,
                                           W1, b1, W2, b2, W3, b3, g, mm);

  // ---- rescale + pooling ----
  hipMemsetAsync(pooled, 0, BB * 64 * sizeof(float), stream);
  pool2_k<<<(NN + 63) / 64, 256, 0, stream>>>(g, batch, mm, pooled);

  // ---- output linear ----
  out_k<<<BB, 64, 0, stream>>>(pooled, Wo, bo, out);
}

// Round 12
// 223.060 us; speedup vs baseline: 21.5829x; 1.2724x over previous
//
#include <hip/hip_runtime.h>
#include <math.h>

#define NN 50000
#define MM 4
#define EE 400000
#define BB 64
#define NROWS (NN*MM)           // 200000
#define NBLK_SCAN 98            // ceil(50000/512)

typedef __attribute__((ext_vector_type(8))) short bf16x8;
typedef __attribute__((ext_vector_type(4))) float f32x4;

// ---------- helpers ----------

__device__ __forceinline__ unsigned enc_f(float f) {
  unsigned u = __float_as_uint(f);
  return (u & 0x80000000u) ? ~u : (u | 0x80000000u);
}
__device__ __forceinline__ float dec_f(unsigned u) {
  return (u & 0x80000000u) ? __uint_as_float(u ^ 0x80000000u) : __uint_as_float(~u);
}
__device__ __forceinline__ float4 add4(float4 a, float4 b) {
  return make_float4(a.x + b.x, a.y + b.y, a.z + b.z, a.w + b.w);
}
__device__ __forceinline__ float4 conv0f(float xv, float av, float4 ws, float4 wn) {
  float4 t;
  t.x = fmaxf(fmaf(xv, ws.x, av * wn.x), 0.f);
  t.y = fmaxf(fmaf(xv, ws.y, av * wn.y), 0.f);
  t.z = fmaxf(fmaf(xv, ws.z, av * wn.z), 0.f);
  t.w = fmaxf(fmaf(xv, ws.w, av * wn.w), 0.f);
  return t;
}

// bf16 pack/unpack (RNE)
__device__ __forceinline__ unsigned short bf16rn(float f) {
  unsigned u = __float_as_uint(f);
  return (unsigned short)((u + 0x7FFFu + ((u >> 16) & 1u)) >> 16);
}
__device__ __forceinline__ float bf2f(unsigned short h) {
  return __uint_as_float(((unsigned)h) << 16);
}
__device__ __forceinline__ float4 b2f4(ushort4 h) {
  return make_float4(bf2f(h.x), bf2f(h.y), bf2f(h.z), bf2f(h.w));
}
__device__ __forceinline__ ushort4 f2b4(float4 v) {
  ushort4 h;
  h.x = bf16rn(v.x); h.y = bf16rn(v.y); h.z = bf16rn(v.z); h.w = bf16rn(v.w);
  return h;
}

// ---------- CSR build (dst-major neighbor lists) ----------

__global__ void hist_k(const int* __restrict__ ei, int* __restrict__ deg) {
  int e = blockIdx.x * blockDim.x + threadIdx.x;
  if (e < EE) atomicAdd(&deg[ei[EE + e]], 1);
}

__global__ __launch_bounds__(512) void scan1_k(const int* __restrict__ deg,
                                               int* __restrict__ rowstart,
                                               int* __restrict__ bsum) {
  __shared__ int s[512];
  int i = blockIdx.x * 512 + threadIdx.x;
  int v = (i < NN) ? deg[i] : 0;
  s[threadIdx.x] = v;
  __syncthreads();
  for (int off = 1; off < 512; off <<= 1) {
    int t = (threadIdx.x >= (unsigned)off) ? s[threadIdx.x - off] : 0;
    __syncthreads();
    s[threadIdx.x] += t;
    __syncthreads();
  }
  if (i < NN) rowstart[i] = s[threadIdx.x] - v;      // exclusive partial
  if (threadIdx.x == 511) bsum[blockIdx.x] = s[511];
}

__global__ void scan2_k(int* __restrict__ bsum) {
  if (threadIdx.x == 0) {
    int acc = 0;
    for (int k = 0; k < NBLK_SCAN; ++k) { int t = bsum[k]; bsum[k] = acc; acc += t; }
  }
}

__global__ __launch_bounds__(512) void scan3_k(int* __restrict__ rowstart,
                                               int* __restrict__ cursor,
                                               const int* __restrict__ bsum) {
  int i = blockIdx.x * 512 + threadIdx.x;
  if (i < NN) {
    int v = rowstart[i] + bsum[blockIdx.x];
    rowstart[i] = v;
    cursor[i] = v;
  }
  if (i == 0) rowstart[NN] = EE;
}

__global__ void fill_k(const int* __restrict__ ei, int* __restrict__ cursor,
                       int* __restrict__ nbr) {
  int e = blockIdx.x * blockDim.x + threadIdx.x;
  if (e >= EE) return;
  int d = ei[EE + e];
  int p = atomicAdd(&cursor[d], 1);
  nbr[p] = ei[e];
}

// ---------- weight prep: 9 matrices transposed+bf16 into wt[m][c][k] ----------
// 0:Ws1 1:Wn1 2:Ws2 3:W1b 4:Wn2 5:W1c 6:W1a 7:W2 8:W3

__global__ void prepw_k(const float* __restrict__ Ws1, const float* __restrict__ Wn1,
                        const float* __restrict__ Ws2, const float* __restrict__ Wn2,
                        const float* __restrict__ W1,  const float* __restrict__ W2,
                        const float* __restrict__ W3,  unsigned short* __restrict__ wt) {
  int idx = blockIdx.x * 256 + threadIdx.x;
  if (idx >= 9 * 4096) return;
  int m = idx >> 12, r = idx & 4095;
  int c = r >> 6, k = r & 63;
  const float* src = Ws1;
  switch (m) {
    case 0: src = Ws1; break;
    case 1: src = Wn1; break;
    case 2: src = Ws2; break;
    case 3: src = W1 + 64 * 64; break;
    case 4: src = Wn2; break;
    case 5: src = W1 + 128 * 64; break;
    case 6: src = W1; break;
    case 7: src = W2; break;
    case 8: src = W3; break;
  }
  wt[idx] = bf16rn(src[k * 64 + c]);
}

// ---------- aggregation 0: agg0[n*4+m] = sum_{s in N(n)} x0[s*4+m] ----------

__global__ void agg0_gather_k(const float* __restrict__ x0,
                              const int* __restrict__ rowstart,
                              const int* __restrict__ nbr,
                              float* __restrict__ agg0) {
  int idx = blockIdx.x * blockDim.x + threadIdx.x;   // NROWS
  if (idx >= NROWS) return;
  int n = idx >> 2, m = idx & 3;
  int beg = rowstart[n], end = rowstart[n + 1];
  float acc = 0.0f;
  for (int i = beg; i < end; ++i) acc += x0[nbr[i] * 4 + m];
  agg0[idx] = acc;
}

// ---------- shared MFMA machinery (bf16 LDS tiles, 72-short rows = 144B aligned) ----------

#define STAGE_WT(mi)                                                   \
  {                                                                    \
    const ushort4* srcp = (const ushort4*)(wt + (mi) * 4096);          \
    int wc = tid >> 4, wp = (tid & 15) << 2;                           \
    *(ushort4*)&WTl[wc][wp]      = srcp[tid];                          \
    *(ushort4*)&WTl[wc + 32][wp] = srcp[tid + 512];                    \
  }

#define MFMA_PHASE(A0, A1)                                              \
  _Pragma("unroll")                                                     \
  for (int kh = 0; kh < 2; ++kh) {                                      \
    bf16x8 af  = *(const bf16x8*)&XAs[mrow0 + fl][(kh << 5) + fk];      \
    bf16x8 bf0 = *(const bf16x8*)&WTl[ncol0 + fl][(kh << 5) + fk];      \
    bf16x8 bf1 = *(const bf16x8*)&WTl[ncol0 + 16 + fl][(kh << 5) + fk]; \
    A0 = __builtin_amdgcn_mfma_f32_16x16x32_bf16(af, bf0, A0, 0, 0, 0); \
    A1 = __builtin_amdgcn_mfma_f32_16x16x32_bf16(af, bf1, A1, 0, 0, 0); \
  }

#define DCOMMIT_RELU(A0, A1)                                            \
  _Pragma("unroll")                                                     \
  for (int j = 0; j < 4; ++j) {                                         \
    XAs[drow + j][dc0] = bf16rn(fmaxf(A0[j], 0.f));                     \
    XAs[drow + j][dc1] = bf16rn(fmaxf(A1[j], 0.f));                     \
  }

// ---------- conv1 (gather fused, 512 thr, MFMA): x1 = relu(x0f@Ws1 + agg1@Wn1) -> bf16 ----------

__global__ __launch_bounds__(512, 4) void conv1_k(const float* __restrict__ x0,
                                                  const float* __restrict__ agg0,
                                                  const int* __restrict__ rowstart,
                                                  const int* __restrict__ nbr,
                                                  const float* __restrict__ Ws0,
                                                  const float* __restrict__ Wn0,
                                                  const unsigned short* __restrict__ wt,
                                                  unsigned short* __restrict__ x1b) {
  __shared__ unsigned short XAs[64][72];
  __shared__ unsigned short WTl[64][72];
  const int row0 = blockIdx.x << 6;
  const int nb0  = blockIdx.x << 4;
  const int tid = threadIdx.x;
  const int tc4 = (tid & 15) << 2;
  const int tr  = tid >> 4;            // 0..31
  const int lane  = tid & 63;
  const int wid   = tid >> 6;
  const int mrow0 = (wid >> 1) << 4;
  const int ncol0 = (wid & 1) << 5;
  const int fl    = lane & 15;
  const int fk    = (lane >> 4) << 3;
  const int drow  = mrow0 + ((lane >> 4) << 2);
  const int dc0   = ncol0 + fl, dc1 = ncol0 + 16 + fl;

  float4 ws = *(const float4*)(Ws0 + tc4);
  float4 wn = *(const float4*)(Wn0 + tc4);

  // stage XAs = x0feat (recomputed, bf16), WTl = Ws1^T
#pragma unroll
  for (int q = 0; q < 2; ++q) {
    int rr = tr + (q << 5);
    *(ushort4*)&XAs[rr][tc4] = f2b4(conv0f(x0[row0 + rr], agg0[row0 + rr], ws, wn));
  }
  STAGE_WT(0);

  // gather agg1 (2 nodes/thread, 4-deep MLP)
  float4 gacc[2];
#pragma unroll
  for (int q = 0; q < 2; ++q) {
    int rr = tr + (q << 5);
    int n = nb0 + (rr >> 2), m = rr & 3;
    int beg = rowstart[n], end = rowstart[n + 1];
    float4 a0 = {0.f,0.f,0.f,0.f}, a1 = {0.f,0.f,0.f,0.f};
    float4 a2 = {0.f,0.f,0.f,0.f}, a3 = {0.f,0.f,0.f,0.f};
    int i = beg;
    for (; i + 4 <= end; i += 4) {
      int s0 = nbr[i] * 4 + m, s1 = nbr[i+1] * 4 + m;
      int s2 = nbr[i+2] * 4 + m, s3 = nbr[i+3] * 4 + m;
      float xv0 = x0[s0], av0 = agg0[s0];
      float xv1 = x0[s1], av1 = agg0[s1];
      float xv2 = x0[s2], av2 = agg0[s2];
      float xv3 = x0[s3], av3 = agg0[s3];
      a0 = add4(a0, conv0f(xv0, av0, ws, wn));
      a1 = add4(a1, conv0f(xv1, av1, ws, wn));
      a2 = add4(a2, conv0f(xv2, av2, ws, wn));
      a3 = add4(a3, conv0f(xv3, av3, ws, wn));
    }
    for (; i < end; ++i) {
      int s0 = nbr[i] * 4 + m;
      a0 = add4(a0, conv0f(x0[s0], agg0[s0], ws, wn));
    }
    gacc[q] = add4(add4(a0, a1), add4(a2, a3));
  }
  __syncthreads();

  // P1: x0f @ Ws1
  f32x4 a0v = {0.f,0.f,0.f,0.f}, a1v = {0.f,0.f,0.f,0.f};
  MFMA_PHASE(a0v, a1v);
  __syncthreads();
#pragma unroll
  for (int q = 0; q < 2; ++q)                        // commit XAs = agg1 (bf16)
    *(ushort4*)&XAs[tr + (q << 5)][tc4] = f2b4(gacc[q]);
  STAGE_WT(1);                                       // WTl = Wn1^T
  __syncthreads();

  // P2: agg1 @ Wn1
  MFMA_PHASE(a0v, a1v);
  __syncthreads();
  DCOMMIT_RELU(a0v, a1v);                            // x1 (bf16) -> XAs
  __syncthreads();

  // coalesced copy XAs -> x1b
#pragma unroll
  for (int q = 0; q < 2; ++q) {
    int rr = tr + (q << 5);
    *(ushort4*)(x1b + (size_t)(row0 + rr) * 64 + tc4) = *(const ushort4*)&XAs[rr][tc4];
  }
}

// ---------- fused conv2 + 3-layer MLP + mean + min/max (512 thr, MFMA, bf16 LDS) ----------
//   P1 x1@Ws2->accP | P2 x1@W1b->accQ | P3 agg2@Wn2->accP, x2=relu
//   P4 x2@W1c->accQ | P5 x0f@W1a->accQ, h1=relu | P6 h1@W2 | P7 h2@W3

__global__ __launch_bounds__(512, 4) void fused2_k(const unsigned short* __restrict__ x1b,
    const int* __restrict__ rowstart, const int* __restrict__ nbr,
    const float* __restrict__ x0, const float* __restrict__ agg0,
    const float* __restrict__ Ws0, const float* __restrict__ Wn0,
    const unsigned short* __restrict__ wt,
    const float* __restrict__ b1, const float* __restrict__ b2,
    const float* __restrict__ b3,
    float* __restrict__ g, unsigned* __restrict__ mm) {
  __shared__ unsigned short XAs[64][72];
  __shared__ unsigned short WTl[64][72];
  __shared__ float red[16];
  const int row0 = blockIdx.x << 6;
  const int nb0  = blockIdx.x << 4;
  const int tid = threadIdx.x;
  const int tc4 = (tid & 15) << 2;
  const int tr  = tid >> 4;            // 0..31
  const int lane  = tid & 63;
  const int wid   = tid >> 6;
  const int mrow0 = (wid >> 1) << 4;
  const int ncol0 = (wid & 1) << 5;
  const int fl    = lane & 15;
  const int fk    = (lane >> 4) << 3;
  const int drow  = mrow0 + ((lane >> 4) << 2);
  const int dc0   = ncol0 + fl, dc1 = ncol0 + 16 + fl;

  // ---- prologue: XAs <- x1 (bf16 direct), WTl <- Ws2^T ----
#pragma unroll
  for (int q = 0; q < 2; ++q) {
    int rr = tr + (q << 5);
    *(ushort4*)&XAs[rr][tc4] = *(const ushort4*)(x1b + (size_t)(row0 + rr) * 64 + tc4);
  }
  STAGE_WT(2);

  // ---- gather agg2 from bf16 x1 (2 nodes/thread, 4-deep MLP) ----
  float4 gacc[2];
#pragma unroll
  for (int q = 0; q < 2; ++q) {
    int rr = tr + (q << 5);
    int n = nb0 + (rr >> 2), m = rr & 3;
    int beg = rowstart[n], end = rowstart[n + 1];
    float4 a0 = {0.f,0.f,0.f,0.f}, a1 = {0.f,0.f,0.f,0.f};
    float4 a2 = {0.f,0.f,0.f,0.f}, a3 = {0.f,0.f,0.f,0.f};
    int i = beg;
    for (; i + 4 <= end; i += 4) {
      ushort4 v0 = *(const ushort4*)(x1b + (size_t)(nbr[i]   * 4 + m) * 64 + tc4);
      ushort4 v1 = *(const ushort4*)(x1b + (size_t)(nbr[i+1] * 4 + m) * 64 + tc4);
      ushort4 v2 = *(const ushort4*)(x1b + (size_t)(nbr[i+2] * 4 + m) * 64 + tc4);
      ushort4 v3 = *(const ushort4*)(x1b + (size_t)(nbr[i+3] * 4 + m) * 64 + tc4);
      a0 = add4(a0, b2f4(v0)); a1 = add4(a1, b2f4(v1));
      a2 = add4(a2, b2f4(v2)); a3 = add4(a3, b2f4(v3));
    }
    for (; i < end; ++i)
      a0 = add4(a0, b2f4(*(const ushort4*)(x1b + (size_t)(nbr[i] * 4 + m) * 64 + tc4)));
    gacc[q] = add4(add4(a0, a1), add4(a2, a3));
  }
  __syncthreads();

  // ---- P1: accP = x1 @ Ws2 ----
  f32x4 accP0 = {0.f,0.f,0.f,0.f}, accP1 = {0.f,0.f,0.f,0.f};
  MFMA_PHASE(accP0, accP1);
  __syncthreads();
  STAGE_WT(3);                                       // W1b^T
  __syncthreads();

  // ---- P2: accQ = b1 + x1 @ W1b ----
  f32x4 accQ0, accQ1;
  {
    float bv0 = b1[dc0], bv1 = b1[dc1];
    accQ0[0]=bv0; accQ0[1]=bv0; accQ0[2]=bv0; accQ0[3]=bv0;
    accQ1[0]=bv1; accQ1[1]=bv1; accQ1[2]=bv1; accQ1[3]=bv1;
  }
  MFMA_PHASE(accQ0, accQ1);
  __syncthreads();
#pragma unroll
  for (int q = 0; q < 2; ++q)                        // commit XAs = agg2 (bf16)
    *(ushort4*)&XAs[tr + (q << 5)][tc4] = f2b4(gacc[q]);
  STAGE_WT(4);                                       // Wn2^T
  __syncthreads();

  // ---- P3: accP += agg2 @ Wn2 ; x2 = relu(accP) ----
  MFMA_PHASE(accP0, accP1);
  __syncthreads();
  DCOMMIT_RELU(accP0, accP1);                        // x2 -> XAs
  STAGE_WT(5);                                       // W1c^T
  __syncthreads();

  // ---- P4: accQ += x2 @ W1c ----
  MFMA_PHASE(accQ0, accQ1);
  __syncthreads();
  {
    float4 ws = *(const float4*)(Ws0 + tc4);
    float4 wn = *(const float4*)(Wn0 + tc4);
#pragma unroll
    for (int q = 0; q < 2; ++q) {                    // commit XAs = x0feat (bf16)
      int rr = tr + (q << 5);
      *(ushort4*)&XAs[rr][tc4] = f2b4(conv0f(x0[row0 + rr], agg0[row0 + rr], ws, wn));
    }
  }
  STAGE_WT(6);                                       // W1a^T
  __syncthreads();

  // ---- P5: accQ += x0f @ W1a ; h1 = relu(accQ) ----
  MFMA_PHASE(accQ0, accQ1);
  __syncthreads();
  DCOMMIT_RELU(accQ0, accQ1);                        // h1 -> XAs
  STAGE_WT(7);                                       // W2^T
  __syncthreads();

  // ---- P6: accR = b2 + h1 @ W2 ; h2 = relu ----
  f32x4 accR0, accR1;
  {
    float bv0 = b2[dc0], bv1 = b2[dc1];
    accR0[0]=bv0; accR0[1]=bv0; accR0[2]=bv0; accR0[3]=bv0;
    accR1[0]=bv1; accR1[1]=bv1; accR1[2]=bv1; accR1[3]=bv1;
  }
  MFMA_PHASE(accR0, accR1);
  __syncthreads();
  DCOMMIT_RELU(accR0, accR1);                        // h2 -> XAs
  STAGE_WT(8);                                       // W3^T
  __syncthreads();

  // ---- P7: accS = b3 + h2 @ W3 (no relu) ----
  f32x4 accS0, accS1;
  {
    float bv0 = b3[dc0], bv1 = b3[dc1];
    accS0[0]=bv0; accS0[1]=bv0; accS0[2]=bv0; accS0[3]=bv0;
    accS1[0]=bv1; accS1[1]=bv1; accS1[2]=bv1; accS1[3]=bv1;
  }
  MFMA_PHASE(accS0, accS1);
  __syncthreads();
#pragma unroll
  for (int j = 0; j < 4; ++j) {                      // h3 -> XAs (no relu)
    XAs[drow + j][dc0] = bf16rn(accS0[j]);
    XAs[drow + j][dc1] = bf16rn(accS1[j]);
  }
  __syncthreads();

  // ---- mean over M + per-block min/max ----
  float lmin = 3.4e38f, lmax = -3.4e38f;
  for (int k = tid; k < 1024; k += 512) {
    int nl = k >> 6, c = k & 63;
    float s = 0.25f * (bf2f(XAs[4*nl][c]) + bf2f(XAs[4*nl+1][c]) +
                       bf2f(XAs[4*nl+2][c]) + bf2f(XAs[4*nl+3][c]));
    g[(size_t)((row0 >> 2) + nl) * 64 + c] = s;
    lmin = fminf(lmin, s);
    lmax = fmaxf(lmax, s);
  }
#pragma unroll
  for (int off = 32; off; off >>= 1) {
    lmin = fminf(lmin, __shfl_xor(lmin, off));
    lmax = fmaxf(lmax, __shfl_xor(lmax, off));
  }
  if ((tid & 63) == 0) { red[tid >> 6] = lmin; red[8 + (tid >> 6)] = lmax; }
  __syncthreads();
  if (tid == 0) {
    float m0 = red[0], m1 = red[8];
#pragma unroll
    for (int w = 1; w < 8; ++w) {
      m0 = fminf(m0, red[w]);
      m1 = fmaxf(m1, red[8 + w]);
    }
    atomicMin(&mm[0], enc_f(m0));
    atomicMax(&mm[1], enc_f(m1));
  }
}

// ---------- rescale + pool (sorted batch -> run-length accumulate) ----------

__global__ __launch_bounds__(256) void pool2_k(const float* __restrict__ g,
                                               const int* __restrict__ batch,
                                               const unsigned* __restrict__ mm,
                                               float* __restrict__ pooled) {
  int c = threadIdx.x & 63;
  int grp = threadIdx.x >> 6;                        // 0..3
  int base = blockIdx.x * 64 + grp * 16;             // 16 consecutive nodes per group
  float gmin = dec_f(mm[0]);
  float sc = 2.0f / (dec_f(mm[1]) - gmin);
  float acc = 0.0f; int cur = -1;
  for (int i = 0; i < 16; ++i) {
    int n = base + i;
    if (n >= NN) break;
    int b = batch[n];
    if (b != cur) {
      if (cur >= 0) unsafeAtomicAdd(&pooled[(cur << 6) + c], acc);
      cur = b; acc = 0.0f;
    }
    acc += (g[(size_t)n * 64 + c] - gmin) * sc;
  }
  if (cur >= 0) unsafeAtomicAdd(&pooled[(cur << 6) + c], acc);
}

// ---------- out[b] = pooled[b,:] . Wo + bo ----------

__global__ void out_k(const float* __restrict__ pooled, const float* __restrict__ Wo,
                      const float* __restrict__ bo, float* __restrict__ out) {
  int b = blockIdx.x, l = threadIdx.x;
  float v = pooled[(b << 6) + l] * Wo[l];
#pragma unroll
  for (int off = 32; off; off >>= 1) v += __shfl_xor(v, off);
  if (l == 0) out[b] = v + bo[0];
}

// ---------- launch ----------

extern "C" void kernel_launch(void* const* d_in, const int* in_sizes, int n_in,
                              void* d_out, int out_size, void* d_ws, size_t ws_size,
                              hipStream_t stream) {
  const float* x0   = (const float*)d_in[0];
  const int*   ei   = (const int*)d_in[1];
  const int*   batch= (const int*)d_in[2];
  const float* Ws0  = (const float*)d_in[3];
  const float* Wn0  = (const float*)d_in[4];
  const float* Ws1  = (const float*)d_in[5];
  const float* Wn1  = (const float*)d_in[6];
  const float* Ws2  = (const float*)d_in[7];
  const float* Wn2  = (const float*)d_in[8];
  const float* W1   = (const float*)d_in[9];
  const float* b1   = (const float*)d_in[10];
  const float* W2   = (const float*)d_in[11];
  const float* b2   = (const float*)d_in[12];
  const float* W3   = (const float*)d_in[13];
  const float* b3   = (const float*)d_in[14];
  const float* Wo   = (const float*)d_in[15];
  const float* bo   = (const float*)d_in[16];
  float* out = (float*)d_out;

  unsigned short* x1b = (unsigned short*)d_ws;        // [NROWS,64] bf16
  unsigned short* wt  = x1b + (size_t)NROWS * 64;     // [9][64][64] bf16 transposed
  float* agg0   = (float*)(wt + 9 * 4096);            // [NROWS]
  float* g      = agg0 + NROWS;                       // [NN,64]
  float* pooled = g    + (size_t)NN * 64;             // [BB,64]
  unsigned* mm  = (unsigned*)(pooled + BB * 64);      // [2]
  int* deg      = (int*)(mm + 2);                     // [NN]
  int* rowstart = deg + NN;                           // [NN+1]
  int* cursor   = rowstart + NN + 1;                  // [NN]
  int* nbr      = cursor + NN;                        // [EE]
  int* bsum     = nbr + EE;                           // [NBLK_SCAN]

  // ---- CSR build + weight prep ----
  hipMemsetAsync(deg, 0, NN * sizeof(int), stream);
  hist_k<<<(EE + 255) / 256, 256, 0, stream>>>(ei, deg);
  prepw_k<<<144, 256, 0, stream>>>(Ws1, Wn1, Ws2, Wn2, W1, W2, W3, wt);
  scan1_k<<<NBLK_SCAN, 512, 0, stream>>>(deg, rowstart, bsum);
  scan2_k<<<1, 64, 0, stream>>>(bsum);
  scan3_k<<<NBLK_SCAN, 512, 0, stream>>>(rowstart, cursor, bsum);
  fill_k<<<(EE + 255) / 256, 256, 0, stream>>>(ei, cursor, nbr);

  // ---- layer 0 aggregate (scalar) ----
  agg0_gather_k<<<(NROWS + 255) / 256, 256, 0, stream>>>(x0, rowstart, nbr, agg0);

  // ---- layer 1 (agg1 gather fused, MFMA) -> x1 (bf16) ----
  conv1_k<<<NROWS / 64, 512, 0, stream>>>(x0, agg0, rowstart, nbr,
                                          Ws0, Wn0, wt, x1b);

  // ---- fused conv2 + MLP + mean + min/max (MFMA, bf16 LDS) ----
  hipMemsetAsync(mm, 0xFF, 4, stream);
  hipMemsetAsync(mm + 1, 0x00, 4, stream);
  fused2_k<<<NROWS / 64, 512, 0, stream>>>(x1b, rowstart, nbr, x0, agg0,
                                           Ws0, Wn0, wt, b1, b2, b3, g, mm);

  // ---- rescale + pooling ----
  hipMemsetAsync(pooled, 0, BB * 64 * sizeof(float), stream);
  pool2_k<<<(NN + 63) / 64, 256, 0, stream>>>(g, batch, mm, pooled);

  // ---- output linear ----
  out_k<<<BB, 64, 0, stream>>>(pooled, Wo, bo, out);
}

// Round 13
// 210.615 us; speedup vs baseline: 22.8582x; 1.0591x over previous
//
#include <hip/hip_runtime.h>
#include <math.h>

#define NN 50000
#define MM 4
#define EE 400000
#define BB 64
#define NROWS (NN*MM)           // 200000
#define NBLK_SCAN 98            // ceil(50000/512)

typedef __attribute__((ext_vector_type(8))) short bf16x8;
typedef __attribute__((ext_vector_type(4))) float f32x4;

struct f8 { float4 lo, hi; };

// ---------- helpers ----------

__device__ __forceinline__ unsigned enc_f(float f) {
  unsigned u = __float_as_uint(f);
  return (u & 0x80000000u) ? ~u : (u | 0x80000000u);
}
__device__ __forceinline__ float dec_f(unsigned u) {
  return (u & 0x80000000u) ? __uint_as_float(u ^ 0x80000000u) : __uint_as_float(~u);
}

__device__ __forceinline__ unsigned short bf16rn(float f) {
  unsigned u = __float_as_uint(f);
  return (unsigned short)((u + 0x7FFFu + ((u >> 16) & 1u)) >> 16);
}
__device__ __forceinline__ float bf2f(unsigned short h) {
  return __uint_as_float(((unsigned)h) << 16);
}

__device__ __forceinline__ f8 zero8() {
  f8 r; r.lo = make_float4(0.f,0.f,0.f,0.f); r.hi = r.lo; return r;
}
__device__ __forceinline__ void add8(f8& a, const f8& b) {
  a.lo.x += b.lo.x; a.lo.y += b.lo.y; a.lo.z += b.lo.z; a.lo.w += b.lo.w;
  a.hi.x += b.hi.x; a.hi.y += b.hi.y; a.hi.z += b.hi.z; a.hi.w += b.hi.w;
}
__device__ __forceinline__ f8 b2f8(bf16x8 v) {
  f8 r;
  r.lo = make_float4(bf2f((unsigned short)v[0]), bf2f((unsigned short)v[1]),
                     bf2f((unsigned short)v[2]), bf2f((unsigned short)v[3]));
  r.hi = make_float4(bf2f((unsigned short)v[4]), bf2f((unsigned short)v[5]),
                     bf2f((unsigned short)v[6]), bf2f((unsigned short)v[7]));
  return r;
}
__device__ __forceinline__ bf16x8 f2b8(const f8& v) {
  bf16x8 h;
  h[0] = (short)bf16rn(v.lo.x); h[1] = (short)bf16rn(v.lo.y);
  h[2] = (short)bf16rn(v.lo.z); h[3] = (short)bf16rn(v.lo.w);
  h[4] = (short)bf16rn(v.hi.x); h[5] = (short)bf16rn(v.hi.y);
  h[6] = (short)bf16rn(v.hi.z); h[7] = (short)bf16rn(v.hi.w);
  return h;
}
// relu(xv*ws + av*wn) over 8 cols
__device__ __forceinline__ f8 conv0f8(float xv, float av, const f8& ws, const f8& wn) {
  f8 t;
  t.lo.x = fmaxf(fmaf(xv, ws.lo.x, av * wn.lo.x), 0.f);
  t.lo.y = fmaxf(fmaf(xv, ws.lo.y, av * wn.lo.y), 0.f);
  t.lo.z = fmaxf(fmaf(xv, ws.lo.z, av * wn.lo.z), 0.f);
  t.lo.w = fmaxf(fmaf(xv, ws.lo.w, av * wn.lo.w), 0.f);
  t.hi.x = fmaxf(fmaf(xv, ws.hi.x, av * wn.hi.x), 0.f);
  t.hi.y = fmaxf(fmaf(xv, ws.hi.y, av * wn.hi.y), 0.f);
  t.hi.z = fmaxf(fmaf(xv, ws.hi.z, av * wn.hi.z), 0.f);
  t.hi.w = fmaxf(fmaf(xv, ws.hi.w, av * wn.hi.w), 0.f);
  return t;
}

// ---------- CSR build (dst-major neighbor lists) ----------

__global__ void hist_k(const int* __restrict__ ei, int* __restrict__ deg) {
  int e = blockIdx.x * blockDim.x + threadIdx.x;
  if (e < EE) atomicAdd(&deg[ei[EE + e]], 1);
}

__global__ __launch_bounds__(512) void scan1_k(const int* __restrict__ deg,
                                               int* __restrict__ rowstart,
                                               int* __restrict__ bsum) {
  __shared__ int s[512];
  int i = blockIdx.x * 512 + threadIdx.x;
  int v = (i < NN) ? deg[i] : 0;
  s[threadIdx.x] = v;
  __syncthreads();
  for (int off = 1; off < 512; off <<= 1) {
    int t = (threadIdx.x >= (unsigned)off) ? s[threadIdx.x - off] : 0;
    __syncthreads();
    s[threadIdx.x] += t;
    __syncthreads();
  }
  if (i < NN) rowstart[i] = s[threadIdx.x] - v;      // exclusive partial
  if (threadIdx.x == 511) bsum[blockIdx.x] = s[511];
}

__global__ void scan2_k(int* __restrict__ bsum) {
  if (threadIdx.x == 0) {
    int acc = 0;
    for (int k = 0; k < NBLK_SCAN; ++k) { int t = bsum[k]; bsum[k] = acc; acc += t; }
  }
}

__global__ __launch_bounds__(512) void scan3_k(int* __restrict__ rowstart,
                                               int* __restrict__ cursor,
                                               const int* __restrict__ bsum) {
  int i = blockIdx.x * 512 + threadIdx.x;
  if (i < NN) {
    int v = rowstart[i] + bsum[blockIdx.x];
    rowstart[i] = v;
    cursor[i] = v;
  }
  if (i == 0) rowstart[NN] = EE;
}

__global__ void fill_k(const int* __restrict__ ei, int* __restrict__ cursor,
                       int* __restrict__ nbr) {
  int e = blockIdx.x * blockDim.x + threadIdx.x;
  if (e >= EE) return;
  int d = ei[EE + e];
  int p = atomicAdd(&cursor[d], 1);
  nbr[p] = ei[e];
}

// ---------- weight prep: 9 matrices transposed+bf16 into wt[m][c][k] ----------
// 0:Ws1 1:Wn1 2:Ws2 3:W1b 4:Wn2 5:W1c 6:W1a 7:W2 8:W3

__global__ void prepw_k(const float* __restrict__ Ws1, const float* __restrict__ Wn1,
                        const float* __restrict__ Ws2, const float* __restrict__ Wn2,
                        const float* __restrict__ W1,  const float* __restrict__ W2,
                        const float* __restrict__ W3,  unsigned short* __restrict__ wt) {
  int idx = blockIdx.x * 256 + threadIdx.x;
  if (idx >= 9 * 4096) return;
  int m = idx >> 12, r = idx & 4095;
  int c = r >> 6, k = r & 63;
  const float* src = Ws1;
  switch (m) {
    case 0: src = Ws1; break;
    case 1: src = Wn1; break;
    case 2: src = Ws2; break;
    case 3: src = W1 + 64 * 64; break;
    case 4: src = Wn2; break;
    case 5: src = W1 + 128 * 64; break;
    case 6: src = W1; break;
    case 7: src = W2; break;
    case 8: src = W3; break;
  }
  wt[idx] = bf16rn(src[k * 64 + c]);
}

// ---------- aggregation 0: agg0[n*4+m] = sum_{s in N(n)} x0[s*4+m] ----------

__global__ void agg0_gather_k(const float* __restrict__ x0,
                              const int* __restrict__ rowstart,
                              const int* __restrict__ nbr,
                              float* __restrict__ agg0) {
  int idx = blockIdx.x * blockDim.x + threadIdx.x;   // NROWS
  if (idx >= NROWS) return;
  int n = idx >> 2, m = idx & 3;
  int beg = rowstart[n], end = rowstart[n + 1];
  float acc = 0.0f;
  for (int i = beg; i < end; ++i) acc += x0[nbr[i] * 4 + m];
  agg0[idx] = acc;
}

// ---------- shared MFMA machinery (bf16 LDS tiles, 72-short rows = 144B aligned) ----------

#define STAGE_WT(mi)                                                        \
  *(bf16x8*)&WTl[tid >> 3][(tid & 7) << 3] =                                \
      ((const bf16x8*)((const short*)wt + (mi) * 4096))[tid];

#define MFMA_PHASE(A0, A1)                                              \
  _Pragma("unroll")                                                     \
  for (int kh = 0; kh < 2; ++kh) {                                      \
    bf16x8 af  = *(const bf16x8*)&XAs[mrow0 + fl][(kh << 5) + fk];      \
    bf16x8 bf0 = *(const bf16x8*)&WTl[ncol0 + fl][(kh << 5) + fk];      \
    bf16x8 bf1 = *(const bf16x8*)&WTl[ncol0 + 16 + fl][(kh << 5) + fk]; \
    A0 = __builtin_amdgcn_mfma_f32_16x16x32_bf16(af, bf0, A0, 0, 0, 0); \
    A1 = __builtin_amdgcn_mfma_f32_16x16x32_bf16(af, bf1, A1, 0, 0, 0); \
  }

#define DCOMMIT_RELU(A0, A1)                                            \
  _Pragma("unroll")                                                     \
  for (int j = 0; j < 4; ++j) {                                         \
    XAs[drow + j][dc0] = bf16rn(fmaxf(A0[j], 0.f));                     \
    XAs[drow + j][dc1] = bf16rn(fmaxf(A1[j], 0.f));                     \
  }

// ---------- conv1 (gather fused, 512 thr, MFMA): x1 = relu(x0f@Ws1 + agg1@Wn1) -> bf16 ----------
// thread -> (row r = tid>>3, 8 cols at c8 = (tid&7)*8)

__global__ __launch_bounds__(512, 4) void conv1_k(const float* __restrict__ x0,
                                                  const float* __restrict__ agg0,
                                                  const int* __restrict__ rowstart,
                                                  const int* __restrict__ nbr,
                                                  const float* __restrict__ Ws0,
                                                  const float* __restrict__ Wn0,
                                                  const unsigned short* __restrict__ wt,
                                                  unsigned short* __restrict__ x1b) {
  __shared__ unsigned short XAs[64][72];
  __shared__ unsigned short WTl[64][72];
  const int row0 = blockIdx.x << 6;
  const int nb0  = blockIdx.x << 4;
  const int tid = threadIdx.x;
  const int r   = tid >> 3;            // 0..63
  const int c8  = (tid & 7) << 3;      // 0..56
  const int lane  = tid & 63;
  const int wid   = tid >> 6;
  const int mrow0 = (wid >> 1) << 4;
  const int ncol0 = (wid & 1) << 5;
  const int fl    = lane & 15;
  const int fk    = (lane >> 4) << 3;
  const int drow  = mrow0 + ((lane >> 4) << 2);
  const int dc0   = ncol0 + fl, dc1 = ncol0 + 16 + fl;

  f8 ws8, wn8;
  ws8.lo = *(const float4*)(Ws0 + c8); ws8.hi = *(const float4*)(Ws0 + c8 + 4);
  wn8.lo = *(const float4*)(Wn0 + c8); wn8.hi = *(const float4*)(Wn0 + c8 + 4);

  // stage XAs = x0feat (recomputed, bf16), WTl = Ws1^T
  *(bf16x8*)&XAs[r][c8] = f2b8(conv0f8(x0[row0 + r], agg0[row0 + r], ws8, wn8));
  STAGE_WT(0);

  // gather agg1: one (n,m) row slice per thread, 4-deep + predicated tail
  const int n = nb0 + (r >> 2), m = r & 3;
  f8 ga;
  {
    int beg = rowstart[n], end = rowstart[n + 1];
    f8 a0 = zero8(), a1 = zero8();
    int i = beg;
    for (; i + 4 <= end; i += 4) {
      int s0 = nbr[i] * 4 + m, s1 = nbr[i+1] * 4 + m;
      int s2 = nbr[i+2] * 4 + m, s3 = nbr[i+3] * 4 + m;
      float xv0 = x0[s0], av0 = agg0[s0];
      float xv1 = x0[s1], av1 = agg0[s1];
      float xv2 = x0[s2], av2 = agg0[s2];
      float xv3 = x0[s3], av3 = agg0[s3];
      f8 t0 = conv0f8(xv0, av0, ws8, wn8); add8(a0, t0);
      f8 t1 = conv0f8(xv1, av1, ws8, wn8); add8(a1, t1);
      f8 t2 = conv0f8(xv2, av2, ws8, wn8); add8(a0, t2);
      f8 t3 = conv0f8(xv3, av3, ws8, wn8); add8(a1, t3);
    }
    bool p0 = i < end, p1 = i + 1 < end, p2 = i + 2 < end;
    float xv0 = 0.f, av0 = 0.f, xv1 = 0.f, av1 = 0.f, xv2 = 0.f, av2 = 0.f;
    if (p0) { int s = nbr[i]     * 4 + m; xv0 = x0[s]; av0 = agg0[s]; }
    if (p1) { int s = nbr[i + 1] * 4 + m; xv1 = x0[s]; av1 = agg0[s]; }
    if (p2) { int s = nbr[i + 2] * 4 + m; xv2 = x0[s]; av2 = agg0[s]; }
    if (p0) { f8 t = conv0f8(xv0, av0, ws8, wn8); add8(a0, t); }
    if (p1) { f8 t = conv0f8(xv1, av1, ws8, wn8); add8(a1, t); }
    if (p2) { f8 t = conv0f8(xv2, av2, ws8, wn8); add8(a0, t); }
    add8(a0, a1);
    ga = a0;
  }
  __syncthreads();

  // P1: x0f @ Ws1
  f32x4 a0v = {0.f,0.f,0.f,0.f}, a1v = {0.f,0.f,0.f,0.f};
  MFMA_PHASE(a0v, a1v);
  __syncthreads();
  *(bf16x8*)&XAs[r][c8] = f2b8(ga);                  // commit XAs = agg1
  STAGE_WT(1);                                       // WTl = Wn1^T
  __syncthreads();

  // P2: agg1 @ Wn1
  MFMA_PHASE(a0v, a1v);
  __syncthreads();
  DCOMMIT_RELU(a0v, a1v);                            // x1 (bf16) -> XAs
  __syncthreads();

  // coalesced copy XAs -> x1b (16B per thread)
  *(bf16x8*)(x1b + (size_t)(row0 + r) * 64 + c8) = *(const bf16x8*)&XAs[r][c8];
}

// ---------- fused conv2 + 3-layer MLP + mean + min/max (512 thr, MFMA, bf16 LDS) ----------
//   P1 x1@Ws2->accP | P2 x1@W1b->accQ | P3 agg2@Wn2->accP, x2=relu
//   P4 x2@W1c->accQ | P5 x0f@W1a->accQ, h1=relu | P6 h1@W2 | P7 h2@W3

__global__ __launch_bounds__(512, 4) void fused2_k(const unsigned short* __restrict__ x1b,
    const int* __restrict__ rowstart, const int* __restrict__ nbr,
    const float* __restrict__ x0, const float* __restrict__ agg0,
    const float* __restrict__ Ws0, const float* __restrict__ Wn0,
    const unsigned short* __restrict__ wt,
    const float* __restrict__ b1, const float* __restrict__ b2,
    const float* __restrict__ b3,
    float* __restrict__ g, unsigned* __restrict__ mm) {
  __shared__ unsigned short XAs[64][72];
  __shared__ unsigned short WTl[64][72];
  __shared__ float red[16];
  const int row0 = blockIdx.x << 6;
  const int nb0  = blockIdx.x << 4;
  const int tid = threadIdx.x;
  const int r   = tid >> 3;            // 0..63
  const int c8  = (tid & 7) << 3;      // 0..56
  const int lane  = tid & 63;
  const int wid   = tid >> 6;
  const int mrow0 = (wid >> 1) << 4;
  const int ncol0 = (wid & 1) << 5;
  const int fl    = lane & 15;
  const int fk    = (lane >> 4) << 3;
  const int drow  = mrow0 + ((lane >> 4) << 2);
  const int dc0   = ncol0 + fl, dc1 = ncol0 + 16 + fl;

  // ---- prologue: XAs <- x1 (bf16 direct, 16B), WTl <- Ws2^T ----
  *(bf16x8*)&XAs[r][c8] = *(const bf16x8*)(x1b + (size_t)(row0 + r) * 64 + c8);
  STAGE_WT(2);

  // ---- gather agg2 from bf16 x1: one row slice/thread, 16B loads, 4-deep + predicated tail ----
  const int n = nb0 + (r >> 2), m = r & 3;
  f8 ga;
  {
    int beg = rowstart[n], end = rowstart[n + 1];
    f8 a0 = zero8(), a1 = zero8();
    int i = beg;
    for (; i + 4 <= end; i += 4) {
      bf16x8 v0 = *(const bf16x8*)(x1b + (size_t)(nbr[i]   * 4 + m) * 64 + c8);
      bf16x8 v1 = *(const bf16x8*)(x1b + (size_t)(nbr[i+1] * 4 + m) * 64 + c8);
      bf16x8 v2 = *(const bf16x8*)(x1b + (size_t)(nbr[i+2] * 4 + m) * 64 + c8);
      bf16x8 v3 = *(const bf16x8*)(x1b + (size_t)(nbr[i+3] * 4 + m) * 64 + c8);
      f8 t0 = b2f8(v0); add8(a0, t0);
      f8 t1 = b2f8(v1); add8(a1, t1);
      f8 t2 = b2f8(v2); add8(a0, t2);
      f8 t3 = b2f8(v3); add8(a1, t3);
    }
    bool p0 = i < end, p1 = i + 1 < end, p2 = i + 2 < end;
    bf16x8 v0 = {}, v1 = {}, v2 = {};
    if (p0) v0 = *(const bf16x8*)(x1b + (size_t)(nbr[i]     * 4 + m) * 64 + c8);
    if (p1) v1 = *(const bf16x8*)(x1b + (size_t)(nbr[i + 1] * 4 + m) * 64 + c8);
    if (p2) v2 = *(const bf16x8*)(x1b + (size_t)(nbr[i + 2] * 4 + m) * 64 + c8);
    if (p0) { f8 t = b2f8(v0); add8(a0, t); }
    if (p1) { f8 t = b2f8(v1); add8(a1, t); }
    if (p2) { f8 t = b2f8(v2); add8(a0, t); }
    add8(a0, a1);
    ga = a0;
  }
  __syncthreads();

  // ---- P1: accP = x1 @ Ws2 ----
  f32x4 accP0 = {0.f,0.f,0.f,0.f}, accP1 = {0.f,0.f,0.f,0.f};
  MFMA_PHASE(accP0, accP1);
  __syncthreads();
  STAGE_WT(3);                                       // W1b^T
  __syncthreads();

  // ---- P2: accQ = b1 + x1 @ W1b ----
  f32x4 accQ0, accQ1;
  {
    float bv0 = b1[dc0], bv1 = b1[dc1];
    accQ0[0]=bv0; accQ0[1]=bv0; accQ0[2]=bv0; accQ0[3]=bv0;
    accQ1[0]=bv1; accQ1[1]=bv1; accQ1[2]=bv1; accQ1[3]=bv1;
  }
  MFMA_PHASE(accQ0, accQ1);
  __syncthreads();
  *(bf16x8*)&XAs[r][c8] = f2b8(ga);                  // commit XAs = agg2
  STAGE_WT(4);                                       // Wn2^T
  __syncthreads();

  // ---- P3: accP += agg2 @ Wn2 ; x2 = relu(accP) ----
  MFMA_PHASE(accP0, accP1);
  __syncthreads();
  DCOMMIT_RELU(accP0, accP1);                        // x2 -> XAs
  STAGE_WT(5);                                       // W1c^T
  __syncthreads();

  // ---- P4: accQ += x2 @ W1c ----
  MFMA_PHASE(accQ0, accQ1);
  __syncthreads();
  {
    f8 ws8, wn8;
    ws8.lo = *(const float4*)(Ws0 + c8); ws8.hi = *(const float4*)(Ws0 + c8 + 4);
    wn8.lo = *(const float4*)(Wn0 + c8); wn8.hi = *(const float4*)(Wn0 + c8 + 4);
    *(bf16x8*)&XAs[r][c8] =
        f2b8(conv0f8(x0[row0 + r], agg0[row0 + r], ws8, wn8));  // XAs = x0feat
  }
  STAGE_WT(6);                                       // W1a^T
  __syncthreads();

  // ---- P5: accQ += x0f @ W1a ; h1 = relu(accQ) ----
  MFMA_PHASE(accQ0, accQ1);
  __syncthreads();
  DCOMMIT_RELU(accQ0, accQ1);                        // h1 -> XAs
  STAGE_WT(7);                                       // W2^T
  __syncthreads();

  // ---- P6: accR = b2 + h1 @ W2 ; h2 = relu ----
  f32x4 accR0, accR1;
  {
    float bv0 = b2[dc0], bv1 = b2[dc1];
    accR0[0]=bv0; accR0[1]=bv0; accR0[2]=bv0; accR0[3]=bv0;
    accR1[0]=bv1; accR1[1]=bv1; accR1[2]=bv1; accR1[3]=bv1;
  }
  MFMA_PHASE(accR0, accR1);
  __syncthreads();
  DCOMMIT_RELU(accR0, accR1);                        // h2 -> XAs
  STAGE_WT(8);                                       // W3^T
  __syncthreads();

  // ---- P7: accS = b3 + h2 @ W3 (no relu) ----
  f32x4 accS0, accS1;
  {
    float bv0 = b3[dc0], bv1 = b3[dc1];
    accS0[0]=bv0; accS0[1]=bv0; accS0[2]=bv0; accS0[3]=bv0;
    accS1[0]=bv1; accS1[1]=bv1; accS1[2]=bv1; accS1[3]=bv1;
  }
  MFMA_PHASE(accS0, accS1);
  __syncthreads();
#pragma unroll
  for (int j = 0; j < 4; ++j) {                      // h3 -> XAs (no relu)
    XAs[drow + j][dc0] = bf16rn(accS0[j]);
    XAs[drow + j][dc1] = bf16rn(accS1[j]);
  }
  __syncthreads();

  // ---- mean over M + per-block min/max ----
  float lmin = 3.4e38f, lmax = -3.4e38f;
  for (int k = tid; k < 1024; k += 512) {
    int nl = k >> 6, c = k & 63;
    float s = 0.25f * (bf2f(XAs[4*nl][c]) + bf2f(XAs[4*nl+1][c]) +
                       bf2f(XAs[4*nl+2][c]) + bf2f(XAs[4*nl+3][c]));
    g[(size_t)((row0 >> 2) + nl) * 64 + c] = s;
    lmin = fminf(lmin, s);
    lmax = fmaxf(lmax, s);
  }
#pragma unroll
  for (int off = 32; off; off >>= 1) {
    lmin = fminf(lmin, __shfl_xor(lmin, off));
    lmax = fmaxf(lmax, __shfl_xor(lmax, off));
  }
  if ((tid & 63) == 0) { red[tid >> 6] = lmin; red[8 + (tid >> 6)] = lmax; }
  __syncthreads();
  if (tid == 0) {
    float m0 = red[0], m1 = red[8];
#pragma unroll
    for (int w = 1; w < 8; ++w) {
      m0 = fminf(m0, red[w]);
      m1 = fmaxf(m1, red[8 + w]);
    }
    atomicMin(&mm[0], enc_f(m0));
    atomicMax(&mm[1], enc_f(m1));
  }
}

// ---------- rescale + pool (sorted batch -> run-length accumulate) ----------

__global__ __launch_bounds__(256) void pool2_k(const float* __restrict__ g,
                                               const int* __restrict__ batch,
                                               const unsigned* __restrict__ mm,
                                               float* __restrict__ pooled) {
  int c = threadIdx.x & 63;
  int grp = threadIdx.x >> 6;                        // 0..3
  int base = blockIdx.x * 64 + grp * 16;             // 16 consecutive nodes per group
  float gmin = dec_f(mm[0]);
  float sc = 2.0f / (dec_f(mm[1]) - gmin);
  float acc = 0.0f; int cur = -1;
  for (int i = 0; i < 16; ++i) {
    int n = base + i;
    if (n >= NN) break;
    int b = batch[n];
    if (b != cur) {
      if (cur >= 0) unsafeAtomicAdd(&pooled[(cur << 6) + c], acc);
      cur = b; acc = 0.0f;
    }
    acc += (g[(size_t)n * 64 + c] - gmin) * sc;
  }
  if (cur >= 0) unsafeAtomicAdd(&pooled[(cur << 6) + c], acc);
}

// ---------- out[b] = pooled[b,:] . Wo + bo ----------

__global__ void out_k(const float* __restrict__ pooled, const float* __restrict__ Wo,
                      const float* __restrict__ bo, float* __restrict__ out) {
  int b = blockIdx.x, l = threadIdx.x;
  float v = pooled[(b << 6) + l] * Wo[l];
#pragma unroll
  for (int off = 32; off; off >>= 1) v += __shfl_xor(v, off);
  if (l == 0) out[b] = v + bo[0];
}

// ---------- launch ----------

extern "C" void kernel_launch(void* const* d_in, const int* in_sizes, int n_in,
                              void* d_out, int out_size, void* d_ws, size_t ws_size,
                              hipStream_t stream) {
  const float* x0   = (const float*)d_in[0];
  const int*   ei   = (const int*)d_in[1];
  const int*   batch= (const int*)d_in[2];
  const float* Ws0  = (const float*)d_in[3];
  const float* Wn0  = (const float*)d_in[4];
  const float* Ws1  = (const float*)d_in[5];
  const float* Wn1  = (const float*)d_in[6];
  const float* Ws2  = (const float*)d_in[7];
  const float* Wn2  = (const float*)d_in[8];
  const float* W1   = (const float*)d_in[9];
  const float* b1   = (const float*)d_in[10];
  const float* W2   = (const float*)d_in[11];
  const float* b2   = (const float*)d_in[12];
  const float* W3   = (const float*)d_in[13];
  const float* b3   = (const float*)d_in[14];
  const float* Wo   = (const float*)d_in[15];
  const float* bo   = (const float*)d_in[16];
  float* out = (float*)d_out;

  unsigned short* x1b = (unsigned short*)d_ws;        // [NROWS,64] bf16
  unsigned short* wt  = x1b + (size_t)NROWS * 64;     // [9][64][64] bf16 transposed
  float* agg0   = (float*)(wt + 9 * 4096);            // [NROWS]
  float* g      = agg0 + NROWS;                       // [NN,64]
  float* pooled = g    + (size_t)NN * 64;             // [BB,64]
  unsigned* mm  = (unsigned*)(pooled + BB * 64);      // [2]
  int* deg      = (int*)(mm + 2);                     // [NN]
  int* rowstart = deg + NN;                           // [NN+1]
  int* cursor   = rowstart + NN + 1;                  // [NN]
  int* nbr      = cursor + NN;                        // [EE]
  int* bsum     = nbr + EE;                           // [NBLK_SCAN]

  // ---- CSR build + weight prep ----
  hipMemsetAsync(deg, 0, NN * sizeof(int), stream);
  hist_k<<<(EE + 255) / 256, 256, 0, stream>>>(ei, deg);
  prepw_k<<<144, 256, 0, stream>>>(Ws1, Wn1, Ws2, Wn2, W1, W2, W3, wt);
  scan1_k<<<NBLK_SCAN, 512, 0, stream>>>(deg, rowstart, bsum);
  scan2_k<<<1, 64, 0, stream>>>(bsum);
  scan3_k<<<NBLK_SCAN, 512, 0, stream>>>(rowstart, cursor, bsum);
  fill_k<<<(EE + 255) / 256, 256, 0, stream>>>(ei, cursor, nbr);

  // ---- layer 0 aggregate (scalar) ----
  agg0_gather_k<<<(NROWS + 255) / 256, 256, 0, stream>>>(x0, rowstart, nbr, agg0);

  // ---- layer 1 (agg1 gather fused, MFMA) -> x1 (bf16) ----
  conv1_k<<<NROWS / 64, 512, 0, stream>>>(x0, agg0, rowstart, nbr,
                                          Ws0, Wn0, wt, x1b);

  // ---- fused conv2 + MLP + mean + min/max (MFMA, bf16 LDS) ----
  hipMemsetAsync(mm, 0xFF, 4, stream);
  hipMemsetAsync(mm + 1, 0x00, 4, stream);
  fused2_k<<<NROWS / 64, 512, 0, stream>>>(x1b, rowstart, nbr, x0, agg0,
                                           Ws0, Wn0, wt, b1, b2, b3, g, mm);

  // ---- rescale + pooling ----
  hipMemsetAsync(pooled, 0, BB * 64 * sizeof(float), stream);
  pool2_k<<<(NN + 63) / 64, 256, 0, stream>>>(g, batch, mm, pooled);

  // ---- output linear ----
  out_k<<<BB, 64, 0, stream>>>(pooled, Wo, bo, out);
}